// Round 6
// baseline (1197.447 us; speedup 1.0000x reference)
//
#include <hip/hip_runtime.h>
#include <math.h>

// EELP: 20-step GNN scan, MFMA-bf16, deferred-r, fused-step.
// Numerics: the H-recurrence is fp32-clean (hi/lo split node GEMM, fp32 A/Bs,
// fp32 H update, libm tanhf). One-shot paths (pair z, dH storage) use bf16.

typedef short bf16x8 __attribute__((ext_vector_type(8)));
typedef float f32x4 __attribute__((ext_vector_type(4)));
typedef unsigned short u16x8 __attribute__((ext_vector_type(8)));

__device__ __forceinline__ float bf2f(unsigned short u) {
  return __uint_as_float(((unsigned)u) << 16);
}
__device__ __forceinline__ unsigned short f2bf(float f) {
  unsigned u = __float_as_uint(f);
  unsigned r = (u + 0x7FFFu + ((u >> 16) & 1u)) >> 16;
  return (unsigned short)r;
}
__device__ __forceinline__ float softplusf(float x) {
  return x > 20.f ? x : log1pf(expf(x));
}

// ---------------- setup: degree count + 3-phase scan + CSR fill ----------------

__global__ void count_kernel(const int* __restrict__ col, int E, int* __restrict__ cnt) {
  int e = blockIdx.x * blockDim.x + threadIdx.x;
  if (e < E) atomicAdd(&cnt[col[e]], 1);
}

__global__ __launch_bounds__(1024) void scan1_kernel(int* __restrict__ cnt,
                                                     int* __restrict__ colptr,
                                                     float* __restrict__ dinv,
                                                     int* __restrict__ bsum, int N) {
  __shared__ int sh[1024];
  int t = threadIdx.x, b = blockIdx.x;
  int i = b * 1024 + t;
  int v = (i < N) ? cnt[i] : 0;
  sh[t] = v;
  __syncthreads();
  for (int off = 1; off < 1024; off <<= 1) {
    int o = (t >= off) ? sh[t - off] : 0;
    __syncthreads();
    sh[t] += o;
    __syncthreads();
  }
  if (i < N) {
    colptr[i] = sh[t] - v;  // exclusive (within block)
    dinv[i] = rsqrtf((float)(v + 1));
    cnt[i] = 0;  // reset cursor for fill
  }
  if (t == 1023) bsum[b] = sh[1023];
}

__global__ void scan2_kernel(int* __restrict__ bsum, int B) {
  if (threadIdx.x == 0 && blockIdx.x == 0) {
    int run = 0;
    for (int b = 0; b < B; b++) {
      int x = bsum[b];
      bsum[b] = run;
      run += x;
    }
    bsum[B] = run;
  }
}

__global__ void scan3_kernel(int* __restrict__ colptr, const int* __restrict__ bsum, int N) {
  int i = blockIdx.x * blockDim.x + threadIdx.x;
  if (i < N) colptr[i] += bsum[i >> 10];
  if (i == N) colptr[N] = bsum[(N + 1023) >> 10];
}

__global__ void fill_kernel(const int* __restrict__ row, const int* __restrict__ col, int E,
                            const int* __restrict__ colptr, int* __restrict__ cur,
                            int* __restrict__ csr) {
  int e = blockIdx.x * blockDim.x + threadIdx.x;
  if (e < E) {
    int c = col[e];
    int pos = colptr[c] + atomicAdd(&cur[c], 1);
    csr[pos] = row[e];
  }
}

// Transposed bf16 weights (row j = output col, col k = input dim):
// Wn2T hi/lo (128 x 64): [Omega_as | W_s]; Wfc1T (128 x 128); WencT/Wp1T (64 x 128)
__global__ void prep_weights(const float* __restrict__ Om, const float* __restrict__ Wsr,
                             const float* __restrict__ Wfc1, const float* __restrict__ Wenc,
                             const float* __restrict__ Wp1, unsigned short* __restrict__ Wn2T,
                             unsigned short* __restrict__ Wn2Tlo,
                             unsigned short* __restrict__ Wfc1T,
                             unsigned short* __restrict__ WencT,
                             unsigned short* __restrict__ Wp1T) {
  int idx = blockIdx.x * blockDim.x + threadIdx.x;
  if (idx < 128 * 64) {
    int j = idx / 64, k = idx % 64;
    float v;
    if (j < 64) {
      v = Om[k * 64 + j] - Om[j * 64 + k];
    } else {
      int jj = j - 64;
      v = 0.5f * (Wsr[k * 64 + jj] + Wsr[jj * 64 + k]);
    }
    unsigned short hi = f2bf(v);
    Wn2T[idx] = hi;
    Wn2Tlo[idx] = f2bf(v - bf2f(hi));
  } else if (idx < 128 * 64 + 128 * 128) {
    int t = idx - 128 * 64;
    int j = t / 128, k = t % 128;
    Wfc1T[t] = f2bf(Wfc1[k * 128 + j]);
  } else if (idx < 128 * 64 + 128 * 128 + 64 * 128) {
    int t = idx - 128 * 64 - 128 * 128;
    int j = t / 128, k = t % 128;
    WencT[t] = f2bf(Wenc[k * 64 + j]);
  } else if (idx < 128 * 64 + 128 * 128 + 2 * 64 * 128) {
    int t = idx - 128 * 64 - 128 * 128 - 64 * 128;
    int j = t / 128, k = t % 128;
    Wp1T[t] = f2bf(Wp1[k * 64 + j]);
  }
}

// ---------------- encoder GEMM: H = relu(x @ Wenc), K=128 ----------------

__global__ __launch_bounds__(256) void enc_gemm(const float* __restrict__ X,
                                                const unsigned short* __restrict__ WT,
                                                float* __restrict__ H, float* __restrict__ H0,
                                                unsigned short* __restrict__ Hb_hi,
                                                unsigned short* __restrict__ Hb_lo, int N) {
  int gw = blockIdx.x * 4 + (threadIdx.x >> 6);
  int l = threadIdx.x & 63;
  int r0 = gw * 16;
  if (r0 >= N) return;
  int arow = min(r0 + (l & 15), N - 1);
  int ak = (l >> 4) * 8;
  bf16x8 a[4];
#pragma unroll
  for (int kk = 0; kk < 4; kk++) {
    const float* xp = X + (size_t)arow * 128 + kk * 32 + ak;
    float4 u = *(const float4*)xp;
    float4 v = *(const float4*)(xp + 4);
    bf16x8 t;
    t[0] = (short)f2bf(u.x); t[1] = (short)f2bf(u.y);
    t[2] = (short)f2bf(u.z); t[3] = (short)f2bf(u.w);
    t[4] = (short)f2bf(v.x); t[5] = (short)f2bf(v.y);
    t[6] = (short)f2bf(v.z); t[7] = (short)f2bf(v.w);
    a[kk] = t;
  }
  int rbase = r0 + (l >> 4) * 4;
#pragma unroll
  for (int c = 0; c < 4; c++) {
    const unsigned short* wp = WT + (size_t)(c * 16 + (l & 15)) * 128 + ak;
    f32x4 acc = {0.f, 0.f, 0.f, 0.f};
#pragma unroll
    for (int kk = 0; kk < 4; kk++)
      acc = __builtin_amdgcn_mfma_f32_16x16x32_bf16(a[kk], *(const bf16x8*)(wp + kk * 32), acc,
                                                    0, 0, 0);
    int gcol = c * 16 + (l & 15);
#pragma unroll
    for (int b = 0; b < 4; b++) {
      int gr = rbase + b;
      if (gr < N) {
        float v = fmaxf(acc[b], 0.f);
        H[(size_t)gr * 64 + gcol] = v;
        H0[(size_t)gr * 64 + gcol] = v;
        unsigned short hi = f2bf(v);
        Hb_hi[(size_t)gr * 64 + gcol] = hi;
        Hb_lo[(size_t)gr * 64 + gcol] = f2bf(v - bf2f(hi));
      }
    }
  }
}

// ---------------- K1: node GEMM (split hi/lo) -> A (f32), Bs (f32) + ftfb ----------------

__global__ __launch_bounds__(256) void node_gemm(const unsigned short* __restrict__ Hb_hi,
                                                 const unsigned short* __restrict__ Hb_lo,
                                                 const unsigned short* __restrict__ Wn2T,
                                                 const unsigned short* __restrict__ Wn2Tlo,
                                                 const float* __restrict__ H,
                                                 const float* __restrict__ Wfv,
                                                 const float* __restrict__ dinv,
                                                 float* __restrict__ Abuf,
                                                 float* __restrict__ Bsbuf,
                                                 float* __restrict__ ftfb, int N) {
  int gw = blockIdx.x * 4 + (threadIdx.x >> 6);
  int l = threadIdx.x & 63;
  int r0 = gw * 16;
  if (r0 >= N) return;
  int arow = min(r0 + (l & 15), N - 1);
  int ak = (l >> 4) * 8;
  bf16x8 a0h = *(const bf16x8*)(Hb_hi + (size_t)arow * 64 + ak);
  bf16x8 a1h = *(const bf16x8*)(Hb_hi + (size_t)arow * 64 + 32 + ak);
  bf16x8 a0l = *(const bf16x8*)(Hb_lo + (size_t)arow * 64 + ak);
  bf16x8 a1l = *(const bf16x8*)(Hb_lo + (size_t)arow * 64 + 32 + ak);
  int rbase = r0 + (l >> 4) * 4;
  float dv[4];
#pragma unroll
  for (int b = 0; b < 4; b++) dv[b] = dinv[min(rbase + b, N - 1)];
#pragma unroll
  for (int c = 0; c < 8; c++) {
    size_t woff = (size_t)(c * 16 + (l & 15)) * 64 + ak;
    bf16x8 b0h = *(const bf16x8*)(Wn2T + woff);
    bf16x8 b1h = *(const bf16x8*)(Wn2T + woff + 32);
    bf16x8 b0l = *(const bf16x8*)(Wn2Tlo + woff);
    bf16x8 b1l = *(const bf16x8*)(Wn2Tlo + woff + 32);
    f32x4 acc = {0.f, 0.f, 0.f, 0.f};
    acc = __builtin_amdgcn_mfma_f32_16x16x32_bf16(a0h, b0h, acc, 0, 0, 0);
    acc = __builtin_amdgcn_mfma_f32_16x16x32_bf16(a1h, b1h, acc, 0, 0, 0);
    acc = __builtin_amdgcn_mfma_f32_16x16x32_bf16(a0l, b0h, acc, 0, 0, 0);
    acc = __builtin_amdgcn_mfma_f32_16x16x32_bf16(a1l, b1h, acc, 0, 0, 0);
    acc = __builtin_amdgcn_mfma_f32_16x16x32_bf16(a0h, b0l, acc, 0, 0, 0);
    acc = __builtin_amdgcn_mfma_f32_16x16x32_bf16(a1h, b1l, acc, 0, 0, 0);
    int gcol = c * 16 + (l & 15);
#pragma unroll
    for (int b = 0; b < 4; b++) {
      int gr = rbase + b;
      if (gr < N) {
        float v = acc[b];
        if (c >= 4) {
          Bsbuf[(size_t)gr * 64 + (gcol - 64)] = v * dv[b];
        } else {
          Abuf[(size_t)gr * 64 + gcol] = v;
        }
      }
    }
  }
  // ftfb from fp32 H (pre-update)
  int d0 = (l >> 4) * 16;
  const float* hp = H + (size_t)arow * 64 + d0;
  float p0 = 0.f, p1 = 0.f;
#pragma unroll
  for (int i = 0; i < 16; i += 4) {
    float4 h = *(const float4*)(hp + i);
    p0 += h.x * Wfv[d0 + i] + h.y * Wfv[d0 + i + 1] + h.z * Wfv[d0 + i + 2] +
          h.w * Wfv[d0 + i + 3];
    p1 += h.x * Wfv[64 + d0 + i] + h.y * Wfv[64 + d0 + i + 1] + h.z * Wfv[64 + d0 + i + 2] +
          h.w * Wfv[64 + d0 + i + 3];
  }
  p0 += __shfl_xor(p0, 16, 64);
  p0 += __shfl_xor(p0, 32, 64);
  p1 += __shfl_xor(p1, 16, 64);
  p1 += __shfl_xor(p1, 32, 64);
  if (l < 16 && r0 + l < N) {
    ftfb[2 * (r0 + l)] = p0;
    ftfb[2 * (r0 + l) + 1] = p1;
  }
}

// ---------------- K2: [pair blocks | aggregate blocks] ----------------

__global__ __launch_bounds__(256) void step_kernel(
    const float* __restrict__ Abuf, const float* __restrict__ Bsbuf,
    const int* __restrict__ colptr, const int* __restrict__ csr,
    const float* __restrict__ dinv, float* __restrict__ H,
    unsigned short* __restrict__ Hn_hi, unsigned short* __restrict__ Hn_lo,
    unsigned short* __restrict__ dHt, const unsigned short* __restrict__ Hc_hi,
    const unsigned short* __restrict__ Hc_lo, const unsigned short* __restrict__ Wfc1T,
    const float* __restrict__ Wfc2, const float* __restrict__ ftfb,
    const int* __restrict__ pairs, const float* __restrict__ gum,
    float* __restrict__ tau_out, int N, int P, int PB) {
  int l = threadIdx.x & 63;
  if ((int)blockIdx.x < PB) {
    // ---- pair part: z = [H[src]|H[dst]] @ Wfc1 via hi+lo MFMA, logits, tau ----
    int w = threadIdx.x >> 6;
    int p0 = (blockIdx.x * 4 + w) * 16;
    if (p0 >= P) return;
    int pr = min(p0 + (l & 15), P - 1);
    int src = pairs[2 * pr], dst = pairs[2 * pr + 1];
    bf16x8 ah[4], al[4];
#pragma unroll
    for (int kk = 0; kk < 4; kk++) {
      int k0 = kk * 32 + (l >> 4) * 8;
      size_t base = (k0 < 64) ? ((size_t)src * 64 + k0) : ((size_t)dst * 64 + (k0 - 64));
      ah[kk] = *(const bf16x8*)(Hc_hi + base);
      al[kk] = *(const bf16x8*)(Hc_lo + base);
    }
    float l0[4] = {0.f, 0.f, 0.f, 0.f};
    float l1[4] = {0.f, 0.f, 0.f, 0.f};
#pragma unroll
    for (int c = 0; c < 8; c++) {
      const unsigned short* wp = Wfc1T + (size_t)(c * 16 + (l & 15)) * 128 + (l >> 4) * 8;
      f32x4 acc = {0.f, 0.f, 0.f, 0.f};
#pragma unroll
      for (int kk = 0; kk < 4; kk++) {
        bf16x8 wv = *(const bf16x8*)(wp + kk * 32);
        acc = __builtin_amdgcn_mfma_f32_16x16x32_bf16(ah[kk], wv, acc, 0, 0, 0);
        acc = __builtin_amdgcn_mfma_f32_16x16x32_bf16(al[kk], wv, acc, 0, 0, 0);
      }
      int m = c * 16 + (l & 15);
      float w0 = Wfc2[2 * m], w1 = Wfc2[2 * m + 1];
#pragma unroll
      for (int b = 0; b < 4; b++) {
        float zz = fmaxf(acc[b], 0.f);
        l0[b] = fmaf(zz, w0, l0[b]);
        l1[b] = fmaf(zz, w1, l1[b]);
      }
    }
#pragma unroll
    for (int off = 1; off < 16; off <<= 1) {
#pragma unroll
      for (int b = 0; b < 4; b++) {
        l0[b] += __shfl_xor(l0[b], off, 64);
        l1[b] += __shfl_xor(l1[b], off, 64);
      }
    }
    int li = l & 15;
    if (li < 4) {
      int pg = p0 + (l >> 4) * 4 + li;
      if (pg < P) {
        int s2 = pairs[2 * pg], d2 = pairs[2 * pg + 1];
        float nu = softplusf(ftfb[2 * s2] + ftfb[2 * d2 + 1]) + 1.0f;
        float g0 = gum[2 * (size_t)pg], g1 = gum[2 * (size_t)pg + 1];
        float dlt = ((l1[li] + g1) - (l0[li] + g0)) / nu;
        tau_out[pg] = 1.0f / (1.0f + expf(dlt));
      }
    }
  } else {
    // ---- aggregate part: wave per node, fp32 Bs gathers ----
    int c = (blockIdx.x - PB) * 4 + (threadIdx.x >> 6);
    if (c >= N) return;
    int g = l >> 4;
    int q = (l & 15) * 4;
    float acc[4] = {0.f, 0.f, 0.f, 0.f};
    if (g == 0) {
      float4 v = *(const float4*)(Bsbuf + (size_t)c * 64 + q);
      acc[0] = v.x; acc[1] = v.y; acc[2] = v.z; acc[3] = v.w;
    }
    int beg = colptr[c], end = colptr[c + 1];
    int i = beg + g;
    for (; i + 4 < end; i += 8) {
      int s0 = csr[i], s1 = csr[i + 4];
      float4 v0 = *(const float4*)(Bsbuf + (size_t)s0 * 64 + q);
      float4 v1 = *(const float4*)(Bsbuf + (size_t)s1 * 64 + q);
      acc[0] += v0.x + v1.x;
      acc[1] += v0.y + v1.y;
      acc[2] += v0.z + v1.z;
      acc[3] += v0.w + v1.w;
    }
    if (i < end) {
      int s0 = csr[i];
      float4 v0 = *(const float4*)(Bsbuf + (size_t)s0 * 64 + q);
      acc[0] += v0.x;
      acc[1] += v0.y;
      acc[2] += v0.z;
      acc[3] += v0.w;
    }
#pragma unroll
    for (int k = 0; k < 4; k++) {
      acc[k] += __shfl_xor(acc[k], 16, 64);
      acc[k] += __shfl_xor(acc[k], 32, 64);
    }
    if (g != 0) return;
    float dval = dinv[c];
    float4 av = *(const float4*)(Abuf + (size_t)c * 64 + q);
    float dh[4];
    dh[0] = fmaxf(tanhf(dval * acc[0] - fmaxf(av.x, 0.f)), 0.f);
    dh[1] = fmaxf(tanhf(dval * acc[1] - fmaxf(av.y, 0.f)), 0.f);
    dh[2] = fmaxf(tanhf(dval * acc[2] - fmaxf(av.z, 0.f)), 0.f);
    dh[3] = fmaxf(tanhf(dval * acc[3] - fmaxf(av.w, 0.f)), 0.f);
    ushort4 o;
    o.x = f2bf(dh[0]); o.y = f2bf(dh[1]); o.z = f2bf(dh[2]); o.w = f2bf(dh[3]);
    *(ushort4*)(dHt + (size_t)c * 64 + q) = o;
    float* hp = H + (size_t)c * 64 + q;
    float4 h = *(const float4*)hp;
    float4 hn;
    hn.x = h.x + dh[0]; hn.y = h.y + dh[1]; hn.z = h.z + dh[2]; hn.w = h.w + dh[3];
    *(float4*)hp = hn;
    ushort4 ohi, olo;
    ohi.x = f2bf(hn.x); olo.x = f2bf(hn.x - bf2f(ohi.x));
    ohi.y = f2bf(hn.y); olo.y = f2bf(hn.y - bf2f(ohi.y));
    ohi.z = f2bf(hn.z); olo.z = f2bf(hn.z - bf2f(ohi.z));
    ohi.w = f2bf(hn.w); olo.w = f2bf(hn.w - bf2f(ohi.w));
    *(ushort4*)(Hn_hi + (size_t)c * 64 + q) = ohi;
    *(ushort4*)(Hn_lo + (size_t)c * 64 + q) = olo;
  }
}

// ---------------- r build: rb(hi/lo) = H0 pair + sum_t tau*dH_t; ts ----------------

__global__ __launch_bounds__(256) void rbuild_kernel(
    const float* __restrict__ H0, const unsigned short* __restrict__ dHall,
    const float* __restrict__ tau, const int* __restrict__ pairs,
    unsigned short* __restrict__ rb_hi, unsigned short* __restrict__ rb_lo,
    float* __restrict__ ts, int P, int N, int Lsteps) {
  int p = blockIdx.x * 16 + (threadIdx.x >> 4);
  int l = threadIdx.x & 15;
  if (p >= P) return;
  int node = (l < 8) ? pairs[2 * p] : pairs[2 * p + 1];
  int d0 = (l & 7) * 8;
  const float* hp = H0 + (size_t)node * 64 + d0;
  float4 h0 = *(const float4*)hp;
  float4 h1 = *(const float4*)(hp + 4);
  float acc[8] = {h0.x, h0.y, h0.z, h0.w, h1.x, h1.y, h1.z, h1.w};
  float tsum = 0.f;
  const unsigned short* dbase = dHall + (size_t)node * 64 + d0;
#pragma unroll 2
  for (int t = 0; t < Lsteps; t++) {
    float tt = tau[(size_t)t * P + p];
    tsum += tt;
    u16x8 v = *(const u16x8*)(dbase + (size_t)t * N * 64);
#pragma unroll
    for (int i = 0; i < 8; i++) acc[i] = fmaf(tt, bf2f(v[i]), acc[i]);
  }
  u16x8 ohi, olo;
#pragma unroll
  for (int i = 0; i < 8; i++) {
    unsigned short hi = f2bf(acc[i]);
    ohi[i] = hi;
    olo[i] = f2bf(acc[i] - bf2f(hi));
  }
  *(u16x8*)(rb_hi + (size_t)p * 128 + l * 8) = ohi;
  *(u16x8*)(rb_lo + (size_t)p * 128 + l * 8) = olo;
  if (l == 0) ts[p] = tsum;
}

// ---------------- final: scores = (relu(rb @ Wp1) @ Wp2), split-A ----------------

__global__ __launch_bounds__(256) void final_gemm(const unsigned short* __restrict__ rb_hi,
                                                  const unsigned short* __restrict__ rb_lo,
                                                  const unsigned short* __restrict__ WT,
                                                  const float* __restrict__ Wp2,
                                                  float* __restrict__ out, int P) {
  int gw = blockIdx.x * 4 + (threadIdx.x >> 6);
  int l = threadIdx.x & 63;
  int r0 = gw * 16;
  if (r0 >= P) return;
  int arow = min(r0 + (l & 15), P - 1);
  int ak = (l >> 4) * 8;
  bf16x8 ah[4], al[4];
#pragma unroll
  for (int kk = 0; kk < 4; kk++) {
    ah[kk] = *(const bf16x8*)(rb_hi + (size_t)arow * 128 + kk * 32 + ak);
    al[kk] = *(const bf16x8*)(rb_lo + (size_t)arow * 128 + kk * 32 + ak);
  }
  float s[4] = {0.f, 0.f, 0.f, 0.f};
#pragma unroll
  for (int c = 0; c < 4; c++) {
    const unsigned short* wp = WT + (size_t)(c * 16 + (l & 15)) * 128 + ak;
    f32x4 acc = {0.f, 0.f, 0.f, 0.f};
#pragma unroll
    for (int kk = 0; kk < 4; kk++) {
      bf16x8 wv = *(const bf16x8*)(wp + kk * 32);
      acc = __builtin_amdgcn_mfma_f32_16x16x32_bf16(ah[kk], wv, acc, 0, 0, 0);
      acc = __builtin_amdgcn_mfma_f32_16x16x32_bf16(al[kk], wv, acc, 0, 0, 0);
    }
    float w = Wp2[c * 16 + (l & 15)];
#pragma unroll
    for (int b = 0; b < 4; b++) s[b] = fmaf(fmaxf(acc[b], 0.f), w, s[b]);
  }
#pragma unroll
  for (int off = 1; off < 16; off <<= 1) {
#pragma unroll
    for (int b = 0; b < 4; b++) s[b] += __shfl_xor(s[b], off, 64);
  }
  if ((l & 15) == 0) {
    int rbase = r0 + (l >> 4) * 4;
#pragma unroll
    for (int b = 0; b < 4; b++) {
      int gr = rbase + b;
      if (gr < P) out[gr] = s[b];
    }
  }
}

// ---------------- launch ----------------

extern "C" void kernel_launch(void* const* d_in, const int* in_sizes, int n_in, void* d_out,
                              int out_size, void* d_ws, size_t ws_size, hipStream_t stream) {
  const float* x = (const float*)d_in[0];
  const int* edge = (const int*)d_in[1];
  const int* pairs = (const int*)d_in[2];
  const float* gumbel = (const float*)d_in[3];
  const float* Wenc = (const float*)d_in[4];
  const float* Om = (const float*)d_in[5];
  const float* Wsr = (const float*)d_in[6];
  const float* Wfc1 = (const float*)d_in[7];
  const float* Wfc2 = (const float*)d_in[8];
  const float* Wfv = (const float*)d_in[9];
  const float* Wp1 = (const float*)d_in[10];
  const float* Wp2 = (const float*)d_in[11];
  const int IN = 128;
  const int N = in_sizes[0] / IN;
  const int E = in_sizes[1] / 2;
  const int P = in_sizes[2] / 2;
  const int L = in_sizes[3] / (2 * P);
  float* out = (float*)d_out;

  char* wsb = (char*)d_ws;
  size_t off = 0;
  auto alloc = [&](size_t bytes) -> char* {
    char* p = wsb + off;
    off = (off + bytes + 255) & ~(size_t)255;
    return p;
  };
  const int NB = (N + 1023) >> 10;
  float* dinv = (float*)alloc((size_t)N * 4);
  int* cnt = (int*)alloc((size_t)N * 4);
  int* colptr = (int*)alloc((size_t)(N + 1) * 4);
  int* bsum = (int*)alloc((size_t)(NB + 1) * 4);
  int* csr = (int*)alloc((size_t)E * 4);
  unsigned short* Wn2T = (unsigned short*)alloc((size_t)128 * 64 * 2);
  unsigned short* Wn2Tlo = (unsigned short*)alloc((size_t)128 * 64 * 2);
  unsigned short* Wfc1T = (unsigned short*)alloc((size_t)128 * 128 * 2);
  unsigned short* WencT = (unsigned short*)alloc((size_t)64 * 128 * 2);
  unsigned short* Wp1T = (unsigned short*)alloc((size_t)64 * 128 * 2);
  float* H = (float*)alloc((size_t)N * 64 * 4);
  float* H0 = (float*)alloc((size_t)N * 64 * 4);
  unsigned short* HbA_hi = (unsigned short*)alloc((size_t)N * 64 * 2);
  unsigned short* HbA_lo = (unsigned short*)alloc((size_t)N * 64 * 2);
  unsigned short* HbB_hi = (unsigned short*)alloc((size_t)N * 64 * 2);
  unsigned short* HbB_lo = (unsigned short*)alloc((size_t)N * 64 * 2);
  float* Abuf = (float*)alloc((size_t)N * 64 * 4);
  float* Bsbuf = (float*)alloc((size_t)N * 64 * 4);
  float* ftfb = (float*)alloc((size_t)N * 2 * 4);
  unsigned short* dHall = (unsigned short*)alloc((size_t)L * N * 64 * 2);
  float* tau = (float*)alloc((size_t)L * P * 4);
  unsigned short* rb_hi = (unsigned short*)alloc((size_t)P * 128 * 2);
  unsigned short* rb_lo = (unsigned short*)alloc((size_t)P * 128 * 2);
  (void)ws_size;
  (void)n_in;
  (void)out_size;

  const int* erow = edge;
  const int* ecol = edge + E;

  hipMemsetAsync(cnt, 0, (size_t)N * 4, stream);
  count_kernel<<<(E + 255) / 256, 256, 0, stream>>>(ecol, E, cnt);
  scan1_kernel<<<NB, 1024, 0, stream>>>(cnt, colptr, dinv, bsum, N);
  scan2_kernel<<<1, 64, 0, stream>>>(bsum, NB);
  scan3_kernel<<<(N + 256) / 256, 256, 0, stream>>>(colptr, bsum, N);
  fill_kernel<<<(E + 255) / 256, 256, 0, stream>>>(erow, ecol, E, colptr, cnt, csr);
  prep_weights<<<(128 * 64 + 128 * 128 + 2 * 64 * 128 + 255) / 256, 256, 0, stream>>>(
      Om, Wsr, Wfc1, Wenc, Wp1, Wn2T, Wn2Tlo, Wfc1T, WencT, Wp1T);

  int nwaves = (N + 15) / 16;
  enc_gemm<<<(nwaves + 3) / 4, 256, 0, stream>>>(x, WencT, H, H0, HbA_hi, HbA_lo, N);

  unsigned short* cur_hi = HbA_hi;
  unsigned short* cur_lo = HbA_lo;
  unsigned short* nxt_hi = HbB_hi;
  unsigned short* nxt_lo = HbB_lo;
  const int PB = (P + 63) / 64;
  const int AGB = (N + 3) / 4;
  for (int t = 0; t < L; t++) {
    node_gemm<<<(nwaves + 3) / 4, 256, 0, stream>>>(cur_hi, cur_lo, Wn2T, Wn2Tlo, H, Wfv, dinv,
                                                    Abuf, Bsbuf, ftfb, N);
    step_kernel<<<PB + AGB, 256, 0, stream>>>(Abuf, Bsbuf, colptr, csr, dinv, H, nxt_hi, nxt_lo,
                                              dHall + (size_t)t * N * 64, cur_hi, cur_lo,
                                              Wfc1T, Wfc2, ftfb, pairs,
                                              gumbel + (size_t)t * P * 2, tau + (size_t)t * P,
                                              N, P, PB);
    unsigned short* th = cur_hi; cur_hi = nxt_hi; nxt_hi = th;
    unsigned short* tl = cur_lo; cur_lo = nxt_lo; nxt_lo = tl;
  }
  rbuild_kernel<<<(P + 15) / 16, 256, 0, stream>>>(H0, dHall, tau, pairs, rb_hi, rb_lo,
                                                   out + P, P, N, L);
  int pwaves = (P + 15) / 16;
  final_gemm<<<(pwaves + 3) / 4, 256, 0, stream>>>(rb_hi, rb_lo, Wp1T, Wp2, out, P);
}

// Round 8
// 936.448 us; speedup vs baseline: 1.2787x; 1.2787x over previous
//
#include <hip/hip_runtime.h>
#include <math.h>

// EELP: 20-step GNN scan. fp32-clean H-recurrence (hi/lo split MFMA, fp32
// A/Bs/H, libm tanh). One fused kernel per step: [pair z-GEMM (hi+lo) |
// aggregate + in-LDS node GEMM for t+1]. Deferred r; node-major dHall.

typedef short bf16x8 __attribute__((ext_vector_type(8)));
typedef float f32x4 __attribute__((ext_vector_type(4)));
typedef unsigned short u16x8 __attribute__((ext_vector_type(8)));

__device__ __forceinline__ float bf2f(unsigned short u) {
  return __uint_as_float(((unsigned)u) << 16);
}
__device__ __forceinline__ unsigned short f2bf(float f) {
  unsigned u = __float_as_uint(f);
  unsigned r = (u + 0x7FFFu + ((u >> 16) & 1u)) >> 16;
  return (unsigned short)r;
}
__device__ __forceinline__ float softplusf(float x) {
  return x > 20.f ? x : log1pf(expf(x));
}

// ---------------- setup: degree count + 3-phase scan + CSR fill ----------------

__global__ void count_kernel(const int* __restrict__ col, int E, int* __restrict__ cnt) {
  int e = blockIdx.x * blockDim.x + threadIdx.x;
  if (e < E) atomicAdd(&cnt[col[e]], 1);
}

__global__ __launch_bounds__(1024) void scan1_kernel(int* __restrict__ cnt,
                                                     int* __restrict__ colptr,
                                                     float* __restrict__ dinv,
                                                     int* __restrict__ bsum, int N) {
  __shared__ int sh[1024];
  int t = threadIdx.x, b = blockIdx.x;
  int i = b * 1024 + t;
  int v = (i < N) ? cnt[i] : 0;
  sh[t] = v;
  __syncthreads();
  for (int off = 1; off < 1024; off <<= 1) {
    int o = (t >= off) ? sh[t - off] : 0;
    __syncthreads();
    sh[t] += o;
    __syncthreads();
  }
  if (i < N) {
    colptr[i] = sh[t] - v;
    dinv[i] = rsqrtf((float)(v + 1));
    cnt[i] = 0;
  }
  if (t == 1023) bsum[b] = sh[1023];
}

__global__ void scan2_kernel(int* __restrict__ bsum, int B) {
  if (threadIdx.x == 0 && blockIdx.x == 0) {
    int run = 0;
    for (int b = 0; b < B; b++) {
      int x = bsum[b];
      bsum[b] = run;
      run += x;
    }
    bsum[B] = run;
  }
}

__global__ void scan3_kernel(int* __restrict__ colptr, const int* __restrict__ bsum, int N) {
  int i = blockIdx.x * blockDim.x + threadIdx.x;
  if (i < N) colptr[i] += bsum[i >> 10];
  if (i == N) colptr[N] = bsum[(N + 1023) >> 10];
}

__global__ void fill_kernel(const int* __restrict__ row, const int* __restrict__ col, int E,
                            const int* __restrict__ colptr, int* __restrict__ cur,
                            int* __restrict__ csr) {
  int e = blockIdx.x * blockDim.x + threadIdx.x;
  if (e < E) {
    int c = col[e];
    int pos = colptr[c] + atomicAdd(&cur[c], 1);
    csr[pos] = row[e];
  }
}

// Transposed bf16 weights (row j = output col, col k = input dim)

__global__ void prep_weights(const float* __restrict__ Om, const float* __restrict__ Wsr,
                             const float* __restrict__ Wfc1, const float* __restrict__ Wenc,
                             const float* __restrict__ Wp1, unsigned short* __restrict__ Wn2T,
                             unsigned short* __restrict__ Wn2Tlo,
                             unsigned short* __restrict__ Wfc1T,
                             unsigned short* __restrict__ WencT,
                             unsigned short* __restrict__ Wp1T) {
  int idx = blockIdx.x * blockDim.x + threadIdx.x;
  if (idx < 128 * 64) {
    int j = idx / 64, k = idx % 64;
    float v;
    if (j < 64) {
      v = Om[k * 64 + j] - Om[j * 64 + k];
    } else {
      int jj = j - 64;
      v = 0.5f * (Wsr[k * 64 + jj] + Wsr[jj * 64 + k]);
    }
    unsigned short hi = f2bf(v);
    Wn2T[idx] = hi;
    Wn2Tlo[idx] = f2bf(v - bf2f(hi));
  } else if (idx < 128 * 64 + 128 * 128) {
    int t = idx - 128 * 64;
    int j = t / 128, k = t % 128;
    Wfc1T[t] = f2bf(Wfc1[k * 128 + j]);
  } else if (idx < 128 * 64 + 128 * 128 + 64 * 128) {
    int t = idx - 128 * 64 - 128 * 128;
    int j = t / 128, k = t % 128;
    WencT[t] = f2bf(Wenc[k * 64 + j]);
  } else if (idx < 128 * 64 + 128 * 128 + 2 * 64 * 128) {
    int t = idx - 128 * 64 - 128 * 128 - 64 * 128;
    int j = t / 128, k = t % 128;
    Wp1T[t] = f2bf(Wp1[k * 64 + j]);
  }
}

// ---------------- encoder GEMM: H = relu(x @ Wenc), K=128 ----------------

__global__ __launch_bounds__(256) void enc_gemm(const float* __restrict__ X,
                                                const unsigned short* __restrict__ WT,
                                                float* __restrict__ H, float* __restrict__ H0,
                                                unsigned short* __restrict__ Hb_hi,
                                                unsigned short* __restrict__ Hb_lo, int N) {
  int gw = blockIdx.x * 4 + (threadIdx.x >> 6);
  int l = threadIdx.x & 63;
  int r0 = gw * 16;
  if (r0 >= N) return;
  int arow = min(r0 + (l & 15), N - 1);
  int ak = (l >> 4) * 8;
  bf16x8 a[4];
#pragma unroll
  for (int kk = 0; kk < 4; kk++) {
    const float* xp = X + (size_t)arow * 128 + kk * 32 + ak;
    float4 u = *(const float4*)xp;
    float4 v = *(const float4*)(xp + 4);
    bf16x8 t;
    t[0] = (short)f2bf(u.x); t[1] = (short)f2bf(u.y);
    t[2] = (short)f2bf(u.z); t[3] = (short)f2bf(u.w);
    t[4] = (short)f2bf(v.x); t[5] = (short)f2bf(v.y);
    t[6] = (short)f2bf(v.z); t[7] = (short)f2bf(v.w);
    a[kk] = t;
  }
  int rbase = r0 + (l >> 4) * 4;
#pragma unroll
  for (int c = 0; c < 4; c++) {
    const unsigned short* wp = WT + (size_t)(c * 16 + (l & 15)) * 128 + ak;
    f32x4 acc = {0.f, 0.f, 0.f, 0.f};
#pragma unroll
    for (int kk = 0; kk < 4; kk++)
      acc = __builtin_amdgcn_mfma_f32_16x16x32_bf16(a[kk], *(const bf16x8*)(wp + kk * 32), acc,
                                                    0, 0, 0);
    int gcol = c * 16 + (l & 15);
#pragma unroll
    for (int b = 0; b < 4; b++) {
      int gr = rbase + b;
      if (gr < N) {
        float v = fmaxf(acc[b], 0.f);
        H[(size_t)gr * 64 + gcol] = v;
        H0[(size_t)gr * 64 + gcol] = v;
        unsigned short hi = f2bf(v);
        Hb_hi[(size_t)gr * 64 + gcol] = hi;
        Hb_lo[(size_t)gr * 64 + gcol] = f2bf(v - bf2f(hi));
      }
    }
  }
}

// ---------------- bootstrap node GEMM (t=0 only): A, Bs fp32 + ftfb ----------------

__global__ __launch_bounds__(256) void node_gemm(const unsigned short* __restrict__ Hb_hi,
                                                 const unsigned short* __restrict__ Hb_lo,
                                                 const unsigned short* __restrict__ Wn2T,
                                                 const unsigned short* __restrict__ Wn2Tlo,
                                                 const float* __restrict__ H,
                                                 const float* __restrict__ Wfv,
                                                 const float* __restrict__ dinv,
                                                 float* __restrict__ Abuf,
                                                 float* __restrict__ Bsbuf,
                                                 float* __restrict__ ftfb, int N) {
  int gw = blockIdx.x * 4 + (threadIdx.x >> 6);
  int l = threadIdx.x & 63;
  int r0 = gw * 16;
  if (r0 >= N) return;
  int arow = min(r0 + (l & 15), N - 1);
  int ak = (l >> 4) * 8;
  bf16x8 a0h = *(const bf16x8*)(Hb_hi + (size_t)arow * 64 + ak);
  bf16x8 a1h = *(const bf16x8*)(Hb_hi + (size_t)arow * 64 + 32 + ak);
  bf16x8 a0l = *(const bf16x8*)(Hb_lo + (size_t)arow * 64 + ak);
  bf16x8 a1l = *(const bf16x8*)(Hb_lo + (size_t)arow * 64 + 32 + ak);
  int rbase = r0 + (l >> 4) * 4;
  float dv[4];
#pragma unroll
  for (int b = 0; b < 4; b++) dv[b] = dinv[min(rbase + b, N - 1)];
#pragma unroll
  for (int c = 0; c < 8; c++) {
    size_t woff = (size_t)(c * 16 + (l & 15)) * 64 + ak;
    bf16x8 b0h = *(const bf16x8*)(Wn2T + woff);
    bf16x8 b1h = *(const bf16x8*)(Wn2T + woff + 32);
    bf16x8 b0l = *(const bf16x8*)(Wn2Tlo + woff);
    bf16x8 b1l = *(const bf16x8*)(Wn2Tlo + woff + 32);
    f32x4 acc = {0.f, 0.f, 0.f, 0.f};
    acc = __builtin_amdgcn_mfma_f32_16x16x32_bf16(a0h, b0h, acc, 0, 0, 0);
    acc = __builtin_amdgcn_mfma_f32_16x16x32_bf16(a1h, b1h, acc, 0, 0, 0);
    acc = __builtin_amdgcn_mfma_f32_16x16x32_bf16(a0l, b0h, acc, 0, 0, 0);
    acc = __builtin_amdgcn_mfma_f32_16x16x32_bf16(a1l, b1h, acc, 0, 0, 0);
    acc = __builtin_amdgcn_mfma_f32_16x16x32_bf16(a0h, b0l, acc, 0, 0, 0);
    acc = __builtin_amdgcn_mfma_f32_16x16x32_bf16(a1h, b1l, acc, 0, 0, 0);
    int gcol = c * 16 + (l & 15);
#pragma unroll
    for (int b = 0; b < 4; b++) {
      int gr = rbase + b;
      if (gr < N) {
        float v = acc[b];
        if (c >= 4) Bsbuf[(size_t)gr * 64 + (gcol - 64)] = v * dv[b];
        else Abuf[(size_t)gr * 64 + gcol] = v;
      }
    }
  }
  int d0 = (l >> 4) * 16;
  const float* hp = H + (size_t)arow * 64 + d0;
  float p0 = 0.f, p1 = 0.f;
#pragma unroll
  for (int i = 0; i < 16; i += 4) {
    float4 h = *(const float4*)(hp + i);
    p0 += h.x * Wfv[d0 + i] + h.y * Wfv[d0 + i + 1] + h.z * Wfv[d0 + i + 2] +
          h.w * Wfv[d0 + i + 3];
    p1 += h.x * Wfv[64 + d0 + i] + h.y * Wfv[64 + d0 + i + 1] + h.z * Wfv[64 + d0 + i + 2] +
          h.w * Wfv[64 + d0 + i + 3];
  }
  p0 += __shfl_xor(p0, 16, 64);
  p0 += __shfl_xor(p0, 32, 64);
  p1 += __shfl_xor(p1, 16, 64);
  p1 += __shfl_xor(p1, 32, 64);
  if (l < 16 && r0 + l < N) {
    ftfb[2 * (r0 + l)] = p0;
    ftfb[2 * (r0 + l) + 1] = p1;
  }
}

// ---------------- fused step: [pair tau | aggregate + next node-GEMM] ----------------

__global__ __launch_bounds__(256) void step_fused(
    const float* __restrict__ A_cur, const float* __restrict__ Bs_cur,
    float* __restrict__ A_nxt, float* __restrict__ Bs_nxt, const int* __restrict__ colptr,
    const int* __restrict__ csr, const float* __restrict__ dinv, float* __restrict__ H,
    const unsigned short* __restrict__ Hc_hi, const unsigned short* __restrict__ Hc_lo,
    unsigned short* __restrict__ Hn_hi, unsigned short* __restrict__ Hn_lo,
    unsigned short* __restrict__ dHall, const unsigned short* __restrict__ Wn2T,
    const unsigned short* __restrict__ Wn2Tlo, const unsigned short* __restrict__ Wfc1T,
    const float* __restrict__ Wfc2, const float* __restrict__ ftfb_cur,
    float* __restrict__ ftfb_nxt, const float* __restrict__ Wfv,
    const int* __restrict__ pairs, const float* __restrict__ gum, float* __restrict__ tau,
    int t, int LT, int N, int P, int PB) {
  __shared__ unsigned short ldsHi[16 * 72];
  __shared__ unsigned short ldsLo[16 * 72];
  int l = threadIdx.x & 63;
  int w = threadIdx.x >> 6;
  if ((int)blockIdx.x < PB) {
    // ---- pair: z = [H[src]|H[dst]] @ Wfc1 (hi+lo), logits, tau ----
    int p0 = ((int)blockIdx.x * 4 + w) * 16;
    if (p0 >= P) return;
    int pr = min(p0 + (l & 15), P - 1);
    int src = pairs[2 * pr], dst = pairs[2 * pr + 1];
    bf16x8 ah[4], al[4];
#pragma unroll
    for (int kk = 0; kk < 4; kk++) {
      int k0 = kk * 32 + (l >> 4) * 8;
      size_t base = (k0 < 64) ? ((size_t)src * 64 + k0) : ((size_t)dst * 64 + (k0 - 64));
      ah[kk] = *(const bf16x8*)(Hc_hi + base);
      al[kk] = *(const bf16x8*)(Hc_lo + base);
    }
    float l0[4] = {0.f, 0.f, 0.f, 0.f};
    float l1[4] = {0.f, 0.f, 0.f, 0.f};
#pragma unroll
    for (int c = 0; c < 8; c++) {
      const unsigned short* wp = Wfc1T + (size_t)(c * 16 + (l & 15)) * 128 + (l >> 4) * 8;
      f32x4 acc = {0.f, 0.f, 0.f, 0.f};
#pragma unroll
      for (int kk = 0; kk < 4; kk++) {
        bf16x8 wv = *(const bf16x8*)(wp + kk * 32);
        acc = __builtin_amdgcn_mfma_f32_16x16x32_bf16(ah[kk], wv, acc, 0, 0, 0);
        acc = __builtin_amdgcn_mfma_f32_16x16x32_bf16(al[kk], wv, acc, 0, 0, 0);
      }
      int m = c * 16 + (l & 15);
      float w0 = Wfc2[2 * m], w1 = Wfc2[2 * m + 1];
#pragma unroll
      for (int b = 0; b < 4; b++) {
        float zz = fmaxf(acc[b], 0.f);
        l0[b] = fmaf(zz, w0, l0[b]);
        l1[b] = fmaf(zz, w1, l1[b]);
      }
    }
#pragma unroll
    for (int off = 1; off < 16; off <<= 1) {
#pragma unroll
      for (int b = 0; b < 4; b++) {
        l0[b] += __shfl_xor(l0[b], off, 64);
        l1[b] += __shfl_xor(l1[b], off, 64);
      }
    }
    int li = l & 15;
    if (li < 4) {
      int pg = p0 + (l >> 4) * 4 + li;
      if (pg < P) {
        int s2 = pairs[2 * pg], d2 = pairs[2 * pg + 1];
        float nu = softplusf(ftfb_cur[2 * s2] + ftfb_cur[2 * d2 + 1]) + 1.0f;
        float g0 = gum[2 * (size_t)pg], g1 = gum[2 * (size_t)pg + 1];
        float dlt = ((l1[li] + g1) - (l0[li] + g0)) / nu;
        tau[(size_t)pg * LT + t] = 1.0f / (1.0f + expf(dlt));
      }
    }
  } else {
    // ---- aggregate + H update + next-step node GEMM (16 nodes/block) ----
    int nb0 = ((int)blockIdx.x - PB) * 16;
    int g = l >> 4;
    int node = nb0 + w * 4 + g;
    int q = (l & 15) * 4;
    bool valid = node < N;
    float4 hn = make_float4(0.f, 0.f, 0.f, 0.f);
    if (valid) {
      size_t base = (size_t)node * 64 + q;
      float4 v = *(const float4*)(Bs_cur + base);
      float aa0 = v.x, aa1 = v.y, aa2 = v.z, aa3 = v.w;
      int beg = colptr[node], end = colptr[node + 1];
      int i = beg;
      for (; i + 3 < end; i += 4) {
        int n0 = csr[i], n1 = csr[i + 1], n2 = csr[i + 2], n3 = csr[i + 3];
        float4 u0 = *(const float4*)(Bs_cur + (size_t)n0 * 64 + q);
        float4 u1 = *(const float4*)(Bs_cur + (size_t)n1 * 64 + q);
        float4 u2 = *(const float4*)(Bs_cur + (size_t)n2 * 64 + q);
        float4 u3 = *(const float4*)(Bs_cur + (size_t)n3 * 64 + q);
        aa0 += (u0.x + u1.x) + (u2.x + u3.x);
        aa1 += (u0.y + u1.y) + (u2.y + u3.y);
        aa2 += (u0.z + u1.z) + (u2.z + u3.z);
        aa3 += (u0.w + u1.w) + (u2.w + u3.w);
      }
      for (; i < end; i++) {
        int n0 = csr[i];
        float4 u0 = *(const float4*)(Bs_cur + (size_t)n0 * 64 + q);
        aa0 += u0.x; aa1 += u0.y; aa2 += u0.z; aa3 += u0.w;
      }
      float dval = dinv[node];
      float4 av = *(const float4*)(A_cur + base);
      float dh0 = fmaxf(tanhf(dval * aa0 - fmaxf(av.x, 0.f)), 0.f);
      float dh1 = fmaxf(tanhf(dval * aa1 - fmaxf(av.y, 0.f)), 0.f);
      float dh2 = fmaxf(tanhf(dval * aa2 - fmaxf(av.z, 0.f)), 0.f);
      float dh3 = fmaxf(tanhf(dval * aa3 - fmaxf(av.w, 0.f)), 0.f);
      ushort4 od;
      od.x = f2bf(dh0); od.y = f2bf(dh1); od.z = f2bf(dh2); od.w = f2bf(dh3);
      *(ushort4*)(dHall + (size_t)node * (LT * 64) + t * 64 + q) = od;
      float* hp = H + base;
      float4 h = *(const float4*)hp;
      hn.x = h.x + dh0; hn.y = h.y + dh1; hn.z = h.z + dh2; hn.w = h.w + dh3;
      *(float4*)hp = hn;
    }
    ushort4 whi, wlo;
    whi.x = f2bf(hn.x); wlo.x = f2bf(hn.x - bf2f(whi.x));
    whi.y = f2bf(hn.y); wlo.y = f2bf(hn.y - bf2f(whi.y));
    whi.z = f2bf(hn.z); wlo.z = f2bf(hn.z - bf2f(whi.z));
    whi.w = f2bf(hn.w); wlo.w = f2bf(hn.w - bf2f(whi.w));
    int r = w * 4 + g;
    *(ushort4*)(ldsHi + r * 72 + q) = whi;
    *(ushort4*)(ldsLo + r * 72 + q) = wlo;
    if (valid) {
      *(ushort4*)(Hn_hi + (size_t)node * 64 + q) = whi;
      *(ushort4*)(Hn_lo + (size_t)node * 64 + q) = wlo;
    }
    float p0 = hn.x * Wfv[q] + hn.y * Wfv[q + 1] + hn.z * Wfv[q + 2] + hn.w * Wfv[q + 3];
    float p1 = hn.x * Wfv[64 + q] + hn.y * Wfv[64 + q + 1] + hn.z * Wfv[64 + q + 2] +
               hn.w * Wfv[64 + q + 3];
#pragma unroll
    for (int off = 1; off < 16; off <<= 1) {
      p0 += __shfl_xor(p0, off, 64);
      p1 += __shfl_xor(p1, off, 64);
    }
    if ((l & 15) == 0 && valid) {
      ftfb_nxt[2 * node] = p0;
      ftfb_nxt[2 * node + 1] = p1;
    }
    __syncthreads();
    // next-step node GEMM from LDS tile (rows = 16 nodes)
    int rowA = l & 15;
    int ak = g * 8;
    bf16x8 a0h = *(const bf16x8*)(ldsHi + rowA * 72 + ak);
    bf16x8 a1h = *(const bf16x8*)(ldsHi + rowA * 72 + 32 + ak);
    bf16x8 a0l = *(const bf16x8*)(ldsLo + rowA * 72 + ak);
    bf16x8 a1l = *(const bf16x8*)(ldsLo + rowA * 72 + 32 + ak);
    float dv[4];
#pragma unroll
    for (int b = 0; b < 4; b++) dv[b] = dinv[min(nb0 + g * 4 + b, N - 1)];
#pragma unroll
    for (int cc = 0; cc < 2; cc++) {
      int c = w * 2 + cc;
      size_t woff = (size_t)(c * 16 + rowA) * 64 + ak;
      bf16x8 b0h = *(const bf16x8*)(Wn2T + woff);
      bf16x8 b1h = *(const bf16x8*)(Wn2T + woff + 32);
      bf16x8 b0l = *(const bf16x8*)(Wn2Tlo + woff);
      bf16x8 b1l = *(const bf16x8*)(Wn2Tlo + woff + 32);
      f32x4 acc = {0.f, 0.f, 0.f, 0.f};
      acc = __builtin_amdgcn_mfma_f32_16x16x32_bf16(a0h, b0h, acc, 0, 0, 0);
      acc = __builtin_amdgcn_mfma_f32_16x16x32_bf16(a1h, b1h, acc, 0, 0, 0);
      acc = __builtin_amdgcn_mfma_f32_16x16x32_bf16(a0l, b0h, acc, 0, 0, 0);
      acc = __builtin_amdgcn_mfma_f32_16x16x32_bf16(a1l, b1h, acc, 0, 0, 0);
      acc = __builtin_amdgcn_mfma_f32_16x16x32_bf16(a0h, b0l, acc, 0, 0, 0);
      acc = __builtin_amdgcn_mfma_f32_16x16x32_bf16(a1h, b1l, acc, 0, 0, 0);
      int gcol = c * 16 + rowA;
#pragma unroll
      for (int b = 0; b < 4; b++) {
        int gr = nb0 + g * 4 + b;
        if (gr < N) {
          float v = acc[b];
          if (c >= 4) Bs_nxt[(size_t)gr * 64 + (gcol - 64)] = v * dv[b];
          else A_nxt[(size_t)gr * 64 + gcol] = v;
        }
      }
    }
  }
}

// ---------------- r build: rb(hi/lo) = H0 pair + sum_t tau*dH_t; ts ----------------

__global__ __launch_bounds__(256) void rbuild_kernel(
    const float* __restrict__ H0, const unsigned short* __restrict__ dHall,
    const float* __restrict__ tau, const int* __restrict__ pairs,
    unsigned short* __restrict__ rb_hi, unsigned short* __restrict__ rb_lo,
    float* __restrict__ ts, int P, int N, int Lsteps) {
  int p = blockIdx.x * 16 + (threadIdx.x >> 4);
  int l = threadIdx.x & 15;
  if (p >= P) return;
  int node = (l < 8) ? pairs[2 * p] : pairs[2 * p + 1];
  int d0 = (l & 7) * 8;
  const float* hp = H0 + (size_t)node * 64 + d0;
  float4 h0 = *(const float4*)hp;
  float4 h1 = *(const float4*)(hp + 4);
  float acc[8] = {h0.x, h0.y, h0.z, h0.w, h1.x, h1.y, h1.z, h1.w};
  float tsum = 0.f;
  const unsigned short* dbase = dHall + (size_t)node * (Lsteps * 64) + d0;
  const float* taup = tau + (size_t)p * Lsteps;
#pragma unroll 4
  for (int t = 0; t < Lsteps; t++) {
    float tt = taup[t];
    tsum += tt;
    u16x8 v = *(const u16x8*)(dbase + t * 64);
#pragma unroll
    for (int i = 0; i < 8; i++) acc[i] = fmaf(tt, bf2f(v[i]), acc[i]);
  }
  u16x8 ohi, olo;
#pragma unroll
  for (int i = 0; i < 8; i++) {
    unsigned short hi = f2bf(acc[i]);
    ohi[i] = hi;
    olo[i] = f2bf(acc[i] - bf2f(hi));
  }
  *(u16x8*)(rb_hi + (size_t)p * 128 + l * 8) = ohi;
  *(u16x8*)(rb_lo + (size_t)p * 128 + l * 8) = olo;
  if (l == 0) ts[p] = tsum;
}

// ---------------- final: scores = (relu(rb @ Wp1) @ Wp2), split-A ----------------

__global__ __launch_bounds__(256) void final_gemm(const unsigned short* __restrict__ rb_hi,
                                                  const unsigned short* __restrict__ rb_lo,
                                                  const unsigned short* __restrict__ WT,
                                                  const float* __restrict__ Wp2,
                                                  float* __restrict__ out, int P) {
  int gw = blockIdx.x * 4 + (threadIdx.x >> 6);
  int l = threadIdx.x & 63;
  int r0 = gw * 16;
  if (r0 >= P) return;
  int arow = min(r0 + (l & 15), P - 1);
  int ak = (l >> 4) * 8;
  bf16x8 ah[4], al[4];
#pragma unroll
  for (int kk = 0; kk < 4; kk++) {
    ah[kk] = *(const bf16x8*)(rb_hi + (size_t)arow * 128 + kk * 32 + ak);
    al[kk] = *(const bf16x8*)(rb_lo + (size_t)arow * 128 + kk * 32 + ak);
  }
  float s[4] = {0.f, 0.f, 0.f, 0.f};
#pragma unroll
  for (int c = 0; c < 4; c++) {
    const unsigned short* wp = WT + (size_t)(c * 16 + (l & 15)) * 128 + ak;
    f32x4 acc = {0.f, 0.f, 0.f, 0.f};
#pragma unroll
    for (int kk = 0; kk < 4; kk++) {
      bf16x8 wv = *(const bf16x8*)(wp + kk * 32);
      acc = __builtin_amdgcn_mfma_f32_16x16x32_bf16(ah[kk], wv, acc, 0, 0, 0);
      acc = __builtin_amdgcn_mfma_f32_16x16x32_bf16(al[kk], wv, acc, 0, 0, 0);
    }
    float w = Wp2[c * 16 + (l & 15)];
#pragma unroll
    for (int b = 0; b < 4; b++) s[b] = fmaf(fmaxf(acc[b], 0.f), w, s[b]);
  }
#pragma unroll
  for (int off = 1; off < 16; off <<= 1) {
#pragma unroll
    for (int b = 0; b < 4; b++) s[b] += __shfl_xor(s[b], off, 64);
  }
  if ((l & 15) == 0) {
    int rbase = r0 + (l >> 4) * 4;
#pragma unroll
    for (int b = 0; b < 4; b++) {
      int gr = rbase + b;
      if (gr < P) out[gr] = s[b];
    }
  }
}

// ---------------- launch ----------------

extern "C" void kernel_launch(void* const* d_in, const int* in_sizes, int n_in, void* d_out,
                              int out_size, void* d_ws, size_t ws_size, hipStream_t stream) {
  const float* x = (const float*)d_in[0];
  const int* edge = (const int*)d_in[1];
  const int* pairs = (const int*)d_in[2];
  const float* gumbel = (const float*)d_in[3];
  const float* Wenc = (const float*)d_in[4];
  const float* Om = (const float*)d_in[5];
  const float* Wsr = (const float*)d_in[6];
  const float* Wfc1 = (const float*)d_in[7];
  const float* Wfc2 = (const float*)d_in[8];
  const float* Wfv = (const float*)d_in[9];
  const float* Wp1 = (const float*)d_in[10];
  const float* Wp2 = (const float*)d_in[11];
  const int IN = 128;
  const int N = in_sizes[0] / IN;
  const int E = in_sizes[1] / 2;
  const int P = in_sizes[2] / 2;
  const int L = in_sizes[3] / (2 * P);
  float* out = (float*)d_out;

  char* wsb = (char*)d_ws;
  size_t off = 0;
  auto alloc = [&](size_t bytes) -> char* {
    char* p = wsb + off;
    off = (off + bytes + 255) & ~(size_t)255;
    return p;
  };
  const int NB = (N + 1023) >> 10;
  float* dinv = (float*)alloc((size_t)N * 4);
  int* cnt = (int*)alloc((size_t)N * 4);
  int* colptr = (int*)alloc((size_t)(N + 1) * 4);
  int* bsum = (int*)alloc((size_t)(NB + 1) * 4);
  int* csr = (int*)alloc((size_t)E * 4);
  unsigned short* Wn2T = (unsigned short*)alloc((size_t)128 * 64 * 2);
  unsigned short* Wn2Tlo = (unsigned short*)alloc((size_t)128 * 64 * 2);
  unsigned short* Wfc1T = (unsigned short*)alloc((size_t)128 * 128 * 2);
  unsigned short* WencT = (unsigned short*)alloc((size_t)64 * 128 * 2);
  unsigned short* Wp1T = (unsigned short*)alloc((size_t)64 * 128 * 2);
  float* H = (float*)alloc((size_t)N * 64 * 4);
  float* H0 = (float*)alloc((size_t)N * 64 * 4);
  unsigned short* HbA_hi = (unsigned short*)alloc((size_t)N * 64 * 2);
  unsigned short* HbA_lo = (unsigned short*)alloc((size_t)N * 64 * 2);
  unsigned short* HbB_hi = (unsigned short*)alloc((size_t)N * 64 * 2);
  unsigned short* HbB_lo = (unsigned short*)alloc((size_t)N * 64 * 2);
  float* A_a = (float*)alloc((size_t)N * 64 * 4);
  float* A_b = (float*)alloc((size_t)N * 64 * 4);
  float* Bs_a = (float*)alloc((size_t)N * 64 * 4);
  float* Bs_b = (float*)alloc((size_t)N * 64 * 4);
  float* ftfbA = (float*)alloc((size_t)N * 2 * 4);
  float* ftfbB = (float*)alloc((size_t)N * 2 * 4);
  unsigned short* dHall = (unsigned short*)alloc((size_t)N * L * 64 * 2);
  float* tau = (float*)alloc((size_t)P * L * 4);
  unsigned short* rb_hi = (unsigned short*)alloc((size_t)P * 128 * 2);
  unsigned short* rb_lo = (unsigned short*)alloc((size_t)P * 128 * 2);
  (void)ws_size;
  (void)n_in;
  (void)out_size;

  const int* erow = edge;
  const int* ecol = edge + E;

  hipMemsetAsync(cnt, 0, (size_t)N * 4, stream);
  count_kernel<<<(E + 255) / 256, 256, 0, stream>>>(ecol, E, cnt);
  scan1_kernel<<<NB, 1024, 0, stream>>>(cnt, colptr, dinv, bsum, N);
  scan2_kernel<<<1, 64, 0, stream>>>(bsum, NB);
  scan3_kernel<<<(N + 256) / 256, 256, 0, stream>>>(colptr, bsum, N);
  fill_kernel<<<(E + 255) / 256, 256, 0, stream>>>(erow, ecol, E, colptr, cnt, csr);
  prep_weights<<<(128 * 64 + 128 * 128 + 2 * 64 * 128 + 255) / 256, 256, 0, stream>>>(
      Om, Wsr, Wfc1, Wenc, Wp1, Wn2T, Wn2Tlo, Wfc1T, WencT, Wp1T);

  int nwaves = (N + 15) / 16;
  enc_gemm<<<(nwaves + 3) / 4, 256, 0, stream>>>(x, WencT, H, H0, HbA_hi, HbA_lo, N);
  node_gemm<<<(nwaves + 3) / 4, 256, 0, stream>>>(HbA_hi, HbA_lo, Wn2T, Wn2Tlo, H, Wfv, dinv,
                                                  A_a, Bs_a, ftfbA, N);

  unsigned short* cur_hi = HbA_hi;
  unsigned short* cur_lo = HbA_lo;
  unsigned short* nxt_hi = HbB_hi;
  unsigned short* nxt_lo = HbB_lo;
  float* A_cur = A_a;
  float* A_nxt = A_b;
  float* Bs_cur = Bs_a;
  float* Bs_nxt = Bs_b;
  float* ff_cur = ftfbA;
  float* ff_nxt = ftfbB;
  const int PB = (P + 63) / 64;
  const int AGB = (N + 15) / 16;
  for (int t = 0; t < L; t++) {
    step_fused<<<PB + AGB, 256, 0, stream>>>(
        A_cur, Bs_cur, A_nxt, Bs_nxt, colptr, csr, dinv, H, cur_hi, cur_lo, nxt_hi, nxt_lo,
        dHall, Wn2T, Wn2Tlo, Wfc1T, Wfc2, ff_cur, ff_nxt, Wfv, pairs,
        gumbel + (size_t)t * P * 2, tau, t, L, N, P, PB);
    { unsigned short* tmp = cur_hi; cur_hi = nxt_hi; nxt_hi = tmp; }
    { unsigned short* tmp = cur_lo; cur_lo = nxt_lo; nxt_lo = tmp; }
    { float* tmp = A_cur; A_cur = A_nxt; A_nxt = tmp; }
    { float* tmp = Bs_cur; Bs_cur = Bs_nxt; Bs_nxt = tmp; }
    { float* tmp = ff_cur; ff_cur = ff_nxt; ff_nxt = tmp; }
  }
  rbuild_kernel<<<(P + 15) / 16, 256, 0, stream>>>(H0, dHall, tau, pairs, rb_hi, rb_lo,
                                                   out + P, P, N, L);
  int pwaves = (P + 15) / 16;
  final_gemm<<<(pwaves + 3) / 4, 256, 0, stream>>>(rb_hi, rb_lo, Wp1T, Wp2, out, P);
}

// Round 9
// 917.364 us; speedup vs baseline: 1.3053x; 1.0208x over previous
//
#include <hip/hip_runtime.h>
#include <math.h>

// EELP: 20-step GNN scan. fp32-clean H-recurrence (hi/lo split MFMA, fp32
// A/Bs/H, libm tanh). Per-node T/D (fp32) replace the per-pair fc1 GEMM:
// z = T[src]+D[dst]. One fused kernel per step: [pair tau (gather+VALU) |
// aggregate + in-LDS node GEMM (A,Bs,T,D) for t+1]. Deferred r.

typedef short bf16x8 __attribute__((ext_vector_type(8)));
typedef float f32x4 __attribute__((ext_vector_type(4)));
typedef unsigned short u16x8 __attribute__((ext_vector_type(8)));

__device__ __forceinline__ float bf2f(unsigned short u) {
  return __uint_as_float(((unsigned)u) << 16);
}
__device__ __forceinline__ unsigned short f2bf(float f) {
  unsigned u = __float_as_uint(f);
  unsigned r = (u + 0x7FFFu + ((u >> 16) & 1u)) >> 16;
  return (unsigned short)r;
}
__device__ __forceinline__ float softplusf(float x) {
  return x > 20.f ? x : log1pf(expf(x));
}

// ---------------- setup: degree count + 3-phase scan + CSR fill ----------------

__global__ void count_kernel(const int* __restrict__ col, int E, int* __restrict__ cnt) {
  int e = blockIdx.x * blockDim.x + threadIdx.x;
  if (e < E) atomicAdd(&cnt[col[e]], 1);
}

__global__ __launch_bounds__(1024) void scan1_kernel(int* __restrict__ cnt,
                                                     int* __restrict__ colptr,
                                                     float* __restrict__ dinv,
                                                     int* __restrict__ bsum, int N) {
  __shared__ int sh[1024];
  int t = threadIdx.x, b = blockIdx.x;
  int i = b * 1024 + t;
  int v = (i < N) ? cnt[i] : 0;
  sh[t] = v;
  __syncthreads();
  for (int off = 1; off < 1024; off <<= 1) {
    int o = (t >= off) ? sh[t - off] : 0;
    __syncthreads();
    sh[t] += o;
    __syncthreads();
  }
  if (i < N) {
    colptr[i] = sh[t] - v;
    dinv[i] = rsqrtf((float)(v + 1));
    cnt[i] = 0;
  }
  if (t == 1023) bsum[b] = sh[1023];
}

__global__ void scan2_kernel(int* __restrict__ bsum, int B) {
  if (threadIdx.x == 0 && blockIdx.x == 0) {
    int run = 0;
    for (int b = 0; b < B; b++) {
      int x = bsum[b];
      bsum[b] = run;
      run += x;
    }
    bsum[B] = run;
  }
}

__global__ void scan3_kernel(int* __restrict__ colptr, const int* __restrict__ bsum, int N) {
  int i = blockIdx.x * blockDim.x + threadIdx.x;
  if (i < N) colptr[i] += bsum[i >> 10];
  if (i == N) colptr[N] = bsum[(N + 1023) >> 10];
}

__global__ void fill_kernel(const int* __restrict__ row, const int* __restrict__ col, int E,
                            const int* __restrict__ colptr, int* __restrict__ cur,
                            int* __restrict__ csr) {
  int e = blockIdx.x * blockDim.x + threadIdx.x;
  if (e < E) {
    int c = col[e];
    int pos = colptr[c] + atomicAdd(&cur[c], 1);
    csr[pos] = row[e];
  }
}

// Transposed bf16 weights (row j = output col, col k = input dim)

__global__ void prep_weights(const float* __restrict__ Om, const float* __restrict__ Wsr,
                             const float* __restrict__ Wfc1, const float* __restrict__ Wenc,
                             const float* __restrict__ Wp1, unsigned short* __restrict__ Wn2T,
                             unsigned short* __restrict__ Wn2Tlo,
                             unsigned short* __restrict__ Wfc1T,
                             unsigned short* __restrict__ WencT,
                             unsigned short* __restrict__ Wp1T) {
  int idx = blockIdx.x * blockDim.x + threadIdx.x;
  if (idx < 128 * 64) {
    int j = idx / 64, k = idx % 64;
    float v;
    if (j < 64) {
      v = Om[k * 64 + j] - Om[j * 64 + k];
    } else {
      int jj = j - 64;
      v = 0.5f * (Wsr[k * 64 + jj] + Wsr[jj * 64 + k]);
    }
    unsigned short hi = f2bf(v);
    Wn2T[idx] = hi;
    Wn2Tlo[idx] = f2bf(v - bf2f(hi));
  } else if (idx < 128 * 64 + 128 * 128) {
    int t = idx - 128 * 64;
    int j = t / 128, k = t % 128;
    Wfc1T[t] = f2bf(Wfc1[k * 128 + j]);
  } else if (idx < 128 * 64 + 128 * 128 + 64 * 128) {
    int t = idx - 128 * 64 - 128 * 128;
    int j = t / 128, k = t % 128;
    WencT[t] = f2bf(Wenc[k * 64 + j]);
  } else if (idx < 128 * 64 + 128 * 128 + 2 * 64 * 128) {
    int t = idx - 128 * 64 - 128 * 128 - 64 * 128;
    int j = t / 128, k = t % 128;
    Wp1T[t] = f2bf(Wp1[k * 64 + j]);
  }
}

// ---------------- encoder GEMM: H = relu(x @ Wenc), K=128 ----------------

__global__ __launch_bounds__(256) void enc_gemm(const float* __restrict__ X,
                                                const unsigned short* __restrict__ WT,
                                                float* __restrict__ H, float* __restrict__ H0,
                                                unsigned short* __restrict__ Hb_hi,
                                                unsigned short* __restrict__ Hb_lo, int N) {
  int gw = blockIdx.x * 4 + (threadIdx.x >> 6);
  int l = threadIdx.x & 63;
  int r0 = gw * 16;
  if (r0 >= N) return;
  int arow = min(r0 + (l & 15), N - 1);
  int ak = (l >> 4) * 8;
  bf16x8 a[4];
#pragma unroll
  for (int kk = 0; kk < 4; kk++) {
    const float* xp = X + (size_t)arow * 128 + kk * 32 + ak;
    float4 u = *(const float4*)xp;
    float4 v = *(const float4*)(xp + 4);
    bf16x8 t;
    t[0] = (short)f2bf(u.x); t[1] = (short)f2bf(u.y);
    t[2] = (short)f2bf(u.z); t[3] = (short)f2bf(u.w);
    t[4] = (short)f2bf(v.x); t[5] = (short)f2bf(v.y);
    t[6] = (short)f2bf(v.z); t[7] = (short)f2bf(v.w);
    a[kk] = t;
  }
  int rbase = r0 + (l >> 4) * 4;
#pragma unroll
  for (int c = 0; c < 4; c++) {
    const unsigned short* wp = WT + (size_t)(c * 16 + (l & 15)) * 128 + ak;
    f32x4 acc = {0.f, 0.f, 0.f, 0.f};
#pragma unroll
    for (int kk = 0; kk < 4; kk++)
      acc = __builtin_amdgcn_mfma_f32_16x16x32_bf16(a[kk], *(const bf16x8*)(wp + kk * 32), acc,
                                                    0, 0, 0);
    int gcol = c * 16 + (l & 15);
#pragma unroll
    for (int b = 0; b < 4; b++) {
      int gr = rbase + b;
      if (gr < N) {
        float v = fmaxf(acc[b], 0.f);
        H[(size_t)gr * 64 + gcol] = v;
        H0[(size_t)gr * 64 + gcol] = v;
        unsigned short hi = f2bf(v);
        Hb_hi[(size_t)gr * 64 + gcol] = hi;
        Hb_lo[(size_t)gr * 64 + gcol] = f2bf(v - bf2f(hi));
      }
    }
  }
}

// ---------------- bootstrap node GEMM (t=0): A, Bs, T, D + ftfb ----------------

__global__ __launch_bounds__(256) void node_gemm(
    const unsigned short* __restrict__ Hb_hi, const unsigned short* __restrict__ Hb_lo,
    const unsigned short* __restrict__ Wn2T, const unsigned short* __restrict__ Wn2Tlo,
    const unsigned short* __restrict__ Wfc1T, const float* __restrict__ H,
    const float* __restrict__ Wfv, const float* __restrict__ dinv, float* __restrict__ Abuf,
    float* __restrict__ Bsbuf, float* __restrict__ Tbuf, float* __restrict__ Dbuf,
    float* __restrict__ ftfb, int N) {
  int gw = blockIdx.x * 4 + (threadIdx.x >> 6);
  int l = threadIdx.x & 63;
  int r0 = gw * 16;
  if (r0 >= N) return;
  int arow = min(r0 + (l & 15), N - 1);
  int ak = (l >> 4) * 8;
  bf16x8 a0h = *(const bf16x8*)(Hb_hi + (size_t)arow * 64 + ak);
  bf16x8 a1h = *(const bf16x8*)(Hb_hi + (size_t)arow * 64 + 32 + ak);
  bf16x8 a0l = *(const bf16x8*)(Hb_lo + (size_t)arow * 64 + ak);
  bf16x8 a1l = *(const bf16x8*)(Hb_lo + (size_t)arow * 64 + 32 + ak);
  int rbase = r0 + (l >> 4) * 4;
  float dv[4];
#pragma unroll
  for (int b = 0; b < 4; b++) dv[b] = dinv[min(rbase + b, N - 1)];
  // A, Bs (hi/lo W)
#pragma unroll
  for (int c = 0; c < 8; c++) {
    size_t woff = (size_t)(c * 16 + (l & 15)) * 64 + ak;
    bf16x8 b0h = *(const bf16x8*)(Wn2T + woff);
    bf16x8 b1h = *(const bf16x8*)(Wn2T + woff + 32);
    bf16x8 b0l = *(const bf16x8*)(Wn2Tlo + woff);
    bf16x8 b1l = *(const bf16x8*)(Wn2Tlo + woff + 32);
    f32x4 acc = {0.f, 0.f, 0.f, 0.f};
    acc = __builtin_amdgcn_mfma_f32_16x16x32_bf16(a0h, b0h, acc, 0, 0, 0);
    acc = __builtin_amdgcn_mfma_f32_16x16x32_bf16(a1h, b1h, acc, 0, 0, 0);
    acc = __builtin_amdgcn_mfma_f32_16x16x32_bf16(a0l, b0h, acc, 0, 0, 0);
    acc = __builtin_amdgcn_mfma_f32_16x16x32_bf16(a1l, b1h, acc, 0, 0, 0);
    acc = __builtin_amdgcn_mfma_f32_16x16x32_bf16(a0h, b0l, acc, 0, 0, 0);
    acc = __builtin_amdgcn_mfma_f32_16x16x32_bf16(a1h, b1l, acc, 0, 0, 0);
    int gcol = c * 16 + (l & 15);
#pragma unroll
    for (int b = 0; b < 4; b++) {
      int gr = rbase + b;
      if (gr < N) {
        float v = acc[b];
        if (c >= 4) Bsbuf[(size_t)gr * 64 + (gcol - 64)] = v * dv[b];
        else Abuf[(size_t)gr * 64 + gcol] = v;
      }
    }
  }
  // T, D (single-bf16 W, hi/lo A)
#pragma unroll
  for (int c = 0; c < 16; c++) {
    int j = ((c & 7) * 16 + (l & 15));
    int koff = (c < 8) ? 0 : 64;
    const unsigned short* wp = Wfc1T + (size_t)j * 128 + koff + ak;
    bf16x8 b0 = *(const bf16x8*)(wp);
    bf16x8 b1 = *(const bf16x8*)(wp + 32);
    f32x4 acc = {0.f, 0.f, 0.f, 0.f};
    acc = __builtin_amdgcn_mfma_f32_16x16x32_bf16(a0h, b0, acc, 0, 0, 0);
    acc = __builtin_amdgcn_mfma_f32_16x16x32_bf16(a1h, b1, acc, 0, 0, 0);
    acc = __builtin_amdgcn_mfma_f32_16x16x32_bf16(a0l, b0, acc, 0, 0, 0);
    acc = __builtin_amdgcn_mfma_f32_16x16x32_bf16(a1l, b1, acc, 0, 0, 0);
    float* dstb = (c < 8) ? Tbuf : Dbuf;
#pragma unroll
    for (int b = 0; b < 4; b++) {
      int gr = rbase + b;
      if (gr < N) dstb[(size_t)gr * 128 + j] = acc[b];
    }
  }
  int d0 = (l >> 4) * 16;
  const float* hp = H + (size_t)arow * 64 + d0;
  float p0 = 0.f, p1 = 0.f;
#pragma unroll
  for (int i = 0; i < 16; i += 4) {
    float4 h = *(const float4*)(hp + i);
    p0 += h.x * Wfv[d0 + i] + h.y * Wfv[d0 + i + 1] + h.z * Wfv[d0 + i + 2] +
          h.w * Wfv[d0 + i + 3];
    p1 += h.x * Wfv[64 + d0 + i] + h.y * Wfv[64 + d0 + i + 1] + h.z * Wfv[64 + d0 + i + 2] +
          h.w * Wfv[64 + d0 + i + 3];
  }
  p0 += __shfl_xor(p0, 16, 64);
  p0 += __shfl_xor(p0, 32, 64);
  p1 += __shfl_xor(p1, 16, 64);
  p1 += __shfl_xor(p1, 32, 64);
  if (l < 16 && r0 + l < N) {
    ftfb[2 * (r0 + l)] = p0;
    ftfb[2 * (r0 + l) + 1] = p1;
  }
}

// ---------------- fused step: [pair tau | aggregate + next node-GEMM] ----------------
// pair blocks: 32 pairs/block, 8 lanes/pair: z = T[src]+D[dst] (fp32), tau.
// agg blocks: 16 nodes/block; CSR gather, dh, H update, LDS tile, A/Bs/T/D GEMM.

__global__ __launch_bounds__(256) void step_fused(
    const float* __restrict__ A_cur, const float* __restrict__ Bs_cur,
    const float* __restrict__ T_cur, const float* __restrict__ D_cur,
    float* __restrict__ A_nxt, float* __restrict__ Bs_nxt, float* __restrict__ T_nxt,
    float* __restrict__ D_nxt, const int* __restrict__ colptr, const int* __restrict__ csr,
    const float* __restrict__ dinv, float* __restrict__ H, unsigned short* __restrict__ dHall,
    const unsigned short* __restrict__ Wn2T, const unsigned short* __restrict__ Wn2Tlo,
    const unsigned short* __restrict__ Wfc1T, const float* __restrict__ Wfc2,
    const float* __restrict__ ftfb_cur, float* __restrict__ ftfb_nxt,
    const float* __restrict__ Wfv, const int* __restrict__ pairs,
    const float* __restrict__ gum, float* __restrict__ tau, int t, int LT, int N, int P,
    int PB) {
  __shared__ unsigned short ldsHi[16 * 72];
  __shared__ unsigned short ldsLo[16 * 72];
  int l = threadIdx.x & 63;
  int w = threadIdx.x >> 6;
  if ((int)blockIdx.x < PB) {
    // ---- pair: z = T[src]+D[dst], logits via Wfc2, tau ----
    int p = (int)blockIdx.x * 32 + w * 8 + (l >> 3);
    bool act = p < P;
    int pc = act ? p : P - 1;
    int src = pairs[2 * pc], dst = pairs[2 * pc + 1];
    int d0 = (l & 7) * 16;
    const float* Tp = T_cur + (size_t)src * 128 + d0;
    const float* Dp = D_cur + (size_t)dst * 128 + d0;
    float l0 = 0.f, l1 = 0.f;
#pragma unroll
    for (int i = 0; i < 16; i += 4) {
      float4 tv = *(const float4*)(Tp + i);
      float4 dv4 = *(const float4*)(Dp + i);
      float z0 = fmaxf(tv.x + dv4.x, 0.f);
      float z1 = fmaxf(tv.y + dv4.y, 0.f);
      float z2 = fmaxf(tv.z + dv4.z, 0.f);
      float z3 = fmaxf(tv.w + dv4.w, 0.f);
      int m = d0 + i;
      l0 = fmaf(z0, Wfc2[2 * m], l0);
      l1 = fmaf(z0, Wfc2[2 * m + 1], l1);
      l0 = fmaf(z1, Wfc2[2 * m + 2], l0);
      l1 = fmaf(z1, Wfc2[2 * m + 3], l1);
      l0 = fmaf(z2, Wfc2[2 * m + 4], l0);
      l1 = fmaf(z2, Wfc2[2 * m + 5], l1);
      l0 = fmaf(z3, Wfc2[2 * m + 6], l0);
      l1 = fmaf(z3, Wfc2[2 * m + 7], l1);
    }
#pragma unroll
    for (int off = 1; off < 8; off <<= 1) {
      l0 += __shfl_xor(l0, off, 64);
      l1 += __shfl_xor(l1, off, 64);
    }
    if ((l & 7) == 0 && act) {
      float nu = softplusf(ftfb_cur[2 * src] + ftfb_cur[2 * dst + 1]) + 1.0f;
      float g0 = gum[2 * (size_t)p], g1 = gum[2 * (size_t)p + 1];
      float dlt = ((l1 + g1) - (l0 + g0)) / nu;
      tau[(size_t)p * LT + t] = 1.0f / (1.0f + expf(dlt));
    }
  } else {
    // ---- aggregate + H update + next-step node GEMM (16 nodes/block) ----
    int nb0 = ((int)blockIdx.x - PB) * 16;
    int g = l >> 4;
    int node = nb0 + w * 4 + g;
    int q = (l & 15) * 4;
    bool valid = node < N;
    float4 hn = make_float4(0.f, 0.f, 0.f, 0.f);
    if (valid) {
      size_t base = (size_t)node * 64 + q;
      float4 v = *(const float4*)(Bs_cur + base);
      float aa0 = v.x, aa1 = v.y, aa2 = v.z, aa3 = v.w;
      int beg = colptr[node], end = colptr[node + 1];
      int i = beg;
      for (; i + 3 < end; i += 4) {
        int n0 = csr[i], n1 = csr[i + 1], n2 = csr[i + 2], n3 = csr[i + 3];
        float4 u0 = *(const float4*)(Bs_cur + (size_t)n0 * 64 + q);
        float4 u1 = *(const float4*)(Bs_cur + (size_t)n1 * 64 + q);
        float4 u2 = *(const float4*)(Bs_cur + (size_t)n2 * 64 + q);
        float4 u3 = *(const float4*)(Bs_cur + (size_t)n3 * 64 + q);
        aa0 += (u0.x + u1.x) + (u2.x + u3.x);
        aa1 += (u0.y + u1.y) + (u2.y + u3.y);
        aa2 += (u0.z + u1.z) + (u2.z + u3.z);
        aa3 += (u0.w + u1.w) + (u2.w + u3.w);
      }
      for (; i < end; i++) {
        int n0 = csr[i];
        float4 u0 = *(const float4*)(Bs_cur + (size_t)n0 * 64 + q);
        aa0 += u0.x; aa1 += u0.y; aa2 += u0.z; aa3 += u0.w;
      }
      float dval = dinv[node];
      float4 av = *(const float4*)(A_cur + base);
      float dh0 = fmaxf(tanhf(dval * aa0 - fmaxf(av.x, 0.f)), 0.f);
      float dh1 = fmaxf(tanhf(dval * aa1 - fmaxf(av.y, 0.f)), 0.f);
      float dh2 = fmaxf(tanhf(dval * aa2 - fmaxf(av.z, 0.f)), 0.f);
      float dh3 = fmaxf(tanhf(dval * aa3 - fmaxf(av.w, 0.f)), 0.f);
      ushort4 od;
      od.x = f2bf(dh0); od.y = f2bf(dh1); od.z = f2bf(dh2); od.w = f2bf(dh3);
      *(ushort4*)(dHall + (size_t)node * (LT * 64) + t * 64 + q) = od;
      float* hp = H + base;
      float4 h = *(const float4*)hp;
      hn.x = h.x + dh0; hn.y = h.y + dh1; hn.z = h.z + dh2; hn.w = h.w + dh3;
      *(float4*)hp = hn;
    }
    ushort4 whi, wlo;
    whi.x = f2bf(hn.x); wlo.x = f2bf(hn.x - bf2f(whi.x));
    whi.y = f2bf(hn.y); wlo.y = f2bf(hn.y - bf2f(whi.y));
    whi.z = f2bf(hn.z); wlo.z = f2bf(hn.z - bf2f(whi.z));
    whi.w = f2bf(hn.w); wlo.w = f2bf(hn.w - bf2f(whi.w));
    int r = w * 4 + g;
    *(ushort4*)(ldsHi + r * 72 + q) = whi;
    *(ushort4*)(ldsLo + r * 72 + q) = wlo;
    float p0 = hn.x * Wfv[q] + hn.y * Wfv[q + 1] + hn.z * Wfv[q + 2] + hn.w * Wfv[q + 3];
    float p1 = hn.x * Wfv[64 + q] + hn.y * Wfv[64 + q + 1] + hn.z * Wfv[64 + q + 2] +
               hn.w * Wfv[64 + q + 3];
#pragma unroll
    for (int off = 1; off < 16; off <<= 1) {
      p0 += __shfl_xor(p0, off, 64);
      p1 += __shfl_xor(p1, off, 64);
    }
    if ((l & 15) == 0 && valid) {
      ftfb_nxt[2 * node] = p0;
      ftfb_nxt[2 * node + 1] = p1;
    }
    __syncthreads();
    // next-step node GEMM from LDS tile (rows = 16 nodes)
    int rowA = l & 15;
    int ak = g * 8;
    bf16x8 a0h = *(const bf16x8*)(ldsHi + rowA * 72 + ak);
    bf16x8 a1h = *(const bf16x8*)(ldsHi + rowA * 72 + 32 + ak);
    bf16x8 a0l = *(const bf16x8*)(ldsLo + rowA * 72 + ak);
    bf16x8 a1l = *(const bf16x8*)(ldsLo + rowA * 72 + 32 + ak);
    float dv[4];
#pragma unroll
    for (int b = 0; b < 4; b++) dv[b] = dinv[min(nb0 + g * 4 + b, N - 1)];
    // A (c=w) and Bs (c=4+w): hi/lo W, 6 MFMA each
#pragma unroll
    for (int cc = 0; cc < 2; cc++) {
      int c = cc * 4 + w;
      size_t woff = (size_t)(c * 16 + rowA) * 64 + ak;
      bf16x8 b0h = *(const bf16x8*)(Wn2T + woff);
      bf16x8 b1h = *(const bf16x8*)(Wn2T + woff + 32);
      bf16x8 b0l = *(const bf16x8*)(Wn2Tlo + woff);
      bf16x8 b1l = *(const bf16x8*)(Wn2Tlo + woff + 32);
      f32x4 acc = {0.f, 0.f, 0.f, 0.f};
      acc = __builtin_amdgcn_mfma_f32_16x16x32_bf16(a0h, b0h, acc, 0, 0, 0);
      acc = __builtin_amdgcn_mfma_f32_16x16x32_bf16(a1h, b1h, acc, 0, 0, 0);
      acc = __builtin_amdgcn_mfma_f32_16x16x32_bf16(a0l, b0h, acc, 0, 0, 0);
      acc = __builtin_amdgcn_mfma_f32_16x16x32_bf16(a1l, b1h, acc, 0, 0, 0);
      acc = __builtin_amdgcn_mfma_f32_16x16x32_bf16(a0h, b0l, acc, 0, 0, 0);
      acc = __builtin_amdgcn_mfma_f32_16x16x32_bf16(a1h, b1l, acc, 0, 0, 0);
      int gcol = c * 16 + rowA;
#pragma unroll
      for (int b = 0; b < 4; b++) {
        int gr = nb0 + g * 4 + b;
        if (gr < N) {
          float v = acc[b];
          if (cc == 1) Bs_nxt[(size_t)gr * 64 + (gcol - 64)] = v * dv[b];
          else A_nxt[(size_t)gr * 64 + gcol] = v;
        }
      }
    }
    // T (blocks 2w,2w+1) and D (blocks 2w,2w+1): single-bf16 W, 4 MFMA each
#pragma unroll
    for (int cc = 0; cc < 4; cc++) {
      int jb = (cc & 1) + 2 * w;          // 0..7
      int koff = (cc < 2) ? 0 : 64;       // T : D
      int j = jb * 16 + rowA;
      const unsigned short* wp = Wfc1T + (size_t)j * 128 + koff + ak;
      bf16x8 b0 = *(const bf16x8*)(wp);
      bf16x8 b1 = *(const bf16x8*)(wp + 32);
      f32x4 acc = {0.f, 0.f, 0.f, 0.f};
      acc = __builtin_amdgcn_mfma_f32_16x16x32_bf16(a0h, b0, acc, 0, 0, 0);
      acc = __builtin_amdgcn_mfma_f32_16x16x32_bf16(a1h, b1, acc, 0, 0, 0);
      acc = __builtin_amdgcn_mfma_f32_16x16x32_bf16(a0l, b0, acc, 0, 0, 0);
      acc = __builtin_amdgcn_mfma_f32_16x16x32_bf16(a1l, b1, acc, 0, 0, 0);
      float* dstb = (cc < 2) ? T_nxt : D_nxt;
#pragma unroll
      for (int b = 0; b < 4; b++) {
        int gr = nb0 + g * 4 + b;
        if (gr < N) dstb[(size_t)gr * 128 + j] = acc[b];
      }
    }
  }
}

// ---------------- r build: rb(hi/lo) = H0 pair + sum_t tau*dH_t; ts ----------------

__global__ __launch_bounds__(256) void rbuild_kernel(
    const float* __restrict__ H0, const unsigned short* __restrict__ dHall,
    const float* __restrict__ tau, const int* __restrict__ pairs,
    unsigned short* __restrict__ rb_hi, unsigned short* __restrict__ rb_lo,
    float* __restrict__ ts, int P, int N, int Lsteps) {
  int p = blockIdx.x * 16 + (threadIdx.x >> 4);
  int l = threadIdx.x & 15;
  if (p >= P) return;
  int node = (l < 8) ? pairs[2 * p] : pairs[2 * p + 1];
  int d0 = (l & 7) * 8;
  const float* hp = H0 + (size_t)node * 64 + d0;
  float4 h0 = *(const float4*)hp;
  float4 h1 = *(const float4*)(hp + 4);
  float acc[8] = {h0.x, h0.y, h0.z, h0.w, h1.x, h1.y, h1.z, h1.w};
  float tsum = 0.f;
  const unsigned short* dbase = dHall + (size_t)node * (Lsteps * 64) + d0;
  const float* taup = tau + (size_t)p * Lsteps;
#pragma unroll 4
  for (int t = 0; t < Lsteps; t++) {
    float tt = taup[t];
    tsum += tt;
    u16x8 v = *(const u16x8*)(dbase + t * 64);
#pragma unroll
    for (int i = 0; i < 8; i++) acc[i] = fmaf(tt, bf2f(v[i]), acc[i]);
  }
  u16x8 ohi, olo;
#pragma unroll
  for (int i = 0; i < 8; i++) {
    unsigned short hi = f2bf(acc[i]);
    ohi[i] = hi;
    olo[i] = f2bf(acc[i] - bf2f(hi));
  }
  *(u16x8*)(rb_hi + (size_t)p * 128 + l * 8) = ohi;
  *(u16x8*)(rb_lo + (size_t)p * 128 + l * 8) = olo;
  if (l == 0) ts[p] = tsum;
}

// ---------------- final: scores = (relu(rb @ Wp1) @ Wp2), split-A ----------------

__global__ __launch_bounds__(256) void final_gemm(const unsigned short* __restrict__ rb_hi,
                                                  const unsigned short* __restrict__ rb_lo,
                                                  const unsigned short* __restrict__ WT,
                                                  const float* __restrict__ Wp2,
                                                  float* __restrict__ out, int P) {
  int gw = blockIdx.x * 4 + (threadIdx.x >> 6);
  int l = threadIdx.x & 63;
  int r0 = gw * 16;
  if (r0 >= P) return;
  int arow = min(r0 + (l & 15), P - 1);
  int ak = (l >> 4) * 8;
  bf16x8 ah[4], al[4];
#pragma unroll
  for (int kk = 0; kk < 4; kk++) {
    ah[kk] = *(const bf16x8*)(rb_hi + (size_t)arow * 128 + kk * 32 + ak);
    al[kk] = *(const bf16x8*)(rb_lo + (size_t)arow * 128 + kk * 32 + ak);
  }
  float s[4] = {0.f, 0.f, 0.f, 0.f};
#pragma unroll
  for (int c = 0; c < 4; c++) {
    const unsigned short* wp = WT + (size_t)(c * 16 + (l & 15)) * 128 + ak;
    f32x4 acc = {0.f, 0.f, 0.f, 0.f};
#pragma unroll
    for (int kk = 0; kk < 4; kk++) {
      bf16x8 wv = *(const bf16x8*)(wp + kk * 32);
      acc = __builtin_amdgcn_mfma_f32_16x16x32_bf16(ah[kk], wv, acc, 0, 0, 0);
      acc = __builtin_amdgcn_mfma_f32_16x16x32_bf16(al[kk], wv, acc, 0, 0, 0);
    }
    float w = Wp2[c * 16 + (l & 15)];
#pragma unroll
    for (int b = 0; b < 4; b++) s[b] = fmaf(fmaxf(acc[b], 0.f), w, s[b]);
  }
#pragma unroll
  for (int off = 1; off < 16; off <<= 1) {
#pragma unroll
    for (int b = 0; b < 4; b++) s[b] += __shfl_xor(s[b], off, 64);
  }
  if ((l & 15) == 0) {
    int rbase = r0 + (l >> 4) * 4;
#pragma unroll
    for (int b = 0; b < 4; b++) {
      int gr = rbase + b;
      if (gr < P) out[gr] = s[b];
    }
  }
}

// ---------------- launch ----------------

extern "C" void kernel_launch(void* const* d_in, const int* in_sizes, int n_in, void* d_out,
                              int out_size, void* d_ws, size_t ws_size, hipStream_t stream) {
  const float* x = (const float*)d_in[0];
  const int* edge = (const int*)d_in[1];
  const int* pairs = (const int*)d_in[2];
  const float* gumbel = (const float*)d_in[3];
  const float* Wenc = (const float*)d_in[4];
  const float* Om = (const float*)d_in[5];
  const float* Wsr = (const float*)d_in[6];
  const float* Wfc1 = (const float*)d_in[7];
  const float* Wfc2 = (const float*)d_in[8];
  const float* Wfv = (const float*)d_in[9];
  const float* Wp1 = (const float*)d_in[10];
  const float* Wp2 = (const float*)d_in[11];
  const int IN = 128;
  const int N = in_sizes[0] / IN;
  const int E = in_sizes[1] / 2;
  const int P = in_sizes[2] / 2;
  const int L = in_sizes[3] / (2 * P);
  float* out = (float*)d_out;

  char* wsb = (char*)d_ws;
  size_t off = 0;
  auto alloc = [&](size_t bytes) -> char* {
    char* p = wsb + off;
    off = (off + bytes + 255) & ~(size_t)255;
    return p;
  };
  const int NB = (N + 1023) >> 10;
  float* dinv = (float*)alloc((size_t)N * 4);
  int* cnt = (int*)alloc((size_t)N * 4);
  int* colptr = (int*)alloc((size_t)(N + 1) * 4);
  int* bsum = (int*)alloc((size_t)(NB + 1) * 4);
  int* csr = (int*)alloc((size_t)E * 4);
  unsigned short* Wn2T = (unsigned short*)alloc((size_t)128 * 64 * 2);
  unsigned short* Wn2Tlo = (unsigned short*)alloc((size_t)128 * 64 * 2);
  unsigned short* Wfc1T = (unsigned short*)alloc((size_t)128 * 128 * 2);
  unsigned short* WencT = (unsigned short*)alloc((size_t)64 * 128 * 2);
  unsigned short* Wp1T = (unsigned short*)alloc((size_t)64 * 128 * 2);
  float* H = (float*)alloc((size_t)N * 64 * 4);
  float* H0 = (float*)alloc((size_t)N * 64 * 4);
  unsigned short* Hb_hi = (unsigned short*)alloc((size_t)N * 64 * 2);
  unsigned short* Hb_lo = (unsigned short*)alloc((size_t)N * 64 * 2);
  float* A_a = (float*)alloc((size_t)N * 64 * 4);
  float* A_b = (float*)alloc((size_t)N * 64 * 4);
  float* Bs_a = (float*)alloc((size_t)N * 64 * 4);
  float* Bs_b = (float*)alloc((size_t)N * 64 * 4);
  float* T_a = (float*)alloc((size_t)N * 128 * 4);
  float* T_b = (float*)alloc((size_t)N * 128 * 4);
  float* D_a = (float*)alloc((size_t)N * 128 * 4);
  float* D_b = (float*)alloc((size_t)N * 128 * 4);
  float* ftfbA = (float*)alloc((size_t)N * 2 * 4);
  float* ftfbB = (float*)alloc((size_t)N * 2 * 4);
  unsigned short* dHall = (unsigned short*)alloc((size_t)N * L * 64 * 2);
  float* tau = (float*)alloc((size_t)P * L * 4);
  unsigned short* rb_hi = (unsigned short*)alloc((size_t)P * 128 * 2);
  unsigned short* rb_lo = (unsigned short*)alloc((size_t)P * 128 * 2);
  (void)ws_size;
  (void)n_in;
  (void)out_size;

  const int* erow = edge;
  const int* ecol = edge + E;

  hipMemsetAsync(cnt, 0, (size_t)N * 4, stream);
  count_kernel<<<(E + 255) / 256, 256, 0, stream>>>(ecol, E, cnt);
  scan1_kernel<<<NB, 1024, 0, stream>>>(cnt, colptr, dinv, bsum, N);
  scan2_kernel<<<1, 64, 0, stream>>>(bsum, NB);
  scan3_kernel<<<(N + 256) / 256, 256, 0, stream>>>(colptr, bsum, N);
  fill_kernel<<<(E + 255) / 256, 256, 0, stream>>>(erow, ecol, E, colptr, cnt, csr);
  prep_weights<<<(128 * 64 + 128 * 128 + 2 * 64 * 128 + 255) / 256, 256, 0, stream>>>(
      Om, Wsr, Wfc1, Wenc, Wp1, Wn2T, Wn2Tlo, Wfc1T, WencT, Wp1T);

  int nwaves = (N + 15) / 16;
  enc_gemm<<<(nwaves + 3) / 4, 256, 0, stream>>>(x, WencT, H, H0, Hb_hi, Hb_lo, N);
  node_gemm<<<(nwaves + 3) / 4, 256, 0, stream>>>(Hb_hi, Hb_lo, Wn2T, Wn2Tlo, Wfc1T, H, Wfv,
                                                  dinv, A_a, Bs_a, T_a, D_a, ftfbA, N);

  float* A_cur = A_a;   float* A_nxt = A_b;
  float* Bs_cur = Bs_a; float* Bs_nxt = Bs_b;
  float* T_cur = T_a;   float* T_nxt = T_b;
  float* D_cur = D_a;   float* D_nxt = D_b;
  float* ff_cur = ftfbA;
  float* ff_nxt = ftfbB;
  const int PB = (P + 31) / 32;
  const int AGB = (N + 15) / 16;
  for (int t = 0; t < L; t++) {
    step_fused<<<PB + AGB, 256, 0, stream>>>(
        A_cur, Bs_cur, T_cur, D_cur, A_nxt, Bs_nxt, T_nxt, D_nxt, colptr, csr, dinv, H, dHall,
        Wn2T, Wn2Tlo, Wfc1T, Wfc2, ff_cur, ff_nxt, Wfv, pairs, gumbel + (size_t)t * P * 2, tau,
        t, L, N, P, PB);
    { float* tmp = A_cur; A_cur = A_nxt; A_nxt = tmp; }
    { float* tmp = Bs_cur; Bs_cur = Bs_nxt; Bs_nxt = tmp; }
    { float* tmp = T_cur; T_cur = T_nxt; T_nxt = tmp; }
    { float* tmp = D_cur; D_cur = D_nxt; D_nxt = tmp; }
    { float* tmp = ff_cur; ff_cur = ff_nxt; ff_nxt = tmp; }
  }
  rbuild_kernel<<<(P + 15) / 16, 256, 0, stream>>>(H0, dHall, tau, pairs, rb_hi, rb_lo,
                                                   out + P, P, N, L);
  int pwaves = (P + 15) / 16;
  final_gemm<<<(pwaves + 3) / 4, 256, 0, stream>>>(rb_hi, rb_lo, Wp1T, Wp2, out, P);
}

// Round 10
// 908.687 us; speedup vs baseline: 1.3178x; 1.0095x over previous
//
#include <hip/hip_runtime.h>
#include <math.h>

// EELP: 20-step GNN scan. fp32-clean H-recurrence (hi/lo split MFMA, fp32
// A/Bs/H, libm tanh). Per-node T/D (fp32); z = T[src]+D[dst]. Pairs processed
// in src-sorted order (porder) for L2 locality. One fused kernel per step.
// rbuild+final fused: r staged in LDS (bf16 hi/lo), Wp1 MFMA + Wp2 in-block.

typedef short bf16x8 __attribute__((ext_vector_type(8)));
typedef float f32x4 __attribute__((ext_vector_type(4)));
typedef unsigned short u16x8 __attribute__((ext_vector_type(8)));

__device__ __forceinline__ float bf2f(unsigned short u) {
  return __uint_as_float(((unsigned)u) << 16);
}
__device__ __forceinline__ unsigned short f2bf(float f) {
  unsigned u = __float_as_uint(f);
  unsigned r = (u + 0x7FFFu + ((u >> 16) & 1u)) >> 16;
  return (unsigned short)r;
}
__device__ __forceinline__ float softplusf(float x) {
  return x > 20.f ? x : log1pf(expf(x));
}

// ---------------- setup: degree count + 3-phase scan + CSR fill ----------------

__global__ void count_kernel(const int* __restrict__ col, int E, int* __restrict__ cnt) {
  int e = blockIdx.x * blockDim.x + threadIdx.x;
  if (e < E) atomicAdd(&cnt[col[e]], 1);
}

// count pairs by src (stride-2 key array)
__global__ void pcount_kernel(const int* __restrict__ pairs, int P, int* __restrict__ cnt) {
  int p = blockIdx.x * blockDim.x + threadIdx.x;
  if (p < P) atomicAdd(&cnt[pairs[2 * p]], 1);
}

__global__ __launch_bounds__(1024) void scan1_kernel(int* __restrict__ cnt,
                                                     int* __restrict__ colptr,
                                                     float* __restrict__ dinv,
                                                     int* __restrict__ bsum, int N) {
  __shared__ int sh[1024];
  int t = threadIdx.x, b = blockIdx.x;
  int i = b * 1024 + t;
  int v = (i < N) ? cnt[i] : 0;
  sh[t] = v;
  __syncthreads();
  for (int off = 1; off < 1024; off <<= 1) {
    int o = (t >= off) ? sh[t - off] : 0;
    __syncthreads();
    sh[t] += o;
    __syncthreads();
  }
  if (i < N) {
    colptr[i] = sh[t] - v;
    if (dinv) dinv[i] = rsqrtf((float)(v + 1));
    cnt[i] = 0;
  }
  if (t == 1023) bsum[b] = sh[1023];
}

__global__ void scan2_kernel(int* __restrict__ bsum, int B) {
  if (threadIdx.x == 0 && blockIdx.x == 0) {
    int run = 0;
    for (int b = 0; b < B; b++) {
      int x = bsum[b];
      bsum[b] = run;
      run += x;
    }
    bsum[B] = run;
  }
}

__global__ void scan3_kernel(int* __restrict__ colptr, const int* __restrict__ bsum, int N) {
  int i = blockIdx.x * blockDim.x + threadIdx.x;
  if (i < N) colptr[i] += bsum[i >> 10];
  if (i == N) colptr[N] = bsum[(N + 1023) >> 10];
}

__global__ void fill_kernel(const int* __restrict__ row, const int* __restrict__ col, int E,
                            const int* __restrict__ colptr, int* __restrict__ cur,
                            int* __restrict__ csr) {
  int e = blockIdx.x * blockDim.x + threadIdx.x;
  if (e < E) {
    int c = col[e];
    int pos = colptr[c] + atomicAdd(&cur[c], 1);
    csr[pos] = row[e];
  }
}

__global__ void pfill_kernel(const int* __restrict__ pairs, int P,
                             const int* __restrict__ pptr, int* __restrict__ pcur,
                             int* __restrict__ porder) {
  int p = blockIdx.x * blockDim.x + threadIdx.x;
  if (p < P) {
    int s = pairs[2 * p];
    int pos = pptr[s] + atomicAdd(&pcur[s], 1);
    porder[pos] = p;
  }
}

// Transposed bf16 weights (row j = output col, col k = input dim)

__global__ void prep_weights(const float* __restrict__ Om, const float* __restrict__ Wsr,
                             const float* __restrict__ Wfc1, const float* __restrict__ Wenc,
                             const float* __restrict__ Wp1, unsigned short* __restrict__ Wn2T,
                             unsigned short* __restrict__ Wn2Tlo,
                             unsigned short* __restrict__ Wfc1T,
                             unsigned short* __restrict__ WencT,
                             unsigned short* __restrict__ Wp1T) {
  int idx = blockIdx.x * blockDim.x + threadIdx.x;
  if (idx < 128 * 64) {
    int j = idx / 64, k = idx % 64;
    float v;
    if (j < 64) {
      v = Om[k * 64 + j] - Om[j * 64 + k];
    } else {
      int jj = j - 64;
      v = 0.5f * (Wsr[k * 64 + jj] + Wsr[jj * 64 + k]);
    }
    unsigned short hi = f2bf(v);
    Wn2T[idx] = hi;
    Wn2Tlo[idx] = f2bf(v - bf2f(hi));
  } else if (idx < 128 * 64 + 128 * 128) {
    int t = idx - 128 * 64;
    int j = t / 128, k = t % 128;
    Wfc1T[t] = f2bf(Wfc1[k * 128 + j]);
  } else if (idx < 128 * 64 + 128 * 128 + 64 * 128) {
    int t = idx - 128 * 64 - 128 * 128;
    int j = t / 128, k = t % 128;
    WencT[t] = f2bf(Wenc[k * 64 + j]);
  } else if (idx < 128 * 64 + 128 * 128 + 2 * 64 * 128) {
    int t = idx - 128 * 64 - 128 * 128 - 64 * 128;
    int j = t / 128, k = t % 128;
    Wp1T[t] = f2bf(Wp1[k * 64 + j]);
  }
}

// ---------------- encoder GEMM: H = relu(x @ Wenc), K=128 ----------------

__global__ __launch_bounds__(256) void enc_gemm(const float* __restrict__ X,
                                                const unsigned short* __restrict__ WT,
                                                float* __restrict__ H, float* __restrict__ H0,
                                                unsigned short* __restrict__ Hb_hi,
                                                unsigned short* __restrict__ Hb_lo, int N) {
  int gw = blockIdx.x * 4 + (threadIdx.x >> 6);
  int l = threadIdx.x & 63;
  int r0 = gw * 16;
  if (r0 >= N) return;
  int arow = min(r0 + (l & 15), N - 1);
  int ak = (l >> 4) * 8;
  bf16x8 a[4];
#pragma unroll
  for (int kk = 0; kk < 4; kk++) {
    const float* xp = X + (size_t)arow * 128 + kk * 32 + ak;
    float4 u = *(const float4*)xp;
    float4 v = *(const float4*)(xp + 4);
    bf16x8 t;
    t[0] = (short)f2bf(u.x); t[1] = (short)f2bf(u.y);
    t[2] = (short)f2bf(u.z); t[3] = (short)f2bf(u.w);
    t[4] = (short)f2bf(v.x); t[5] = (short)f2bf(v.y);
    t[6] = (short)f2bf(v.z); t[7] = (short)f2bf(v.w);
    a[kk] = t;
  }
  int rbase = r0 + (l >> 4) * 4;
#pragma unroll
  for (int c = 0; c < 4; c++) {
    const unsigned short* wp = WT + (size_t)(c * 16 + (l & 15)) * 128 + ak;
    f32x4 acc = {0.f, 0.f, 0.f, 0.f};
#pragma unroll
    for (int kk = 0; kk < 4; kk++)
      acc = __builtin_amdgcn_mfma_f32_16x16x32_bf16(a[kk], *(const bf16x8*)(wp + kk * 32), acc,
                                                    0, 0, 0);
    int gcol = c * 16 + (l & 15);
#pragma unroll
    for (int b = 0; b < 4; b++) {
      int gr = rbase + b;
      if (gr < N) {
        float v = fmaxf(acc[b], 0.f);
        H[(size_t)gr * 64 + gcol] = v;
        H0[(size_t)gr * 64 + gcol] = v;
        unsigned short hi = f2bf(v);
        Hb_hi[(size_t)gr * 64 + gcol] = hi;
        Hb_lo[(size_t)gr * 64 + gcol] = f2bf(v - bf2f(hi));
      }
    }
  }
}

// ---------------- bootstrap node GEMM (t=0): A, Bs, T, D + ftfb ----------------

__global__ __launch_bounds__(256) void node_gemm(
    const unsigned short* __restrict__ Hb_hi, const unsigned short* __restrict__ Hb_lo,
    const unsigned short* __restrict__ Wn2T, const unsigned short* __restrict__ Wn2Tlo,
    const unsigned short* __restrict__ Wfc1T, const float* __restrict__ H,
    const float* __restrict__ Wfv, const float* __restrict__ dinv, float* __restrict__ Abuf,
    float* __restrict__ Bsbuf, float* __restrict__ Tbuf, float* __restrict__ Dbuf,
    float* __restrict__ ftfb, int N) {
  int gw = blockIdx.x * 4 + (threadIdx.x >> 6);
  int l = threadIdx.x & 63;
  int r0 = gw * 16;
  if (r0 >= N) return;
  int arow = min(r0 + (l & 15), N - 1);
  int ak = (l >> 4) * 8;
  bf16x8 a0h = *(const bf16x8*)(Hb_hi + (size_t)arow * 64 + ak);
  bf16x8 a1h = *(const bf16x8*)(Hb_hi + (size_t)arow * 64 + 32 + ak);
  bf16x8 a0l = *(const bf16x8*)(Hb_lo + (size_t)arow * 64 + ak);
  bf16x8 a1l = *(const bf16x8*)(Hb_lo + (size_t)arow * 64 + 32 + ak);
  int rbase = r0 + (l >> 4) * 4;
  float dv[4];
#pragma unroll
  for (int b = 0; b < 4; b++) dv[b] = dinv[min(rbase + b, N - 1)];
#pragma unroll
  for (int c = 0; c < 8; c++) {
    size_t woff = (size_t)(c * 16 + (l & 15)) * 64 + ak;
    bf16x8 b0h = *(const bf16x8*)(Wn2T + woff);
    bf16x8 b1h = *(const bf16x8*)(Wn2T + woff + 32);
    bf16x8 b0l = *(const bf16x8*)(Wn2Tlo + woff);
    bf16x8 b1l = *(const bf16x8*)(Wn2Tlo + woff + 32);
    f32x4 acc = {0.f, 0.f, 0.f, 0.f};
    acc = __builtin_amdgcn_mfma_f32_16x16x32_bf16(a0h, b0h, acc, 0, 0, 0);
    acc = __builtin_amdgcn_mfma_f32_16x16x32_bf16(a1h, b1h, acc, 0, 0, 0);
    acc = __builtin_amdgcn_mfma_f32_16x16x32_bf16(a0l, b0h, acc, 0, 0, 0);
    acc = __builtin_amdgcn_mfma_f32_16x16x32_bf16(a1l, b1h, acc, 0, 0, 0);
    acc = __builtin_amdgcn_mfma_f32_16x16x32_bf16(a0h, b0l, acc, 0, 0, 0);
    acc = __builtin_amdgcn_mfma_f32_16x16x32_bf16(a1h, b1l, acc, 0, 0, 0);
    int gcol = c * 16 + (l & 15);
#pragma unroll
    for (int b = 0; b < 4; b++) {
      int gr = rbase + b;
      if (gr < N) {
        float v = acc[b];
        if (c >= 4) Bsbuf[(size_t)gr * 64 + (gcol - 64)] = v * dv[b];
        else Abuf[(size_t)gr * 64 + gcol] = v;
      }
    }
  }
#pragma unroll
  for (int c = 0; c < 16; c++) {
    int j = ((c & 7) * 16 + (l & 15));
    int koff = (c < 8) ? 0 : 64;
    const unsigned short* wp = Wfc1T + (size_t)j * 128 + koff + ak;
    bf16x8 b0 = *(const bf16x8*)(wp);
    bf16x8 b1 = *(const bf16x8*)(wp + 32);
    f32x4 acc = {0.f, 0.f, 0.f, 0.f};
    acc = __builtin_amdgcn_mfma_f32_16x16x32_bf16(a0h, b0, acc, 0, 0, 0);
    acc = __builtin_amdgcn_mfma_f32_16x16x32_bf16(a1h, b1, acc, 0, 0, 0);
    acc = __builtin_amdgcn_mfma_f32_16x16x32_bf16(a0l, b0, acc, 0, 0, 0);
    acc = __builtin_amdgcn_mfma_f32_16x16x32_bf16(a1l, b1, acc, 0, 0, 0);
    float* dstb = (c < 8) ? Tbuf : Dbuf;
#pragma unroll
    for (int b = 0; b < 4; b++) {
      int gr = rbase + b;
      if (gr < N) dstb[(size_t)gr * 128 + j] = acc[b];
    }
  }
  int d0 = (l >> 4) * 16;
  const float* hp = H + (size_t)arow * 64 + d0;
  float p0 = 0.f, p1 = 0.f;
#pragma unroll
  for (int i = 0; i < 16; i += 4) {
    float4 h = *(const float4*)(hp + i);
    p0 += h.x * Wfv[d0 + i] + h.y * Wfv[d0 + i + 1] + h.z * Wfv[d0 + i + 2] +
          h.w * Wfv[d0 + i + 3];
    p1 += h.x * Wfv[64 + d0 + i] + h.y * Wfv[64 + d0 + i + 1] + h.z * Wfv[64 + d0 + i + 2] +
          h.w * Wfv[64 + d0 + i + 3];
  }
  p0 += __shfl_xor(p0, 16, 64);
  p0 += __shfl_xor(p0, 32, 64);
  p1 += __shfl_xor(p1, 16, 64);
  p1 += __shfl_xor(p1, 32, 64);
  if (l < 16 && r0 + l < N) {
    ftfb[2 * (r0 + l)] = p0;
    ftfb[2 * (r0 + l) + 1] = p1;
  }
}

// ---------------- fused step: [pair tau (src-sorted) | aggregate + next node-GEMM] --------

__global__ __launch_bounds__(256) void step_fused(
    const float* __restrict__ A_cur, const float* __restrict__ Bs_cur,
    const float* __restrict__ T_cur, const float* __restrict__ D_cur,
    float* __restrict__ A_nxt, float* __restrict__ Bs_nxt, float* __restrict__ T_nxt,
    float* __restrict__ D_nxt, const int* __restrict__ colptr, const int* __restrict__ csr,
    const float* __restrict__ dinv, float* __restrict__ H, unsigned short* __restrict__ dHall,
    const unsigned short* __restrict__ Wn2T, const unsigned short* __restrict__ Wn2Tlo,
    const unsigned short* __restrict__ Wfc1T, const float* __restrict__ Wfc2,
    const float* __restrict__ ftfb_cur, float* __restrict__ ftfb_nxt,
    const float* __restrict__ Wfv, const int* __restrict__ pairs,
    const int* __restrict__ porder, const float* __restrict__ gum, float* __restrict__ tau,
    int t, int LT, int N, int P, int PB) {
  __shared__ unsigned short ldsHi[16 * 72];
  __shared__ unsigned short ldsLo[16 * 72];
  int l = threadIdx.x & 63;
  int w = threadIdx.x >> 6;
  if ((int)blockIdx.x < PB) {
    // ---- pair: z = T[src]+D[dst], logits via Wfc2, tau; src-sorted order ----
    int idx = (int)blockIdx.x * 32 + w * 8 + (l >> 3);
    bool act = idx < P;
    int p = porder[act ? idx : P - 1];
    int src = pairs[2 * p], dst = pairs[2 * p + 1];
    int d0 = (l & 7) * 16;
    const float* Tp = T_cur + (size_t)src * 128 + d0;
    const float* Dp = D_cur + (size_t)dst * 128 + d0;
    float l0 = 0.f, l1 = 0.f;
#pragma unroll
    for (int i = 0; i < 16; i += 4) {
      float4 tv = *(const float4*)(Tp + i);
      float4 dv4 = *(const float4*)(Dp + i);
      float z0 = fmaxf(tv.x + dv4.x, 0.f);
      float z1 = fmaxf(tv.y + dv4.y, 0.f);
      float z2 = fmaxf(tv.z + dv4.z, 0.f);
      float z3 = fmaxf(tv.w + dv4.w, 0.f);
      int m = d0 + i;
      l0 = fmaf(z0, Wfc2[2 * m], l0);
      l1 = fmaf(z0, Wfc2[2 * m + 1], l1);
      l0 = fmaf(z1, Wfc2[2 * m + 2], l0);
      l1 = fmaf(z1, Wfc2[2 * m + 3], l1);
      l0 = fmaf(z2, Wfc2[2 * m + 4], l0);
      l1 = fmaf(z2, Wfc2[2 * m + 5], l1);
      l0 = fmaf(z3, Wfc2[2 * m + 6], l0);
      l1 = fmaf(z3, Wfc2[2 * m + 7], l1);
    }
#pragma unroll
    for (int off = 1; off < 8; off <<= 1) {
      l0 += __shfl_xor(l0, off, 64);
      l1 += __shfl_xor(l1, off, 64);
    }
    if ((l & 7) == 0 && act) {
      float nu = softplusf(ftfb_cur[2 * src] + ftfb_cur[2 * dst + 1]) + 1.0f;
      float g0 = gum[2 * (size_t)p], g1 = gum[2 * (size_t)p + 1];
      float dlt = ((l1 + g1) - (l0 + g0)) / nu;
      tau[(size_t)p * LT + t] = 1.0f / (1.0f + expf(dlt));
    }
  } else {
    // ---- aggregate + H update + next-step node GEMM (16 nodes/block) ----
    int nb0 = ((int)blockIdx.x - PB) * 16;
    int g = l >> 4;
    int node = nb0 + w * 4 + g;
    int q = (l & 15) * 4;
    bool valid = node < N;
    float4 hn = make_float4(0.f, 0.f, 0.f, 0.f);
    if (valid) {
      size_t base = (size_t)node * 64 + q;
      float4 v = *(const float4*)(Bs_cur + base);
      float aa0 = v.x, aa1 = v.y, aa2 = v.z, aa3 = v.w;
      int beg = colptr[node], end = colptr[node + 1];
      int i = beg;
      for (; i + 3 < end; i += 4) {
        int n0 = csr[i], n1 = csr[i + 1], n2 = csr[i + 2], n3 = csr[i + 3];
        float4 u0 = *(const float4*)(Bs_cur + (size_t)n0 * 64 + q);
        float4 u1 = *(const float4*)(Bs_cur + (size_t)n1 * 64 + q);
        float4 u2 = *(const float4*)(Bs_cur + (size_t)n2 * 64 + q);
        float4 u3 = *(const float4*)(Bs_cur + (size_t)n3 * 64 + q);
        aa0 += (u0.x + u1.x) + (u2.x + u3.x);
        aa1 += (u0.y + u1.y) + (u2.y + u3.y);
        aa2 += (u0.z + u1.z) + (u2.z + u3.z);
        aa3 += (u0.w + u1.w) + (u2.w + u3.w);
      }
      for (; i < end; i++) {
        int n0 = csr[i];
        float4 u0 = *(const float4*)(Bs_cur + (size_t)n0 * 64 + q);
        aa0 += u0.x; aa1 += u0.y; aa2 += u0.z; aa3 += u0.w;
      }
      float dval = dinv[node];
      float4 av = *(const float4*)(A_cur + base);
      float dh0 = fmaxf(tanhf(dval * aa0 - fmaxf(av.x, 0.f)), 0.f);
      float dh1 = fmaxf(tanhf(dval * aa1 - fmaxf(av.y, 0.f)), 0.f);
      float dh2 = fmaxf(tanhf(dval * aa2 - fmaxf(av.z, 0.f)), 0.f);
      float dh3 = fmaxf(tanhf(dval * aa3 - fmaxf(av.w, 0.f)), 0.f);
      ushort4 od;
      od.x = f2bf(dh0); od.y = f2bf(dh1); od.z = f2bf(dh2); od.w = f2bf(dh3);
      *(ushort4*)(dHall + (size_t)node * (LT * 64) + t * 64 + q) = od;
      float* hp = H + base;
      float4 h = *(const float4*)hp;
      hn.x = h.x + dh0; hn.y = h.y + dh1; hn.z = h.z + dh2; hn.w = h.w + dh3;
      *(float4*)hp = hn;
    }
    ushort4 whi, wlo;
    whi.x = f2bf(hn.x); wlo.x = f2bf(hn.x - bf2f(whi.x));
    whi.y = f2bf(hn.y); wlo.y = f2bf(hn.y - bf2f(whi.y));
    whi.z = f2bf(hn.z); wlo.z = f2bf(hn.z - bf2f(whi.z));
    whi.w = f2bf(hn.w); wlo.w = f2bf(hn.w - bf2f(whi.w));
    int r = w * 4 + g;
    *(ushort4*)(ldsHi + r * 72 + q) = whi;
    *(ushort4*)(ldsLo + r * 72 + q) = wlo;
    float p0 = hn.x * Wfv[q] + hn.y * Wfv[q + 1] + hn.z * Wfv[q + 2] + hn.w * Wfv[q + 3];
    float p1 = hn.x * Wfv[64 + q] + hn.y * Wfv[64 + q + 1] + hn.z * Wfv[64 + q + 2] +
               hn.w * Wfv[64 + q + 3];
#pragma unroll
    for (int off = 1; off < 16; off <<= 1) {
      p0 += __shfl_xor(p0, off, 64);
      p1 += __shfl_xor(p1, off, 64);
    }
    if ((l & 15) == 0 && valid) {
      ftfb_nxt[2 * node] = p0;
      ftfb_nxt[2 * node + 1] = p1;
    }
    __syncthreads();
    int rowA = l & 15;
    int ak = g * 8;
    bf16x8 a0h = *(const bf16x8*)(ldsHi + rowA * 72 + ak);
    bf16x8 a1h = *(const bf16x8*)(ldsHi + rowA * 72 + 32 + ak);
    bf16x8 a0l = *(const bf16x8*)(ldsLo + rowA * 72 + ak);
    bf16x8 a1l = *(const bf16x8*)(ldsLo + rowA * 72 + 32 + ak);
    float dv[4];
#pragma unroll
    for (int b = 0; b < 4; b++) dv[b] = dinv[min(nb0 + g * 4 + b, N - 1)];
#pragma unroll
    for (int cc = 0; cc < 2; cc++) {
      int c = cc * 4 + w;
      size_t woff = (size_t)(c * 16 + rowA) * 64 + ak;
      bf16x8 b0h = *(const bf16x8*)(Wn2T + woff);
      bf16x8 b1h = *(const bf16x8*)(Wn2T + woff + 32);
      bf16x8 b0l = *(const bf16x8*)(Wn2Tlo + woff);
      bf16x8 b1l = *(const bf16x8*)(Wn2Tlo + woff + 32);
      f32x4 acc = {0.f, 0.f, 0.f, 0.f};
      acc = __builtin_amdgcn_mfma_f32_16x16x32_bf16(a0h, b0h, acc, 0, 0, 0);
      acc = __builtin_amdgcn_mfma_f32_16x16x32_bf16(a1h, b1h, acc, 0, 0, 0);
      acc = __builtin_amdgcn_mfma_f32_16x16x32_bf16(a0l, b0h, acc, 0, 0, 0);
      acc = __builtin_amdgcn_mfma_f32_16x16x32_bf16(a1l, b1h, acc, 0, 0, 0);
      acc = __builtin_amdgcn_mfma_f32_16x16x32_bf16(a0h, b0l, acc, 0, 0, 0);
      acc = __builtin_amdgcn_mfma_f32_16x16x32_bf16(a1h, b1l, acc, 0, 0, 0);
      int gcol = c * 16 + rowA;
#pragma unroll
      for (int b = 0; b < 4; b++) {
        int gr = nb0 + g * 4 + b;
        if (gr < N) {
          float v = acc[b];
          if (cc == 1) Bs_nxt[(size_t)gr * 64 + (gcol - 64)] = v * dv[b];
          else A_nxt[(size_t)gr * 64 + gcol] = v;
        }
      }
    }
#pragma unroll
    for (int cc = 0; cc < 4; cc++) {
      int jb = (cc & 1) + 2 * w;
      int koff = (cc < 2) ? 0 : 64;
      int j = jb * 16 + rowA;
      const unsigned short* wp = Wfc1T + (size_t)j * 128 + koff + ak;
      bf16x8 b0 = *(const bf16x8*)(wp);
      bf16x8 b1 = *(const bf16x8*)(wp + 32);
      f32x4 acc = {0.f, 0.f, 0.f, 0.f};
      acc = __builtin_amdgcn_mfma_f32_16x16x32_bf16(a0h, b0, acc, 0, 0, 0);
      acc = __builtin_amdgcn_mfma_f32_16x16x32_bf16(a1h, b1, acc, 0, 0, 0);
      acc = __builtin_amdgcn_mfma_f32_16x16x32_bf16(a0l, b0, acc, 0, 0, 0);
      acc = __builtin_amdgcn_mfma_f32_16x16x32_bf16(a1l, b1, acc, 0, 0, 0);
      float* dstb = (cc < 2) ? T_nxt : D_nxt;
#pragma unroll
      for (int b = 0; b < 4; b++) {
        int gr = nb0 + g * 4 + b;
        if (gr < N) dstb[(size_t)gr * 128 + j] = acc[b];
      }
    }
  }
}

// ---------------- fused rbuild + final: scores + ts, src-sorted order ----------------
// block = 256 thr = 16 pairs. Phase1: acc r rows, stage bf16 hi/lo in LDS.
// Phase2: 4 waves x 16-col blocks of relu(r@Wp1), dot Wp2, cross-wave reduce.

__global__ __launch_bounds__(256) void rbuild_final(
    const float* __restrict__ H0, const unsigned short* __restrict__ dHall,
    const float* __restrict__ tau, const int* __restrict__ pairs,
    const int* __restrict__ porder, const unsigned short* __restrict__ Wp1T,
    const float* __restrict__ Wp2, float* __restrict__ out, float* __restrict__ ts, int P,
    int N, int Lsteps) {
  __shared__ unsigned short sHi[16 * 136];
  __shared__ unsigned short sLo[16 * 136];
  __shared__ float sS[4][16];
  __shared__ int sP[16];
  __shared__ int sV[16];
  int pr = threadIdx.x >> 4;   // pair row 0..15
  int l16 = threadIdx.x & 15;
  int i0 = (int)blockIdx.x * 16;
  bool act = (i0 + pr) < P;
  int p = porder[act ? (i0 + pr) : P - 1];
  if (l16 == 0) {
    sP[pr] = p;
    sV[pr] = act ? 1 : 0;
  }
  int node = (l16 < 8) ? pairs[2 * p] : pairs[2 * p + 1];
  int d0 = (l16 & 7) * 8;
  const float* hp = H0 + (size_t)node * 64 + d0;
  float4 h0 = *(const float4*)hp;
  float4 h1 = *(const float4*)(hp + 4);
  float acc[8] = {h0.x, h0.y, h0.z, h0.w, h1.x, h1.y, h1.z, h1.w};
  float tsum = 0.f;
  const unsigned short* dbase = dHall + (size_t)node * (Lsteps * 64) + d0;
  const float* taup = tau + (size_t)p * Lsteps;
#pragma unroll 4
  for (int t = 0; t < Lsteps; t++) {
    float tt = taup[t];
    tsum += tt;
    u16x8 v = *(const u16x8*)(dbase + t * 64);
#pragma unroll
    for (int i = 0; i < 8; i++) acc[i] = fmaf(tt, bf2f(v[i]), acc[i]);
  }
  u16x8 ohi, olo;
#pragma unroll
  for (int i = 0; i < 8; i++) {
    unsigned short hi = f2bf(acc[i]);
    ohi[i] = hi;
    olo[i] = f2bf(acc[i] - bf2f(hi));
  }
  *(u16x8*)(sHi + pr * 136 + l16 * 8) = ohi;
  *(u16x8*)(sLo + pr * 136 + l16 * 8) = olo;
  if (l16 == 0 && act) ts[p] = tsum;
  __syncthreads();
  // phase 2: wave w handles col block w (cols w*16 .. +16)
  int w = threadIdx.x >> 6;
  int l = threadIdx.x & 63;
  int rowA = l & 15;
  int ak = (l >> 4) * 8;
  bf16x8 ah[4], al[4];
#pragma unroll
  for (int kk = 0; kk < 4; kk++) {
    ah[kk] = *(const bf16x8*)(sHi + rowA * 136 + kk * 32 + ak);
    al[kk] = *(const bf16x8*)(sLo + rowA * 136 + kk * 32 + ak);
  }
  const unsigned short* wp = Wp1T + (size_t)(w * 16 + rowA) * 128 + ak;
  f32x4 macc = {0.f, 0.f, 0.f, 0.f};
#pragma unroll
  for (int kk = 0; kk < 4; kk++) {
    bf16x8 wv = *(const bf16x8*)(wp + kk * 32);
    macc = __builtin_amdgcn_mfma_f32_16x16x32_bf16(ah[kk], wv, macc, 0, 0, 0);
    macc = __builtin_amdgcn_mfma_f32_16x16x32_bf16(al[kk], wv, macc, 0, 0, 0);
  }
  float wcol = Wp2[w * 16 + rowA];
  float s[4];
#pragma unroll
  for (int b = 0; b < 4; b++) s[b] = fmaxf(macc[b], 0.f) * wcol;
#pragma unroll
  for (int off = 1; off < 16; off <<= 1) {
#pragma unroll
    for (int b = 0; b < 4; b++) s[b] += __shfl_xor(s[b], off, 64);
  }
  if ((l & 15) == 0) {
#pragma unroll
    for (int b = 0; b < 4; b++) sS[w][(l >> 4) * 4 + b] = s[b];
  }
  __syncthreads();
  if (threadIdx.x < 16) {
    int row = threadIdx.x;
    float sum = sS[0][row] + sS[1][row] + sS[2][row] + sS[3][row];
    if (sV[row]) out[sP[row]] = sum;
  }
}

// ---------------- launch ----------------

extern "C" void kernel_launch(void* const* d_in, const int* in_sizes, int n_in, void* d_out,
                              int out_size, void* d_ws, size_t ws_size, hipStream_t stream) {
  const float* x = (const float*)d_in[0];
  const int* edge = (const int*)d_in[1];
  const int* pairs = (const int*)d_in[2];
  const float* gumbel = (const float*)d_in[3];
  const float* Wenc = (const float*)d_in[4];
  const float* Om = (const float*)d_in[5];
  const float* Wsr = (const float*)d_in[6];
  const float* Wfc1 = (const float*)d_in[7];
  const float* Wfc2 = (const float*)d_in[8];
  const float* Wfv = (const float*)d_in[9];
  const float* Wp1 = (const float*)d_in[10];
  const float* Wp2 = (const float*)d_in[11];
  const int IN = 128;
  const int N = in_sizes[0] / IN;
  const int E = in_sizes[1] / 2;
  const int P = in_sizes[2] / 2;
  const int L = in_sizes[3] / (2 * P);
  float* out = (float*)d_out;

  char* wsb = (char*)d_ws;
  size_t off = 0;
  auto alloc = [&](size_t bytes) -> char* {
    char* p = wsb + off;
    off = (off + bytes + 255) & ~(size_t)255;
    return p;
  };
  const int NB = (N + 1023) >> 10;
  float* dinv = (float*)alloc((size_t)N * 4);
  int* cnt = (int*)alloc((size_t)N * 4);
  int* colptr = (int*)alloc((size_t)(N + 1) * 4);
  int* bsum = (int*)alloc((size_t)(NB + 1) * 4);
  int* csr = (int*)alloc((size_t)E * 4);
  int* pcnt = (int*)alloc((size_t)N * 4);
  int* pptr = (int*)alloc((size_t)(N + 1) * 4);
  int* pbsum = (int*)alloc((size_t)(NB + 1) * 4);
  int* porder = (int*)alloc((size_t)P * 4);
  unsigned short* Wn2T = (unsigned short*)alloc((size_t)128 * 64 * 2);
  unsigned short* Wn2Tlo = (unsigned short*)alloc((size_t)128 * 64 * 2);
  unsigned short* Wfc1T = (unsigned short*)alloc((size_t)128 * 128 * 2);
  unsigned short* WencT = (unsigned short*)alloc((size_t)64 * 128 * 2);
  unsigned short* Wp1T = (unsigned short*)alloc((size_t)64 * 128 * 2);
  float* H = (float*)alloc((size_t)N * 64 * 4);
  float* H0 = (float*)alloc((size_t)N * 64 * 4);
  unsigned short* Hb_hi = (unsigned short*)alloc((size_t)N * 64 * 2);
  unsigned short* Hb_lo = (unsigned short*)alloc((size_t)N * 64 * 2);
  float* A_a = (float*)alloc((size_t)N * 64 * 4);
  float* A_b = (float*)alloc((size_t)N * 64 * 4);
  float* Bs_a = (float*)alloc((size_t)N * 64 * 4);
  float* Bs_b = (float*)alloc((size_t)N * 64 * 4);
  float* T_a = (float*)alloc((size_t)N * 128 * 4);
  float* T_b = (float*)alloc((size_t)N * 128 * 4);
  float* D_a = (float*)alloc((size_t)N * 128 * 4);
  float* D_b = (float*)alloc((size_t)N * 128 * 4);
  float* ftfbA = (float*)alloc((size_t)N * 2 * 4);
  float* ftfbB = (float*)alloc((size_t)N * 2 * 4);
  unsigned short* dHall = (unsigned short*)alloc((size_t)N * L * 64 * 2);
  float* tau = (float*)alloc((size_t)P * L * 4);
  (void)ws_size;
  (void)n_in;
  (void)out_size;

  const int* erow = edge;
  const int* ecol = edge + E;

  hipMemsetAsync(cnt, 0, (size_t)N * 4, stream);
  hipMemsetAsync(pcnt, 0, (size_t)N * 4, stream);
  count_kernel<<<(E + 255) / 256, 256, 0, stream>>>(ecol, E, cnt);
  pcount_kernel<<<(P + 255) / 256, 256, 0, stream>>>(pairs, P, pcnt);
  scan1_kernel<<<NB, 1024, 0, stream>>>(cnt, colptr, dinv, bsum, N);
  scan1_kernel<<<NB, 1024, 0, stream>>>(pcnt, pptr, nullptr, pbsum, N);
  scan2_kernel<<<1, 64, 0, stream>>>(bsum, NB);
  scan2_kernel<<<1, 64, 0, stream>>>(pbsum, NB);
  scan3_kernel<<<(N + 256) / 256, 256, 0, stream>>>(colptr, bsum, N);
  scan3_kernel<<<(N + 256) / 256, 256, 0, stream>>>(pptr, pbsum, N);
  fill_kernel<<<(E + 255) / 256, 256, 0, stream>>>(erow, ecol, E, colptr, cnt, csr);
  pfill_kernel<<<(P + 255) / 256, 256, 0, stream>>>(pairs, P, pptr, pcnt, porder);
  prep_weights<<<(128 * 64 + 128 * 128 + 2 * 64 * 128 + 255) / 256, 256, 0, stream>>>(
      Om, Wsr, Wfc1, Wenc, Wp1, Wn2T, Wn2Tlo, Wfc1T, WencT, Wp1T);

  int nwaves = (N + 15) / 16;
  enc_gemm<<<(nwaves + 3) / 4, 256, 0, stream>>>(x, WencT, H, H0, Hb_hi, Hb_lo, N);
  node_gemm<<<(nwaves + 3) / 4, 256, 0, stream>>>(Hb_hi, Hb_lo, Wn2T, Wn2Tlo, Wfc1T, H, Wfv,
                                                  dinv, A_a, Bs_a, T_a, D_a, ftfbA, N);

  float* A_cur = A_a;   float* A_nxt = A_b;
  float* Bs_cur = Bs_a; float* Bs_nxt = Bs_b;
  float* T_cur = T_a;   float* T_nxt = T_b;
  float* D_cur = D_a;   float* D_nxt = D_b;
  float* ff_cur = ftfbA;
  float* ff_nxt = ftfbB;
  const int PB = (P + 31) / 32;
  const int AGB = (N + 15) / 16;
  for (int t = 0; t < L; t++) {
    step_fused<<<PB + AGB, 256, 0, stream>>>(
        A_cur, Bs_cur, T_cur, D_cur, A_nxt, Bs_nxt, T_nxt, D_nxt, colptr, csr, dinv, H, dHall,
        Wn2T, Wn2Tlo, Wfc1T, Wfc2, ff_cur, ff_nxt, Wfv, pairs, porder,
        gumbel + (size_t)t * P * 2, tau, t, L, N, P, PB);
    { float* tmp = A_cur; A_cur = A_nxt; A_nxt = tmp; }
    { float* tmp = Bs_cur; Bs_cur = Bs_nxt; Bs_nxt = tmp; }
    { float* tmp = T_cur; T_cur = T_nxt; T_nxt = tmp; }
    { float* tmp = D_cur; D_cur = D_nxt; D_nxt = tmp; }
    { float* tmp = ff_cur; ff_cur = ff_nxt; ff_nxt = tmp; }
  }
  rbuild_final<<<(P + 15) / 16, 256, 0, stream>>>(H0, dHall, tau, pairs, porder, Wp1T, Wp2,
                                                  out, out + P, P, N, L);
}

// Round 11
// 887.326 us; speedup vs baseline: 1.3495x; 1.0241x over previous
//
#include <hip/hip_runtime.h>
#include <math.h>

// EELP: 20-step GNN scan. fp32-clean H-recurrence (hi/lo split MFMA, fp32
// A/Bs/H, libm tanh). Per-node T/D (fp32); z = T[src]+D[dst]. Pairs processed
// in src-sorted order (porder). One fused kernel per step. rbuild+final fused.
// MLP tuning: 8-wide gather rounds in agg, 10-wide unroll in rbuild.

typedef short bf16x8 __attribute__((ext_vector_type(8)));
typedef float f32x4 __attribute__((ext_vector_type(4)));
typedef unsigned short u16x8 __attribute__((ext_vector_type(8)));

__device__ __forceinline__ float bf2f(unsigned short u) {
  return __uint_as_float(((unsigned)u) << 16);
}
__device__ __forceinline__ unsigned short f2bf(float f) {
  unsigned u = __float_as_uint(f);
  unsigned r = (u + 0x7FFFu + ((u >> 16) & 1u)) >> 16;
  return (unsigned short)r;
}
__device__ __forceinline__ float softplusf(float x) {
  return x > 20.f ? x : log1pf(expf(x));
}

// ---------------- setup: degree count + 3-phase scan + CSR fill ----------------

__global__ void count_kernel(const int* __restrict__ col, int E, int* __restrict__ cnt) {
  int e = blockIdx.x * blockDim.x + threadIdx.x;
  if (e < E) atomicAdd(&cnt[col[e]], 1);
}

__global__ void pcount_kernel(const int* __restrict__ pairs, int P, int* __restrict__ cnt) {
  int p = blockIdx.x * blockDim.x + threadIdx.x;
  if (p < P) atomicAdd(&cnt[pairs[2 * p]], 1);
}

__global__ __launch_bounds__(1024) void scan1_kernel(int* __restrict__ cnt,
                                                     int* __restrict__ colptr,
                                                     float* __restrict__ dinv,
                                                     int* __restrict__ bsum, int N) {
  __shared__ int sh[1024];
  int t = threadIdx.x, b = blockIdx.x;
  int i = b * 1024 + t;
  int v = (i < N) ? cnt[i] : 0;
  sh[t] = v;
  __syncthreads();
  for (int off = 1; off < 1024; off <<= 1) {
    int o = (t >= off) ? sh[t - off] : 0;
    __syncthreads();
    sh[t] += o;
    __syncthreads();
  }
  if (i < N) {
    colptr[i] = sh[t] - v;
    if (dinv) dinv[i] = rsqrtf((float)(v + 1));
    cnt[i] = 0;
  }
  if (t == 1023) bsum[b] = sh[1023];
}

__global__ void scan2_kernel(int* __restrict__ bsum, int B) {
  if (threadIdx.x == 0 && blockIdx.x == 0) {
    int run = 0;
    for (int b = 0; b < B; b++) {
      int x = bsum[b];
      bsum[b] = run;
      run += x;
    }
    bsum[B] = run;
  }
}

__global__ void scan3_kernel(int* __restrict__ colptr, const int* __restrict__ bsum, int N) {
  int i = blockIdx.x * blockDim.x + threadIdx.x;
  if (i < N) colptr[i] += bsum[i >> 10];
  if (i == N) colptr[N] = bsum[(N + 1023) >> 10];
}

__global__ void fill_kernel(const int* __restrict__ row, const int* __restrict__ col, int E,
                            const int* __restrict__ colptr, int* __restrict__ cur,
                            int* __restrict__ csr) {
  int e = blockIdx.x * blockDim.x + threadIdx.x;
  if (e < E) {
    int c = col[e];
    int pos = colptr[c] + atomicAdd(&cur[c], 1);
    csr[pos] = row[e];
  }
}

__global__ void pfill_kernel(const int* __restrict__ pairs, int P,
                             const int* __restrict__ pptr, int* __restrict__ pcur,
                             int* __restrict__ porder) {
  int p = blockIdx.x * blockDim.x + threadIdx.x;
  if (p < P) {
    int s = pairs[2 * p];
    int pos = pptr[s] + atomicAdd(&pcur[s], 1);
    porder[pos] = p;
  }
}

// Transposed bf16 weights (row j = output col, col k = input dim)

__global__ void prep_weights(const float* __restrict__ Om, const float* __restrict__ Wsr,
                             const float* __restrict__ Wfc1, const float* __restrict__ Wenc,
                             const float* __restrict__ Wp1, unsigned short* __restrict__ Wn2T,
                             unsigned short* __restrict__ Wn2Tlo,
                             unsigned short* __restrict__ Wfc1T,
                             unsigned short* __restrict__ WencT,
                             unsigned short* __restrict__ Wp1T) {
  int idx = blockIdx.x * blockDim.x + threadIdx.x;
  if (idx < 128 * 64) {
    int j = idx / 64, k = idx % 64;
    float v;
    if (j < 64) {
      v = Om[k * 64 + j] - Om[j * 64 + k];
    } else {
      int jj = j - 64;
      v = 0.5f * (Wsr[k * 64 + jj] + Wsr[jj * 64 + k]);
    }
    unsigned short hi = f2bf(v);
    Wn2T[idx] = hi;
    Wn2Tlo[idx] = f2bf(v - bf2f(hi));
  } else if (idx < 128 * 64 + 128 * 128) {
    int t = idx - 128 * 64;
    int j = t / 128, k = t % 128;
    Wfc1T[t] = f2bf(Wfc1[k * 128 + j]);
  } else if (idx < 128 * 64 + 128 * 128 + 64 * 128) {
    int t = idx - 128 * 64 - 128 * 128;
    int j = t / 128, k = t % 128;
    WencT[t] = f2bf(Wenc[k * 64 + j]);
  } else if (idx < 128 * 64 + 128 * 128 + 2 * 64 * 128) {
    int t = idx - 128 * 64 - 128 * 128 - 64 * 128;
    int j = t / 128, k = t % 128;
    Wp1T[t] = f2bf(Wp1[k * 64 + j]);
  }
}

// ---------------- encoder GEMM: H = relu(x @ Wenc), K=128 ----------------

__global__ __launch_bounds__(256) void enc_gemm(const float* __restrict__ X,
                                                const unsigned short* __restrict__ WT,
                                                float* __restrict__ H, float* __restrict__ H0,
                                                unsigned short* __restrict__ Hb_hi,
                                                unsigned short* __restrict__ Hb_lo, int N) {
  int gw = blockIdx.x * 4 + (threadIdx.x >> 6);
  int l = threadIdx.x & 63;
  int r0 = gw * 16;
  if (r0 >= N) return;
  int arow = min(r0 + (l & 15), N - 1);
  int ak = (l >> 4) * 8;
  bf16x8 a[4];
#pragma unroll
  for (int kk = 0; kk < 4; kk++) {
    const float* xp = X + (size_t)arow * 128 + kk * 32 + ak;
    float4 u = *(const float4*)xp;
    float4 v = *(const float4*)(xp + 4);
    bf16x8 t;
    t[0] = (short)f2bf(u.x); t[1] = (short)f2bf(u.y);
    t[2] = (short)f2bf(u.z); t[3] = (short)f2bf(u.w);
    t[4] = (short)f2bf(v.x); t[5] = (short)f2bf(v.y);
    t[6] = (short)f2bf(v.z); t[7] = (short)f2bf(v.w);
    a[kk] = t;
  }
  int rbase = r0 + (l >> 4) * 4;
#pragma unroll
  for (int c = 0; c < 4; c++) {
    const unsigned short* wp = WT + (size_t)(c * 16 + (l & 15)) * 128 + ak;
    f32x4 acc = {0.f, 0.f, 0.f, 0.f};
#pragma unroll
    for (int kk = 0; kk < 4; kk++)
      acc = __builtin_amdgcn_mfma_f32_16x16x32_bf16(a[kk], *(const bf16x8*)(wp + kk * 32), acc,
                                                    0, 0, 0);
    int gcol = c * 16 + (l & 15);
#pragma unroll
    for (int b = 0; b < 4; b++) {
      int gr = rbase + b;
      if (gr < N) {
        float v = fmaxf(acc[b], 0.f);
        H[(size_t)gr * 64 + gcol] = v;
        H0[(size_t)gr * 64 + gcol] = v;
        unsigned short hi = f2bf(v);
        Hb_hi[(size_t)gr * 64 + gcol] = hi;
        Hb_lo[(size_t)gr * 64 + gcol] = f2bf(v - bf2f(hi));
      }
    }
  }
}

// ---------------- bootstrap node GEMM (t=0): A, Bs, T, D + ftfb ----------------

__global__ __launch_bounds__(256) void node_gemm(
    const unsigned short* __restrict__ Hb_hi, const unsigned short* __restrict__ Hb_lo,
    const unsigned short* __restrict__ Wn2T, const unsigned short* __restrict__ Wn2Tlo,
    const unsigned short* __restrict__ Wfc1T, const float* __restrict__ H,
    const float* __restrict__ Wfv, const float* __restrict__ dinv, float* __restrict__ Abuf,
    float* __restrict__ Bsbuf, float* __restrict__ Tbuf, float* __restrict__ Dbuf,
    float* __restrict__ ftfb, int N) {
  int gw = blockIdx.x * 4 + (threadIdx.x >> 6);
  int l = threadIdx.x & 63;
  int r0 = gw * 16;
  if (r0 >= N) return;
  int arow = min(r0 + (l & 15), N - 1);
  int ak = (l >> 4) * 8;
  bf16x8 a0h = *(const bf16x8*)(Hb_hi + (size_t)arow * 64 + ak);
  bf16x8 a1h = *(const bf16x8*)(Hb_hi + (size_t)arow * 64 + 32 + ak);
  bf16x8 a0l = *(const bf16x8*)(Hb_lo + (size_t)arow * 64 + ak);
  bf16x8 a1l = *(const bf16x8*)(Hb_lo + (size_t)arow * 64 + 32 + ak);
  int rbase = r0 + (l >> 4) * 4;
  float dv[4];
#pragma unroll
  for (int b = 0; b < 4; b++) dv[b] = dinv[min(rbase + b, N - 1)];
#pragma unroll
  for (int c = 0; c < 8; c++) {
    size_t woff = (size_t)(c * 16 + (l & 15)) * 64 + ak;
    bf16x8 b0h = *(const bf16x8*)(Wn2T + woff);
    bf16x8 b1h = *(const bf16x8*)(Wn2T + woff + 32);
    bf16x8 b0l = *(const bf16x8*)(Wn2Tlo + woff);
    bf16x8 b1l = *(const bf16x8*)(Wn2Tlo + woff + 32);
    f32x4 acc = {0.f, 0.f, 0.f, 0.f};
    acc = __builtin_amdgcn_mfma_f32_16x16x32_bf16(a0h, b0h, acc, 0, 0, 0);
    acc = __builtin_amdgcn_mfma_f32_16x16x32_bf16(a1h, b1h, acc, 0, 0, 0);
    acc = __builtin_amdgcn_mfma_f32_16x16x32_bf16(a0l, b0h, acc, 0, 0, 0);
    acc = __builtin_amdgcn_mfma_f32_16x16x32_bf16(a1l, b1h, acc, 0, 0, 0);
    acc = __builtin_amdgcn_mfma_f32_16x16x32_bf16(a0h, b0l, acc, 0, 0, 0);
    acc = __builtin_amdgcn_mfma_f32_16x16x32_bf16(a1h, b1l, acc, 0, 0, 0);
    int gcol = c * 16 + (l & 15);
#pragma unroll
    for (int b = 0; b < 4; b++) {
      int gr = rbase + b;
      if (gr < N) {
        float v = acc[b];
        if (c >= 4) Bsbuf[(size_t)gr * 64 + (gcol - 64)] = v * dv[b];
        else Abuf[(size_t)gr * 64 + gcol] = v;
      }
    }
  }
#pragma unroll
  for (int c = 0; c < 16; c++) {
    int j = ((c & 7) * 16 + (l & 15));
    int koff = (c < 8) ? 0 : 64;
    const unsigned short* wp = Wfc1T + (size_t)j * 128 + koff + ak;
    bf16x8 b0 = *(const bf16x8*)(wp);
    bf16x8 b1 = *(const bf16x8*)(wp + 32);
    f32x4 acc = {0.f, 0.f, 0.f, 0.f};
    acc = __builtin_amdgcn_mfma_f32_16x16x32_bf16(a0h, b0, acc, 0, 0, 0);
    acc = __builtin_amdgcn_mfma_f32_16x16x32_bf16(a1h, b1, acc, 0, 0, 0);
    acc = __builtin_amdgcn_mfma_f32_16x16x32_bf16(a0l, b0, acc, 0, 0, 0);
    acc = __builtin_amdgcn_mfma_f32_16x16x32_bf16(a1l, b1, acc, 0, 0, 0);
    float* dstb = (c < 8) ? Tbuf : Dbuf;
#pragma unroll
    for (int b = 0; b < 4; b++) {
      int gr = rbase + b;
      if (gr < N) dstb[(size_t)gr * 128 + j] = acc[b];
    }
  }
  int d0 = (l >> 4) * 16;
  const float* hp = H + (size_t)arow * 64 + d0;
  float p0 = 0.f, p1 = 0.f;
#pragma unroll
  for (int i = 0; i < 16; i += 4) {
    float4 h = *(const float4*)(hp + i);
    p0 += h.x * Wfv[d0 + i] + h.y * Wfv[d0 + i + 1] + h.z * Wfv[d0 + i + 2] +
          h.w * Wfv[d0 + i + 3];
    p1 += h.x * Wfv[64 + d0 + i] + h.y * Wfv[64 + d0 + i + 1] + h.z * Wfv[64 + d0 + i + 2] +
          h.w * Wfv[64 + d0 + i + 3];
  }
  p0 += __shfl_xor(p0, 16, 64);
  p0 += __shfl_xor(p0, 32, 64);
  p1 += __shfl_xor(p1, 16, 64);
  p1 += __shfl_xor(p1, 32, 64);
  if (l < 16 && r0 + l < N) {
    ftfb[2 * (r0 + l)] = p0;
    ftfb[2 * (r0 + l) + 1] = p1;
  }
}

// ---------------- fused step: [pair tau (src-sorted) | aggregate + next node-GEMM] --------

__global__ __launch_bounds__(256, 4) void step_fused(
    const float* __restrict__ A_cur, const float* __restrict__ Bs_cur,
    const float* __restrict__ T_cur, const float* __restrict__ D_cur,
    float* __restrict__ A_nxt, float* __restrict__ Bs_nxt, float* __restrict__ T_nxt,
    float* __restrict__ D_nxt, const int* __restrict__ colptr, const int* __restrict__ csr,
    const float* __restrict__ dinv, float* __restrict__ H, unsigned short* __restrict__ dHall,
    const unsigned short* __restrict__ Wn2T, const unsigned short* __restrict__ Wn2Tlo,
    const unsigned short* __restrict__ Wfc1T, const float* __restrict__ Wfc2,
    const float* __restrict__ ftfb_cur, float* __restrict__ ftfb_nxt,
    const float* __restrict__ Wfv, const int* __restrict__ pairs,
    const int* __restrict__ porder, const float* __restrict__ gum, float* __restrict__ tau,
    int t, int LT, int N, int P, int PB) {
  __shared__ unsigned short ldsHi[16 * 72];
  __shared__ unsigned short ldsLo[16 * 72];
  int l = threadIdx.x & 63;
  int w = threadIdx.x >> 6;
  if ((int)blockIdx.x < PB) {
    // ---- pair: z = T[src]+D[dst], logits via Wfc2, tau; src-sorted order ----
    int idx = (int)blockIdx.x * 32 + w * 8 + (l >> 3);
    bool act = idx < P;
    int p = porder[act ? idx : P - 1];
    int src = pairs[2 * p], dst = pairs[2 * p + 1];
    int d0 = (l & 7) * 16;
    const float* Tp = T_cur + (size_t)src * 128 + d0;
    const float* Dp = D_cur + (size_t)dst * 128 + d0;
    float l0 = 0.f, l1 = 0.f;
#pragma unroll
    for (int i = 0; i < 16; i += 4) {
      float4 tv = *(const float4*)(Tp + i);
      float4 dv4 = *(const float4*)(Dp + i);
      float z0 = fmaxf(tv.x + dv4.x, 0.f);
      float z1 = fmaxf(tv.y + dv4.y, 0.f);
      float z2 = fmaxf(tv.z + dv4.z, 0.f);
      float z3 = fmaxf(tv.w + dv4.w, 0.f);
      int m = d0 + i;
      l0 = fmaf(z0, Wfc2[2 * m], l0);
      l1 = fmaf(z0, Wfc2[2 * m + 1], l1);
      l0 = fmaf(z1, Wfc2[2 * m + 2], l0);
      l1 = fmaf(z1, Wfc2[2 * m + 3], l1);
      l0 = fmaf(z2, Wfc2[2 * m + 4], l0);
      l1 = fmaf(z2, Wfc2[2 * m + 5], l1);
      l0 = fmaf(z3, Wfc2[2 * m + 6], l0);
      l1 = fmaf(z3, Wfc2[2 * m + 7], l1);
    }
#pragma unroll
    for (int off = 1; off < 8; off <<= 1) {
      l0 += __shfl_xor(l0, off, 64);
      l1 += __shfl_xor(l1, off, 64);
    }
    if ((l & 7) == 0 && act) {
      float nu = softplusf(ftfb_cur[2 * src] + ftfb_cur[2 * dst + 1]) + 1.0f;
      float g0 = gum[2 * (size_t)p], g1 = gum[2 * (size_t)p + 1];
      float dlt = ((l1 + g1) - (l0 + g0)) / nu;
      tau[(size_t)p * LT + t] = 1.0f / (1.0f + expf(dlt));
    }
  } else {
    // ---- aggregate + H update + next-step node GEMM (16 nodes/block) ----
    int nb0 = ((int)blockIdx.x - PB) * 16;
    int g = l >> 4;
    int node = nb0 + w * 4 + g;
    int q = (l & 15) * 4;
    bool valid = node < N;
    float4 hn = make_float4(0.f, 0.f, 0.f, 0.f);
    if (valid) {
      size_t base = (size_t)node * 64 + q;
      float4 v = *(const float4*)(Bs_cur + base);
      float aa0 = v.x, aa1 = v.y, aa2 = v.z, aa3 = v.w;
      int beg = colptr[node], end = colptr[node + 1];
      int i = beg;
      // 8-wide rounds: 8 independent index loads, then 8 row-gathers in flight
      for (; i + 7 < end; i += 8) {
        int n0 = csr[i], n1 = csr[i + 1], n2 = csr[i + 2], n3 = csr[i + 3];
        int n4 = csr[i + 4], n5 = csr[i + 5], n6 = csr[i + 6], n7 = csr[i + 7];
        float4 u0 = *(const float4*)(Bs_cur + (size_t)n0 * 64 + q);
        float4 u1 = *(const float4*)(Bs_cur + (size_t)n1 * 64 + q);
        float4 u2 = *(const float4*)(Bs_cur + (size_t)n2 * 64 + q);
        float4 u3 = *(const float4*)(Bs_cur + (size_t)n3 * 64 + q);
        float4 u4 = *(const float4*)(Bs_cur + (size_t)n4 * 64 + q);
        float4 u5 = *(const float4*)(Bs_cur + (size_t)n5 * 64 + q);
        float4 u6 = *(const float4*)(Bs_cur + (size_t)n6 * 64 + q);
        float4 u7 = *(const float4*)(Bs_cur + (size_t)n7 * 64 + q);
        aa0 += ((u0.x + u1.x) + (u2.x + u3.x)) + ((u4.x + u5.x) + (u6.x + u7.x));
        aa1 += ((u0.y + u1.y) + (u2.y + u3.y)) + ((u4.y + u5.y) + (u6.y + u7.y));
        aa2 += ((u0.z + u1.z) + (u2.z + u3.z)) + ((u4.z + u5.z) + (u6.z + u7.z));
        aa3 += ((u0.w + u1.w) + (u2.w + u3.w)) + ((u4.w + u5.w) + (u6.w + u7.w));
      }
      for (; i + 3 < end; i += 4) {
        int n0 = csr[i], n1 = csr[i + 1], n2 = csr[i + 2], n3 = csr[i + 3];
        float4 u0 = *(const float4*)(Bs_cur + (size_t)n0 * 64 + q);
        float4 u1 = *(const float4*)(Bs_cur + (size_t)n1 * 64 + q);
        float4 u2 = *(const float4*)(Bs_cur + (size_t)n2 * 64 + q);
        float4 u3 = *(const float4*)(Bs_cur + (size_t)n3 * 64 + q);
        aa0 += (u0.x + u1.x) + (u2.x + u3.x);
        aa1 += (u0.y + u1.y) + (u2.y + u3.y);
        aa2 += (u0.z + u1.z) + (u2.z + u3.z);
        aa3 += (u0.w + u1.w) + (u2.w + u3.w);
      }
      for (; i < end; i++) {
        int n0 = csr[i];
        float4 u0 = *(const float4*)(Bs_cur + (size_t)n0 * 64 + q);
        aa0 += u0.x; aa1 += u0.y; aa2 += u0.z; aa3 += u0.w;
      }
      float dval = dinv[node];
      float4 av = *(const float4*)(A_cur + base);
      float dh0 = fmaxf(tanhf(dval * aa0 - fmaxf(av.x, 0.f)), 0.f);
      float dh1 = fmaxf(tanhf(dval * aa1 - fmaxf(av.y, 0.f)), 0.f);
      float dh2 = fmaxf(tanhf(dval * aa2 - fmaxf(av.z, 0.f)), 0.f);
      float dh3 = fmaxf(tanhf(dval * aa3 - fmaxf(av.w, 0.f)), 0.f);
      ushort4 od;
      od.x = f2bf(dh0); od.y = f2bf(dh1); od.z = f2bf(dh2); od.w = f2bf(dh3);
      *(ushort4*)(dHall + (size_t)node * (LT * 64) + t * 64 + q) = od;
      float* hp = H + base;
      float4 h = *(const float4*)hp;
      hn.x = h.x + dh0; hn.y = h.y + dh1; hn.z = h.z + dh2; hn.w = h.w + dh3;
      *(float4*)hp = hn;
    }
    ushort4 whi, wlo;
    whi.x = f2bf(hn.x); wlo.x = f2bf(hn.x - bf2f(whi.x));
    whi.y = f2bf(hn.y); wlo.y = f2bf(hn.y - bf2f(whi.y));
    whi.z = f2bf(hn.z); wlo.z = f2bf(hn.z - bf2f(whi.z));
    whi.w = f2bf(hn.w); wlo.w = f2bf(hn.w - bf2f(whi.w));
    int r = w * 4 + g;
    *(ushort4*)(ldsHi + r * 72 + q) = whi;
    *(ushort4*)(ldsLo + r * 72 + q) = wlo;
    float p0 = hn.x * Wfv[q] + hn.y * Wfv[q + 1] + hn.z * Wfv[q + 2] + hn.w * Wfv[q + 3];
    float p1 = hn.x * Wfv[64 + q] + hn.y * Wfv[64 + q + 1] + hn.z * Wfv[64 + q + 2] +
               hn.w * Wfv[64 + q + 3];
#pragma unroll
    for (int off = 1; off < 16; off <<= 1) {
      p0 += __shfl_xor(p0, off, 64);
      p1 += __shfl_xor(p1, off, 64);
    }
    if ((l & 15) == 0 && valid) {
      ftfb_nxt[2 * node] = p0;
      ftfb_nxt[2 * node + 1] = p1;
    }
    __syncthreads();
    int rowA = l & 15;
    int ak = g * 8;
    bf16x8 a0h = *(const bf16x8*)(ldsHi + rowA * 72 + ak);
    bf16x8 a1h = *(const bf16x8*)(ldsHi + rowA * 72 + 32 + ak);
    bf16x8 a0l = *(const bf16x8*)(ldsLo + rowA * 72 + ak);
    bf16x8 a1l = *(const bf16x8*)(ldsLo + rowA * 72 + 32 + ak);
    float dv[4];
#pragma unroll
    for (int b = 0; b < 4; b++) dv[b] = dinv[min(nb0 + g * 4 + b, N - 1)];
#pragma unroll
    for (int cc = 0; cc < 2; cc++) {
      int c = cc * 4 + w;
      size_t woff = (size_t)(c * 16 + rowA) * 64 + ak;
      bf16x8 b0h = *(const bf16x8*)(Wn2T + woff);
      bf16x8 b1h = *(const bf16x8*)(Wn2T + woff + 32);
      bf16x8 b0l = *(const bf16x8*)(Wn2Tlo + woff);
      bf16x8 b1l = *(const bf16x8*)(Wn2Tlo + woff + 32);
      f32x4 acc = {0.f, 0.f, 0.f, 0.f};
      acc = __builtin_amdgcn_mfma_f32_16x16x32_bf16(a0h, b0h, acc, 0, 0, 0);
      acc = __builtin_amdgcn_mfma_f32_16x16x32_bf16(a1h, b1h, acc, 0, 0, 0);
      acc = __builtin_amdgcn_mfma_f32_16x16x32_bf16(a0l, b0h, acc, 0, 0, 0);
      acc = __builtin_amdgcn_mfma_f32_16x16x32_bf16(a1l, b1h, acc, 0, 0, 0);
      acc = __builtin_amdgcn_mfma_f32_16x16x32_bf16(a0h, b0l, acc, 0, 0, 0);
      acc = __builtin_amdgcn_mfma_f32_16x16x32_bf16(a1h, b1l, acc, 0, 0, 0);
      int gcol = c * 16 + rowA;
#pragma unroll
      for (int b = 0; b < 4; b++) {
        int gr = nb0 + g * 4 + b;
        if (gr < N) {
          float v = acc[b];
          if (cc == 1) Bs_nxt[(size_t)gr * 64 + (gcol - 64)] = v * dv[b];
          else A_nxt[(size_t)gr * 64 + gcol] = v;
        }
      }
    }
#pragma unroll
    for (int cc = 0; cc < 4; cc++) {
      int jb = (cc & 1) + 2 * w;
      int koff = (cc < 2) ? 0 : 64;
      int j = jb * 16 + rowA;
      const unsigned short* wp = Wfc1T + (size_t)j * 128 + koff + ak;
      bf16x8 b0 = *(const bf16x8*)(wp);
      bf16x8 b1 = *(const bf16x8*)(wp + 32);
      f32x4 acc = {0.f, 0.f, 0.f, 0.f};
      acc = __builtin_amdgcn_mfma_f32_16x16x32_bf16(a0h, b0, acc, 0, 0, 0);
      acc = __builtin_amdgcn_mfma_f32_16x16x32_bf16(a1h, b1, acc, 0, 0, 0);
      acc = __builtin_amdgcn_mfma_f32_16x16x32_bf16(a0l, b0, acc, 0, 0, 0);
      acc = __builtin_amdgcn_mfma_f32_16x16x32_bf16(a1l, b1, acc, 0, 0, 0);
      float* dstb = (cc < 2) ? T_nxt : D_nxt;
#pragma unroll
      for (int b = 0; b < 4; b++) {
        int gr = nb0 + g * 4 + b;
        if (gr < N) dstb[(size_t)gr * 128 + j] = acc[b];
      }
    }
  }
}

// ---------------- fused rbuild + final: scores + ts, src-sorted order ----------------

__global__ __launch_bounds__(256, 4) void rbuild_final(
    const float* __restrict__ H0, const unsigned short* __restrict__ dHall,
    const float* __restrict__ tau, const int* __restrict__ pairs,
    const int* __restrict__ porder, const unsigned short* __restrict__ Wp1T,
    const float* __restrict__ Wp2, float* __restrict__ out, float* __restrict__ ts, int P,
    int N, int Lsteps) {
  __shared__ unsigned short sHi[16 * 136];
  __shared__ unsigned short sLo[16 * 136];
  __shared__ float sS[4][16];
  __shared__ int sP[16];
  __shared__ int sV[16];
  int pr = threadIdx.x >> 4;
  int l16 = threadIdx.x & 15;
  int i0 = (int)blockIdx.x * 16;
  bool act = (i0 + pr) < P;
  int p = porder[act ? (i0 + pr) : P - 1];
  if (l16 == 0) {
    sP[pr] = p;
    sV[pr] = act ? 1 : 0;
  }
  int node = (l16 < 8) ? pairs[2 * p] : pairs[2 * p + 1];
  int d0 = (l16 & 7) * 8;
  const float* hp = H0 + (size_t)node * 64 + d0;
  float4 h0 = *(const float4*)hp;
  float4 h1 = *(const float4*)(hp + 4);
  float acc[8] = {h0.x, h0.y, h0.z, h0.w, h1.x, h1.y, h1.z, h1.w};
  float tsum = 0.f;
  const unsigned short* dbase = dHall + (size_t)node * (Lsteps * 64) + d0;
  const float* taup = tau + (size_t)p * Lsteps;
#pragma unroll 10
  for (int t = 0; t < Lsteps; t++) {
    float tt = taup[t];
    tsum += tt;
    u16x8 v = *(const u16x8*)(dbase + t * 64);
#pragma unroll
    for (int i = 0; i < 8; i++) acc[i] = fmaf(tt, bf2f(v[i]), acc[i]);
  }
  u16x8 ohi, olo;
#pragma unroll
  for (int i = 0; i < 8; i++) {
    unsigned short hi = f2bf(acc[i]);
    ohi[i] = hi;
    olo[i] = f2bf(acc[i] - bf2f(hi));
  }
  *(u16x8*)(sHi + pr * 136 + l16 * 8) = ohi;
  *(u16x8*)(sLo + pr * 136 + l16 * 8) = olo;
  if (l16 == 0 && act) ts[p] = tsum;
  __syncthreads();
  int w = threadIdx.x >> 6;
  int l = threadIdx.x & 63;
  int rowA = l & 15;
  int ak = (l >> 4) * 8;
  bf16x8 ah[4], al[4];
#pragma unroll
  for (int kk = 0; kk < 4; kk++) {
    ah[kk] = *(const bf16x8*)(sHi + rowA * 136 + kk * 32 + ak);
    al[kk] = *(const bf16x8*)(sLo + rowA * 136 + kk * 32 + ak);
  }
  const unsigned short* wp = Wp1T + (size_t)(w * 16 + rowA) * 128 + ak;
  f32x4 macc = {0.f, 0.f, 0.f, 0.f};
#pragma unroll
  for (int kk = 0; kk < 4; kk++) {
    bf16x8 wv = *(const bf16x8*)(wp + kk * 32);
    macc = __builtin_amdgcn_mfma_f32_16x16x32_bf16(ah[kk], wv, macc, 0, 0, 0);
    macc = __builtin_amdgcn_mfma_f32_16x16x32_bf16(al[kk], wv, macc, 0, 0, 0);
  }
  float wcol = Wp2[w * 16 + rowA];
  float s[4];
#pragma unroll
  for (int b = 0; b < 4; b++) s[b] = fmaxf(macc[b], 0.f) * wcol;
#pragma unroll
  for (int off = 1; off < 16; off <<= 1) {
#pragma unroll
    for (int b = 0; b < 4; b++) s[b] += __shfl_xor(s[b], off, 64);
  }
  if ((l & 15) == 0) {
#pragma unroll
    for (int b = 0; b < 4; b++) sS[w][(l >> 4) * 4 + b] = s[b];
  }
  __syncthreads();
  if (threadIdx.x < 16) {
    int row = threadIdx.x;
    float sum = sS[0][row] + sS[1][row] + sS[2][row] + sS[3][row];
    if (sV[row]) out[sP[row]] = sum;
  }
}

// ---------------- launch ----------------

extern "C" void kernel_launch(void* const* d_in, const int* in_sizes, int n_in, void* d_out,
                              int out_size, void* d_ws, size_t ws_size, hipStream_t stream) {
  const float* x = (const float*)d_in[0];
  const int* edge = (const int*)d_in[1];
  const int* pairs = (const int*)d_in[2];
  const float* gumbel = (const float*)d_in[3];
  const float* Wenc = (const float*)d_in[4];
  const float* Om = (const float*)d_in[5];
  const float* Wsr = (const float*)d_in[6];
  const float* Wfc1 = (const float*)d_in[7];
  const float* Wfc2 = (const float*)d_in[8];
  const float* Wfv = (const float*)d_in[9];
  const float* Wp1 = (const float*)d_in[10];
  const float* Wp2 = (const float*)d_in[11];
  const int IN = 128;
  const int N = in_sizes[0] / IN;
  const int E = in_sizes[1] / 2;
  const int P = in_sizes[2] / 2;
  const int L = in_sizes[3] / (2 * P);
  float* out = (float*)d_out;

  char* wsb = (char*)d_ws;
  size_t off = 0;
  auto alloc = [&](size_t bytes) -> char* {
    char* p = wsb + off;
    off = (off + bytes + 255) & ~(size_t)255;
    return p;
  };
  const int NB = (N + 1023) >> 10;
  float* dinv = (float*)alloc((size_t)N * 4);
  int* cnt = (int*)alloc((size_t)N * 4);
  int* colptr = (int*)alloc((size_t)(N + 1) * 4);
  int* bsum = (int*)alloc((size_t)(NB + 1) * 4);
  int* csr = (int*)alloc((size_t)E * 4);
  int* pcnt = (int*)alloc((size_t)N * 4);
  int* pptr = (int*)alloc((size_t)(N + 1) * 4);
  int* pbsum = (int*)alloc((size_t)(NB + 1) * 4);
  int* porder = (int*)alloc((size_t)P * 4);
  unsigned short* Wn2T = (unsigned short*)alloc((size_t)128 * 64 * 2);
  unsigned short* Wn2Tlo = (unsigned short*)alloc((size_t)128 * 64 * 2);
  unsigned short* Wfc1T = (unsigned short*)alloc((size_t)128 * 128 * 2);
  unsigned short* WencT = (unsigned short*)alloc((size_t)64 * 128 * 2);
  unsigned short* Wp1T = (unsigned short*)alloc((size_t)64 * 128 * 2);
  float* H = (float*)alloc((size_t)N * 64 * 4);
  float* H0 = (float*)alloc((size_t)N * 64 * 4);
  unsigned short* Hb_hi = (unsigned short*)alloc((size_t)N * 64 * 2);
  unsigned short* Hb_lo = (unsigned short*)alloc((size_t)N * 64 * 2);
  float* A_a = (float*)alloc((size_t)N * 64 * 4);
  float* A_b = (float*)alloc((size_t)N * 64 * 4);
  float* Bs_a = (float*)alloc((size_t)N * 64 * 4);
  float* Bs_b = (float*)alloc((size_t)N * 64 * 4);
  float* T_a = (float*)alloc((size_t)N * 128 * 4);
  float* T_b = (float*)alloc((size_t)N * 128 * 4);
  float* D_a = (float*)alloc((size_t)N * 128 * 4);
  float* D_b = (float*)alloc((size_t)N * 128 * 4);
  float* ftfbA = (float*)alloc((size_t)N * 2 * 4);
  float* ftfbB = (float*)alloc((size_t)N * 2 * 4);
  unsigned short* dHall = (unsigned short*)alloc((size_t)N * L * 64 * 2);
  float* tau = (float*)alloc((size_t)P * L * 4);
  (void)ws_size;
  (void)n_in;
  (void)out_size;

  const int* erow = edge;
  const int* ecol = edge + E;

  hipMemsetAsync(cnt, 0, (size_t)N * 4, stream);
  hipMemsetAsync(pcnt, 0, (size_t)N * 4, stream);
  count_kernel<<<(E + 255) / 256, 256, 0, stream>>>(ecol, E, cnt);
  pcount_kernel<<<(P + 255) / 256, 256, 0, stream>>>(pairs, P, pcnt);
  scan1_kernel<<<NB, 1024, 0, stream>>>(cnt, colptr, dinv, bsum, N);
  scan1_kernel<<<NB, 1024, 0, stream>>>(pcnt, pptr, nullptr, pbsum, N);
  scan2_kernel<<<1, 64, 0, stream>>>(bsum, NB);
  scan2_kernel<<<1, 64, 0, stream>>>(pbsum, NB);
  scan3_kernel<<<(N + 256) / 256, 256, 0, stream>>>(colptr, bsum, N);
  scan3_kernel<<<(N + 256) / 256, 256, 0, stream>>>(pptr, pbsum, N);
  fill_kernel<<<(E + 255) / 256, 256, 0, stream>>>(erow, ecol, E, colptr, cnt, csr);
  pfill_kernel<<<(P + 255) / 256, 256, 0, stream>>>(pairs, P, pptr, pcnt, porder);
  prep_weights<<<(128 * 64 + 128 * 128 + 2 * 64 * 128 + 255) / 256, 256, 0, stream>>>(
      Om, Wsr, Wfc1, Wenc, Wp1, Wn2T, Wn2Tlo, Wfc1T, WencT, Wp1T);

  int nwaves = (N + 15) / 16;
  enc_gemm<<<(nwaves + 3) / 4, 256, 0, stream>>>(x, WencT, H, H0, Hb_hi, Hb_lo, N);
  node_gemm<<<(nwaves + 3) / 4, 256, 0, stream>>>(Hb_hi, Hb_lo, Wn2T, Wn2Tlo, Wfc1T, H, Wfv,
                                                  dinv, A_a, Bs_a, T_a, D_a, ftfbA, N);

  float* A_cur = A_a;   float* A_nxt = A_b;
  float* Bs_cur = Bs_a; float* Bs_nxt = Bs_b;
  float* T_cur = T_a;   float* T_nxt = T_b;
  float* D_cur = D_a;   float* D_nxt = D_b;
  float* ff_cur = ftfbA;
  float* ff_nxt = ftfbB;
  const int PB = (P + 31) / 32;
  const int AGB = (N + 15) / 16;
  for (int t = 0; t < L; t++) {
    step_fused<<<PB + AGB, 256, 0, stream>>>(
        A_cur, Bs_cur, T_cur, D_cur, A_nxt, Bs_nxt, T_nxt, D_nxt, colptr, csr, dinv, H, dHall,
        Wn2T, Wn2Tlo, Wfc1T, Wfc2, ff_cur, ff_nxt, Wfv, pairs, porder,
        gumbel + (size_t)t * P * 2, tau, t, L, N, P, PB);
    { float* tmp = A_cur; A_cur = A_nxt; A_nxt = tmp; }
    { float* tmp = Bs_cur; Bs_cur = Bs_nxt; Bs_nxt = tmp; }
    { float* tmp = T_cur; T_cur = T_nxt; T_nxt = tmp; }
    { float* tmp = D_cur; D_cur = D_nxt; D_nxt = tmp; }
    { float* tmp = ff_cur; ff_cur = ff_nxt; ff_nxt = tmp; }
  }
  rbuild_final<<<(P + 15) / 16, 256, 0, stream>>>(H0, dHall, tau, pairs, porder, Wp1T, Wp2,
                                                  out, out + P, P, N, L);
}

// Round 12
// 851.375 us; speedup vs baseline: 1.4065x; 1.0422x over previous
//
#include <hip/hip_runtime.h>
#include <math.h>

// EELP: 20-step GNN scan. fp32-clean H-recurrence (hi/lo split MFMA, fp32
// A/Bs/H, libm tanh). Per-node T/D in bf16 (tau path only); z = T[src]+D[dst].
// Pairs src-sorted (porder). One fused kernel per step. rbuild+final fused.

typedef short bf16x8 __attribute__((ext_vector_type(8)));
typedef float f32x4 __attribute__((ext_vector_type(4)));
typedef unsigned short u16x8 __attribute__((ext_vector_type(8)));

__device__ __forceinline__ float bf2f(unsigned short u) {
  return __uint_as_float(((unsigned)u) << 16);
}
__device__ __forceinline__ unsigned short f2bf(float f) {
  unsigned u = __float_as_uint(f);
  unsigned r = (u + 0x7FFFu + ((u >> 16) & 1u)) >> 16;
  return (unsigned short)r;
}
__device__ __forceinline__ float softplusf(float x) {
  return x > 20.f ? x : log1pf(expf(x));
}

// ---------------- setup: degree count + 3-phase scan + CSR fill ----------------

__global__ void count_kernel(const int* __restrict__ col, int E, int* __restrict__ cnt) {
  int e = blockIdx.x * blockDim.x + threadIdx.x;
  if (e < E) atomicAdd(&cnt[col[e]], 1);
}

__global__ void pcount_kernel(const int* __restrict__ pairs, int P, int* __restrict__ cnt) {
  int p = blockIdx.x * blockDim.x + threadIdx.x;
  if (p < P) atomicAdd(&cnt[pairs[2 * p]], 1);
}

__global__ __launch_bounds__(1024) void scan1_kernel(int* __restrict__ cnt,
                                                     int* __restrict__ colptr,
                                                     float* __restrict__ dinv,
                                                     int* __restrict__ bsum, int N) {
  __shared__ int sh[1024];
  int t = threadIdx.x, b = blockIdx.x;
  int i = b * 1024 + t;
  int v = (i < N) ? cnt[i] : 0;
  sh[t] = v;
  __syncthreads();
  for (int off = 1; off < 1024; off <<= 1) {
    int o = (t >= off) ? sh[t - off] : 0;
    __syncthreads();
    sh[t] += o;
    __syncthreads();
  }
  if (i < N) {
    colptr[i] = sh[t] - v;
    if (dinv) dinv[i] = rsqrtf((float)(v + 1));
    cnt[i] = 0;
  }
  if (t == 1023) bsum[b] = sh[1023];
}

__global__ void scan2_kernel(int* __restrict__ bsum, int B) {
  if (threadIdx.x == 0 && blockIdx.x == 0) {
    int run = 0;
    for (int b = 0; b < B; b++) {
      int x = bsum[b];
      bsum[b] = run;
      run += x;
    }
    bsum[B] = run;
  }
}

__global__ void scan3_kernel(int* __restrict__ colptr, const int* __restrict__ bsum, int N) {
  int i = blockIdx.x * blockDim.x + threadIdx.x;
  if (i < N) colptr[i] += bsum[i >> 10];
  if (i == N) colptr[N] = bsum[(N + 1023) >> 10];
}

__global__ void fill_kernel(const int* __restrict__ row, const int* __restrict__ col, int E,
                            const int* __restrict__ colptr, int* __restrict__ cur,
                            int* __restrict__ csr) {
  int e = blockIdx.x * blockDim.x + threadIdx.x;
  if (e < E) {
    int c = col[e];
    int pos = colptr[c] + atomicAdd(&cur[c], 1);
    csr[pos] = row[e];
  }
}

__global__ void pfill_kernel(const int* __restrict__ pairs, int P,
                             const int* __restrict__ pptr, int* __restrict__ pcur,
                             int* __restrict__ porder) {
  int p = blockIdx.x * blockDim.x + threadIdx.x;
  if (p < P) {
    int s = pairs[2 * p];
    int pos = pptr[s] + atomicAdd(&pcur[s], 1);
    porder[pos] = p;
  }
}

// Transposed bf16 weights (row j = output col, col k = input dim)

__global__ void prep_weights(const float* __restrict__ Om, const float* __restrict__ Wsr,
                             const float* __restrict__ Wfc1, const float* __restrict__ Wenc,
                             const float* __restrict__ Wp1, unsigned short* __restrict__ Wn2T,
                             unsigned short* __restrict__ Wn2Tlo,
                             unsigned short* __restrict__ Wfc1T,
                             unsigned short* __restrict__ WencT,
                             unsigned short* __restrict__ Wp1T) {
  int idx = blockIdx.x * blockDim.x + threadIdx.x;
  if (idx < 128 * 64) {
    int j = idx / 64, k = idx % 64;
    float v;
    if (j < 64) {
      v = Om[k * 64 + j] - Om[j * 64 + k];
    } else {
      int jj = j - 64;
      v = 0.5f * (Wsr[k * 64 + jj] + Wsr[jj * 64 + k]);
    }
    unsigned short hi = f2bf(v);
    Wn2T[idx] = hi;
    Wn2Tlo[idx] = f2bf(v - bf2f(hi));
  } else if (idx < 128 * 64 + 128 * 128) {
    int t = idx - 128 * 64;
    int j = t / 128, k = t % 128;
    Wfc1T[t] = f2bf(Wfc1[k * 128 + j]);
  } else if (idx < 128 * 64 + 128 * 128 + 64 * 128) {
    int t = idx - 128 * 64 - 128 * 128;
    int j = t / 128, k = t % 128;
    WencT[t] = f2bf(Wenc[k * 64 + j]);
  } else if (idx < 128 * 64 + 128 * 128 + 2 * 64 * 128) {
    int t = idx - 128 * 64 - 128 * 128 - 64 * 128;
    int j = t / 128, k = t % 128;
    Wp1T[t] = f2bf(Wp1[k * 64 + j]);
  }
}

// ---------------- encoder GEMM: H = relu(x @ Wenc), K=128 ----------------

__global__ __launch_bounds__(256) void enc_gemm(const float* __restrict__ X,
                                                const unsigned short* __restrict__ WT,
                                                float* __restrict__ H, float* __restrict__ H0,
                                                unsigned short* __restrict__ Hb_hi,
                                                unsigned short* __restrict__ Hb_lo, int N) {
  int gw = blockIdx.x * 4 + (threadIdx.x >> 6);
  int l = threadIdx.x & 63;
  int r0 = gw * 16;
  if (r0 >= N) return;
  int arow = min(r0 + (l & 15), N - 1);
  int ak = (l >> 4) * 8;
  bf16x8 a[4];
#pragma unroll
  for (int kk = 0; kk < 4; kk++) {
    const float* xp = X + (size_t)arow * 128 + kk * 32 + ak;
    float4 u = *(const float4*)xp;
    float4 v = *(const float4*)(xp + 4);
    bf16x8 t;
    t[0] = (short)f2bf(u.x); t[1] = (short)f2bf(u.y);
    t[2] = (short)f2bf(u.z); t[3] = (short)f2bf(u.w);
    t[4] = (short)f2bf(v.x); t[5] = (short)f2bf(v.y);
    t[6] = (short)f2bf(v.z); t[7] = (short)f2bf(v.w);
    a[kk] = t;
  }
  int rbase = r0 + (l >> 4) * 4;
#pragma unroll
  for (int c = 0; c < 4; c++) {
    const unsigned short* wp = WT + (size_t)(c * 16 + (l & 15)) * 128 + ak;
    f32x4 acc = {0.f, 0.f, 0.f, 0.f};
#pragma unroll
    for (int kk = 0; kk < 4; kk++)
      acc = __builtin_amdgcn_mfma_f32_16x16x32_bf16(a[kk], *(const bf16x8*)(wp + kk * 32), acc,
                                                    0, 0, 0);
    int gcol = c * 16 + (l & 15);
#pragma unroll
    for (int b = 0; b < 4; b++) {
      int gr = rbase + b;
      if (gr < N) {
        float v = fmaxf(acc[b], 0.f);
        H[(size_t)gr * 64 + gcol] = v;
        H0[(size_t)gr * 64 + gcol] = v;
        unsigned short hi = f2bf(v);
        Hb_hi[(size_t)gr * 64 + gcol] = hi;
        Hb_lo[(size_t)gr * 64 + gcol] = f2bf(v - bf2f(hi));
      }
    }
  }
}

// ---------------- bootstrap node GEMM (t=0): A, Bs (f32), T, D (bf16) + ftfb ----------------

__global__ __launch_bounds__(256) void node_gemm(
    const unsigned short* __restrict__ Hb_hi, const unsigned short* __restrict__ Hb_lo,
    const unsigned short* __restrict__ Wn2T, const unsigned short* __restrict__ Wn2Tlo,
    const unsigned short* __restrict__ Wfc1T, const float* __restrict__ H,
    const float* __restrict__ Wfv, const float* __restrict__ dinv, float* __restrict__ Abuf,
    float* __restrict__ Bsbuf, unsigned short* __restrict__ Tbuf,
    unsigned short* __restrict__ Dbuf, float* __restrict__ ftfb, int N) {
  int gw = blockIdx.x * 4 + (threadIdx.x >> 6);
  int l = threadIdx.x & 63;
  int r0 = gw * 16;
  if (r0 >= N) return;
  int arow = min(r0 + (l & 15), N - 1);
  int ak = (l >> 4) * 8;
  bf16x8 a0h = *(const bf16x8*)(Hb_hi + (size_t)arow * 64 + ak);
  bf16x8 a1h = *(const bf16x8*)(Hb_hi + (size_t)arow * 64 + 32 + ak);
  bf16x8 a0l = *(const bf16x8*)(Hb_lo + (size_t)arow * 64 + ak);
  bf16x8 a1l = *(const bf16x8*)(Hb_lo + (size_t)arow * 64 + 32 + ak);
  int rbase = r0 + (l >> 4) * 4;
  float dv[4];
#pragma unroll
  for (int b = 0; b < 4; b++) dv[b] = dinv[min(rbase + b, N - 1)];
#pragma unroll
  for (int c = 0; c < 8; c++) {
    size_t woff = (size_t)(c * 16 + (l & 15)) * 64 + ak;
    bf16x8 b0h = *(const bf16x8*)(Wn2T + woff);
    bf16x8 b1h = *(const bf16x8*)(Wn2T + woff + 32);
    bf16x8 b0l = *(const bf16x8*)(Wn2Tlo + woff);
    bf16x8 b1l = *(const bf16x8*)(Wn2Tlo + woff + 32);
    f32x4 acc = {0.f, 0.f, 0.f, 0.f};
    acc = __builtin_amdgcn_mfma_f32_16x16x32_bf16(a0h, b0h, acc, 0, 0, 0);
    acc = __builtin_amdgcn_mfma_f32_16x16x32_bf16(a1h, b1h, acc, 0, 0, 0);
    acc = __builtin_amdgcn_mfma_f32_16x16x32_bf16(a0l, b0h, acc, 0, 0, 0);
    acc = __builtin_amdgcn_mfma_f32_16x16x32_bf16(a1l, b1h, acc, 0, 0, 0);
    acc = __builtin_amdgcn_mfma_f32_16x16x32_bf16(a0h, b0l, acc, 0, 0, 0);
    acc = __builtin_amdgcn_mfma_f32_16x16x32_bf16(a1h, b1l, acc, 0, 0, 0);
    int gcol = c * 16 + (l & 15);
#pragma unroll
    for (int b = 0; b < 4; b++) {
      int gr = rbase + b;
      if (gr < N) {
        float v = acc[b];
        if (c >= 4) Bsbuf[(size_t)gr * 64 + (gcol - 64)] = v * dv[b];
        else Abuf[(size_t)gr * 64 + gcol] = v;
      }
    }
  }
#pragma unroll
  for (int c = 0; c < 16; c++) {
    int j = ((c & 7) * 16 + (l & 15));
    int koff = (c < 8) ? 0 : 64;
    const unsigned short* wp = Wfc1T + (size_t)j * 128 + koff + ak;
    bf16x8 b0 = *(const bf16x8*)(wp);
    bf16x8 b1 = *(const bf16x8*)(wp + 32);
    f32x4 acc = {0.f, 0.f, 0.f, 0.f};
    acc = __builtin_amdgcn_mfma_f32_16x16x32_bf16(a0h, b0, acc, 0, 0, 0);
    acc = __builtin_amdgcn_mfma_f32_16x16x32_bf16(a1h, b1, acc, 0, 0, 0);
    acc = __builtin_amdgcn_mfma_f32_16x16x32_bf16(a0l, b0, acc, 0, 0, 0);
    acc = __builtin_amdgcn_mfma_f32_16x16x32_bf16(a1l, b1, acc, 0, 0, 0);
    unsigned short* dstb = (c < 8) ? Tbuf : Dbuf;
#pragma unroll
    for (int b = 0; b < 4; b++) {
      int gr = rbase + b;
      if (gr < N) dstb[(size_t)gr * 128 + j] = f2bf(acc[b]);
    }
  }
  int d0 = (l >> 4) * 16;
  const float* hp = H + (size_t)arow * 64 + d0;
  float p0 = 0.f, p1 = 0.f;
#pragma unroll
  for (int i = 0; i < 16; i += 4) {
    float4 h = *(const float4*)(hp + i);
    p0 += h.x * Wfv[d0 + i] + h.y * Wfv[d0 + i + 1] + h.z * Wfv[d0 + i + 2] +
          h.w * Wfv[d0 + i + 3];
    p1 += h.x * Wfv[64 + d0 + i] + h.y * Wfv[64 + d0 + i + 1] + h.z * Wfv[64 + d0 + i + 2] +
          h.w * Wfv[64 + d0 + i + 3];
  }
  p0 += __shfl_xor(p0, 16, 64);
  p0 += __shfl_xor(p0, 32, 64);
  p1 += __shfl_xor(p1, 16, 64);
  p1 += __shfl_xor(p1, 32, 64);
  if (l < 16 && r0 + l < N) {
    ftfb[2 * (r0 + l)] = p0;
    ftfb[2 * (r0 + l) + 1] = p1;
  }
}

// ---------------- fused step: [pair tau (src-sorted) | aggregate + next node-GEMM] --------

__global__ __launch_bounds__(256, 4) void step_fused(
    const float* __restrict__ A_cur, const float* __restrict__ Bs_cur,
    const unsigned short* __restrict__ T_cur, const unsigned short* __restrict__ D_cur,
    float* __restrict__ A_nxt, float* __restrict__ Bs_nxt, unsigned short* __restrict__ T_nxt,
    unsigned short* __restrict__ D_nxt, const int* __restrict__ colptr,
    const int* __restrict__ csr, const float* __restrict__ dinv, float* __restrict__ H,
    unsigned short* __restrict__ dHall, const unsigned short* __restrict__ Wn2T,
    const unsigned short* __restrict__ Wn2Tlo, const unsigned short* __restrict__ Wfc1T,
    const float* __restrict__ Wfc2, const float* __restrict__ ftfb_cur,
    float* __restrict__ ftfb_nxt, const float* __restrict__ Wfv,
    const int* __restrict__ pairs, const int* __restrict__ porder,
    const float* __restrict__ gum, float* __restrict__ tau, int t, int LT, int N, int P,
    int PB) {
  __shared__ unsigned short ldsHi[16 * 72];
  __shared__ unsigned short ldsLo[16 * 72];
  int l = threadIdx.x & 63;
  int w = threadIdx.x >> 6;
  if ((int)blockIdx.x < PB) {
    // ---- pair: z = T[src]+D[dst] (bf16), logits via Wfc2, tau; src-sorted ----
    int idx = (int)blockIdx.x * 32 + w * 8 + (l >> 3);
    bool act = idx < P;
    int p = porder[act ? idx : P - 1];
    int src = pairs[2 * p], dst = pairs[2 * p + 1];
    int d0 = (l & 7) * 16;
    const unsigned short* Tp = T_cur + (size_t)src * 128 + d0;
    const unsigned short* Dp = D_cur + (size_t)dst * 128 + d0;
    u16x8 tv0 = *(const u16x8*)(Tp);
    u16x8 tv1 = *(const u16x8*)(Tp + 8);
    u16x8 dv0 = *(const u16x8*)(Dp);
    u16x8 dv1 = *(const u16x8*)(Dp + 8);
    float l0 = 0.f, l1 = 0.f;
#pragma unroll
    for (int i = 0; i < 8; i++) {
      float z = fmaxf(bf2f(tv0[i]) + bf2f(dv0[i]), 0.f);
      int m = d0 + i;
      l0 = fmaf(z, Wfc2[2 * m], l0);
      l1 = fmaf(z, Wfc2[2 * m + 1], l1);
    }
#pragma unroll
    for (int i = 0; i < 8; i++) {
      float z = fmaxf(bf2f(tv1[i]) + bf2f(dv1[i]), 0.f);
      int m = d0 + 8 + i;
      l0 = fmaf(z, Wfc2[2 * m], l0);
      l1 = fmaf(z, Wfc2[2 * m + 1], l1);
    }
#pragma unroll
    for (int off = 1; off < 8; off <<= 1) {
      l0 += __shfl_xor(l0, off, 64);
      l1 += __shfl_xor(l1, off, 64);
    }
    if ((l & 7) == 0 && act) {
      float nu = softplusf(ftfb_cur[2 * src] + ftfb_cur[2 * dst + 1]) + 1.0f;
      float g0 = gum[2 * (size_t)p], g1 = gum[2 * (size_t)p + 1];
      float dlt = ((l1 + g1) - (l0 + g0)) / nu;
      tau[(size_t)p * LT + t] = 1.0f / (1.0f + expf(dlt));
    }
  } else {
    // ---- aggregate + H update + next-step node GEMM (16 nodes/block) ----
    int nb0 = ((int)blockIdx.x - PB) * 16;
    int g = l >> 4;
    int node = nb0 + w * 4 + g;
    int q = (l & 15) * 4;
    bool valid = node < N;
    float4 hn = make_float4(0.f, 0.f, 0.f, 0.f);
    if (valid) {
      size_t base = (size_t)node * 64 + q;
      float4 v = *(const float4*)(Bs_cur + base);
      float aa0 = v.x, aa1 = v.y, aa2 = v.z, aa3 = v.w;
      int beg = colptr[node], end = colptr[node + 1];
      int i = beg;
      for (; i + 7 < end; i += 8) {
        int n0 = csr[i], n1 = csr[i + 1], n2 = csr[i + 2], n3 = csr[i + 3];
        int n4 = csr[i + 4], n5 = csr[i + 5], n6 = csr[i + 6], n7 = csr[i + 7];
        float4 u0 = *(const float4*)(Bs_cur + (size_t)n0 * 64 + q);
        float4 u1 = *(const float4*)(Bs_cur + (size_t)n1 * 64 + q);
        float4 u2 = *(const float4*)(Bs_cur + (size_t)n2 * 64 + q);
        float4 u3 = *(const float4*)(Bs_cur + (size_t)n3 * 64 + q);
        float4 u4 = *(const float4*)(Bs_cur + (size_t)n4 * 64 + q);
        float4 u5 = *(const float4*)(Bs_cur + (size_t)n5 * 64 + q);
        float4 u6 = *(const float4*)(Bs_cur + (size_t)n6 * 64 + q);
        float4 u7 = *(const float4*)(Bs_cur + (size_t)n7 * 64 + q);
        aa0 += ((u0.x + u1.x) + (u2.x + u3.x)) + ((u4.x + u5.x) + (u6.x + u7.x));
        aa1 += ((u0.y + u1.y) + (u2.y + u3.y)) + ((u4.y + u5.y) + (u6.y + u7.y));
        aa2 += ((u0.z + u1.z) + (u2.z + u3.z)) + ((u4.z + u5.z) + (u6.z + u7.z));
        aa3 += ((u0.w + u1.w) + (u2.w + u3.w)) + ((u4.w + u5.w) + (u6.w + u7.w));
      }
      for (; i + 3 < end; i += 4) {
        int n0 = csr[i], n1 = csr[i + 1], n2 = csr[i + 2], n3 = csr[i + 3];
        float4 u0 = *(const float4*)(Bs_cur + (size_t)n0 * 64 + q);
        float4 u1 = *(const float4*)(Bs_cur + (size_t)n1 * 64 + q);
        float4 u2 = *(const float4*)(Bs_cur + (size_t)n2 * 64 + q);
        float4 u3 = *(const float4*)(Bs_cur + (size_t)n3 * 64 + q);
        aa0 += (u0.x + u1.x) + (u2.x + u3.x);
        aa1 += (u0.y + u1.y) + (u2.y + u3.y);
        aa2 += (u0.z + u1.z) + (u2.z + u3.z);
        aa3 += (u0.w + u1.w) + (u2.w + u3.w);
      }
      for (; i < end; i++) {
        int n0 = csr[i];
        float4 u0 = *(const float4*)(Bs_cur + (size_t)n0 * 64 + q);
        aa0 += u0.x; aa1 += u0.y; aa2 += u0.z; aa3 += u0.w;
      }
      float dval = dinv[node];
      float4 av = *(const float4*)(A_cur + base);
      float dh0 = fmaxf(tanhf(dval * aa0 - fmaxf(av.x, 0.f)), 0.f);
      float dh1 = fmaxf(tanhf(dval * aa1 - fmaxf(av.y, 0.f)), 0.f);
      float dh2 = fmaxf(tanhf(dval * aa2 - fmaxf(av.z, 0.f)), 0.f);
      float dh3 = fmaxf(tanhf(dval * aa3 - fmaxf(av.w, 0.f)), 0.f);
      ushort4 od;
      od.x = f2bf(dh0); od.y = f2bf(dh1); od.z = f2bf(dh2); od.w = f2bf(dh3);
      *(ushort4*)(dHall + (size_t)node * (LT * 64) + t * 64 + q) = od;
      float* hp = H + base;
      float4 h = *(const float4*)hp;
      hn.x = h.x + dh0; hn.y = h.y + dh1; hn.z = h.z + dh2; hn.w = h.w + dh3;
      *(float4*)hp = hn;
    }
    ushort4 whi, wlo;
    whi.x = f2bf(hn.x); wlo.x = f2bf(hn.x - bf2f(whi.x));
    whi.y = f2bf(hn.y); wlo.y = f2bf(hn.y - bf2f(whi.y));
    whi.z = f2bf(hn.z); wlo.z = f2bf(hn.z - bf2f(whi.z));
    whi.w = f2bf(hn.w); wlo.w = f2bf(hn.w - bf2f(whi.w));
    int r = w * 4 + g;
    *(ushort4*)(ldsHi + r * 72 + q) = whi;
    *(ushort4*)(ldsLo + r * 72 + q) = wlo;
    float p0 = hn.x * Wfv[q] + hn.y * Wfv[q + 1] + hn.z * Wfv[q + 2] + hn.w * Wfv[q + 3];
    float p1 = hn.x * Wfv[64 + q] + hn.y * Wfv[64 + q + 1] + hn.z * Wfv[64 + q + 2] +
               hn.w * Wfv[64 + q + 3];
#pragma unroll
    for (int off = 1; off < 16; off <<= 1) {
      p0 += __shfl_xor(p0, off, 64);
      p1 += __shfl_xor(p1, off, 64);
    }
    if ((l & 15) == 0 && valid) {
      ftfb_nxt[2 * node] = p0;
      ftfb_nxt[2 * node + 1] = p1;
    }
    __syncthreads();
    int rowA = l & 15;
    int ak = g * 8;
    bf16x8 a0h = *(const bf16x8*)(ldsHi + rowA * 72 + ak);
    bf16x8 a1h = *(const bf16x8*)(ldsHi + rowA * 72 + 32 + ak);
    bf16x8 a0l = *(const bf16x8*)(ldsLo + rowA * 72 + ak);
    bf16x8 a1l = *(const bf16x8*)(ldsLo + rowA * 72 + 32 + ak);
    float dv[4];
#pragma unroll
    for (int b = 0; b < 4; b++) dv[b] = dinv[min(nb0 + g * 4 + b, N - 1)];
#pragma unroll
    for (int cc = 0; cc < 2; cc++) {
      int c = cc * 4 + w;
      size_t woff = (size_t)(c * 16 + rowA) * 64 + ak;
      bf16x8 b0h = *(const bf16x8*)(Wn2T + woff);
      bf16x8 b1h = *(const bf16x8*)(Wn2T + woff + 32);
      bf16x8 b0l = *(const bf16x8*)(Wn2Tlo + woff);
      bf16x8 b1l = *(const bf16x8*)(Wn2Tlo + woff + 32);
      f32x4 acc = {0.f, 0.f, 0.f, 0.f};
      acc = __builtin_amdgcn_mfma_f32_16x16x32_bf16(a0h, b0h, acc, 0, 0, 0);
      acc = __builtin_amdgcn_mfma_f32_16x16x32_bf16(a1h, b1h, acc, 0, 0, 0);
      acc = __builtin_amdgcn_mfma_f32_16x16x32_bf16(a0l, b0h, acc, 0, 0, 0);
      acc = __builtin_amdgcn_mfma_f32_16x16x32_bf16(a1l, b1h, acc, 0, 0, 0);
      acc = __builtin_amdgcn_mfma_f32_16x16x32_bf16(a0h, b0l, acc, 0, 0, 0);
      acc = __builtin_amdgcn_mfma_f32_16x16x32_bf16(a1h, b1l, acc, 0, 0, 0);
      int gcol = c * 16 + rowA;
#pragma unroll
      for (int b = 0; b < 4; b++) {
        int gr = nb0 + g * 4 + b;
        if (gr < N) {
          float v = acc[b];
          if (cc == 1) Bs_nxt[(size_t)gr * 64 + (gcol - 64)] = v * dv[b];
          else A_nxt[(size_t)gr * 64 + gcol] = v;
        }
      }
    }
#pragma unroll
    for (int cc = 0; cc < 4; cc++) {
      int jb = (cc & 1) + 2 * w;
      int koff = (cc < 2) ? 0 : 64;
      int j = jb * 16 + rowA;
      const unsigned short* wp = Wfc1T + (size_t)j * 128 + koff + ak;
      bf16x8 b0 = *(const bf16x8*)(wp);
      bf16x8 b1 = *(const bf16x8*)(wp + 32);
      f32x4 acc = {0.f, 0.f, 0.f, 0.f};
      acc = __builtin_amdgcn_mfma_f32_16x16x32_bf16(a0h, b0, acc, 0, 0, 0);
      acc = __builtin_amdgcn_mfma_f32_16x16x32_bf16(a1h, b1, acc, 0, 0, 0);
      acc = __builtin_amdgcn_mfma_f32_16x16x32_bf16(a0l, b0, acc, 0, 0, 0);
      acc = __builtin_amdgcn_mfma_f32_16x16x32_bf16(a1l, b1, acc, 0, 0, 0);
      unsigned short* dstb = (cc < 2) ? T_nxt : D_nxt;
#pragma unroll
      for (int b = 0; b < 4; b++) {
        int gr = nb0 + g * 4 + b;
        if (gr < N) dstb[(size_t)gr * 128 + j] = f2bf(acc[b]);
      }
    }
  }
}

// ---------------- fused rbuild + final: scores + ts, src-sorted order ----------------

__global__ __launch_bounds__(256, 4) void rbuild_final(
    const float* __restrict__ H0, const unsigned short* __restrict__ dHall,
    const float* __restrict__ tau, const int* __restrict__ pairs,
    const int* __restrict__ porder, const unsigned short* __restrict__ Wp1T,
    const float* __restrict__ Wp2, float* __restrict__ out, float* __restrict__ ts, int P,
    int N, int Lsteps) {
  __shared__ unsigned short sHi[16 * 136];
  __shared__ unsigned short sLo[16 * 136];
  __shared__ float sS[4][16];
  __shared__ int sP[16];
  __shared__ int sV[16];
  int pr = threadIdx.x >> 4;
  int l16 = threadIdx.x & 15;
  int i0 = (int)blockIdx.x * 16;
  bool act = (i0 + pr) < P;
  int p = porder[act ? (i0 + pr) : P - 1];
  if (l16 == 0) {
    sP[pr] = p;
    sV[pr] = act ? 1 : 0;
  }
  int node = (l16 < 8) ? pairs[2 * p] : pairs[2 * p + 1];
  int d0 = (l16 & 7) * 8;
  const float* hp = H0 + (size_t)node * 64 + d0;
  float4 h0 = *(const float4*)hp;
  float4 h1 = *(const float4*)(hp + 4);
  float acc[8] = {h0.x, h0.y, h0.z, h0.w, h1.x, h1.y, h1.z, h1.w};
  float tsum = 0.f;
  const unsigned short* dbase = dHall + (size_t)node * (Lsteps * 64) + d0;
  const float* taup = tau + (size_t)p * Lsteps;
#pragma unroll 10
  for (int t = 0; t < Lsteps; t++) {
    float tt = taup[t];
    tsum += tt;
    u16x8 v = *(const u16x8*)(dbase + t * 64);
#pragma unroll
    for (int i = 0; i < 8; i++) acc[i] = fmaf(tt, bf2f(v[i]), acc[i]);
  }
  u16x8 ohi, olo;
#pragma unroll
  for (int i = 0; i < 8; i++) {
    unsigned short hi = f2bf(acc[i]);
    ohi[i] = hi;
    olo[i] = f2bf(acc[i] - bf2f(hi));
  }
  *(u16x8*)(sHi + pr * 136 + l16 * 8) = ohi;
  *(u16x8*)(sLo + pr * 136 + l16 * 8) = olo;
  if (l16 == 0 && act) ts[p] = tsum;
  __syncthreads();
  int w = threadIdx.x >> 6;
  int l = threadIdx.x & 63;
  int rowA = l & 15;
  int ak = (l >> 4) * 8;
  bf16x8 ah[4], al[4];
#pragma unroll
  for (int kk = 0; kk < 4; kk++) {
    ah[kk] = *(const bf16x8*)(sHi + rowA * 136 + kk * 32 + ak);
    al[kk] = *(const bf16x8*)(sLo + rowA * 136 + kk * 32 + ak);
  }
  const unsigned short* wp = Wp1T + (size_t)(w * 16 + rowA) * 128 + ak;
  f32x4 macc = {0.f, 0.f, 0.f, 0.f};
#pragma unroll
  for (int kk = 0; kk < 4; kk++) {
    bf16x8 wv = *(const bf16x8*)(wp + kk * 32);
    macc = __builtin_amdgcn_mfma_f32_16x16x32_bf16(ah[kk], wv, macc, 0, 0, 0);
    macc = __builtin_amdgcn_mfma_f32_16x16x32_bf16(al[kk], wv, macc, 0, 0, 0);
  }
  float wcol = Wp2[w * 16 + rowA];
  float s[4];
#pragma unroll
  for (int b = 0; b < 4; b++) s[b] = fmaxf(macc[b], 0.f) * wcol;
#pragma unroll
  for (int off = 1; off < 16; off <<= 1) {
#pragma unroll
    for (int b = 0; b < 4; b++) s[b] += __shfl_xor(s[b], off, 64);
  }
  if ((l & 15) == 0) {
#pragma unroll
    for (int b = 0; b < 4; b++) sS[w][(l >> 4) * 4 + b] = s[b];
  }
  __syncthreads();
  if (threadIdx.x < 16) {
    int row = threadIdx.x;
    float sum = sS[0][row] + sS[1][row] + sS[2][row] + sS[3][row];
    if (sV[row]) out[sP[row]] = sum;
  }
}

// ---------------- launch ----------------

extern "C" void kernel_launch(void* const* d_in, const int* in_sizes, int n_in, void* d_out,
                              int out_size, void* d_ws, size_t ws_size, hipStream_t stream) {
  const float* x = (const float*)d_in[0];
  const int* edge = (const int*)d_in[1];
  const int* pairs = (const int*)d_in[2];
  const float* gumbel = (const float*)d_in[3];
  const float* Wenc = (const float*)d_in[4];
  const float* Om = (const float*)d_in[5];
  const float* Wsr = (const float*)d_in[6];
  const float* Wfc1 = (const float*)d_in[7];
  const float* Wfc2 = (const float*)d_in[8];
  const float* Wfv = (const float*)d_in[9];
  const float* Wp1 = (const float*)d_in[10];
  const float* Wp2 = (const float*)d_in[11];
  const int IN = 128;
  const int N = in_sizes[0] / IN;
  const int E = in_sizes[1] / 2;
  const int P = in_sizes[2] / 2;
  const int L = in_sizes[3] / (2 * P);
  float* out = (float*)d_out;

  char* wsb = (char*)d_ws;
  size_t off = 0;
  auto alloc = [&](size_t bytes) -> char* {
    char* p = wsb + off;
    off = (off + bytes + 255) & ~(size_t)255;
    return p;
  };
  const int NB = (N + 1023) >> 10;
  float* dinv = (float*)alloc((size_t)N * 4);
  int* cnt = (int*)alloc((size_t)N * 4);
  int* colptr = (int*)alloc((size_t)(N + 1) * 4);
  int* bsum = (int*)alloc((size_t)(NB + 1) * 4);
  int* csr = (int*)alloc((size_t)E * 4);
  int* pcnt = (int*)alloc((size_t)N * 4);
  int* pptr = (int*)alloc((size_t)(N + 1) * 4);
  int* pbsum = (int*)alloc((size_t)(NB + 1) * 4);
  int* porder = (int*)alloc((size_t)P * 4);
  unsigned short* Wn2T = (unsigned short*)alloc((size_t)128 * 64 * 2);
  unsigned short* Wn2Tlo = (unsigned short*)alloc((size_t)128 * 64 * 2);
  unsigned short* Wfc1T = (unsigned short*)alloc((size_t)128 * 128 * 2);
  unsigned short* WencT = (unsigned short*)alloc((size_t)64 * 128 * 2);
  unsigned short* Wp1T = (unsigned short*)alloc((size_t)64 * 128 * 2);
  float* H = (float*)alloc((size_t)N * 64 * 4);
  float* H0 = (float*)alloc((size_t)N * 64 * 4);
  unsigned short* Hb_hi = (unsigned short*)alloc((size_t)N * 64 * 2);
  unsigned short* Hb_lo = (unsigned short*)alloc((size_t)N * 64 * 2);
  float* A_a = (float*)alloc((size_t)N * 64 * 4);
  float* A_b = (float*)alloc((size_t)N * 64 * 4);
  float* Bs_a = (float*)alloc((size_t)N * 64 * 4);
  float* Bs_b = (float*)alloc((size_t)N * 64 * 4);
  unsigned short* T_a = (unsigned short*)alloc((size_t)N * 128 * 2);
  unsigned short* T_b = (unsigned short*)alloc((size_t)N * 128 * 2);
  unsigned short* D_a = (unsigned short*)alloc((size_t)N * 128 * 2);
  unsigned short* D_b = (unsigned short*)alloc((size_t)N * 128 * 2);
  float* ftfbA = (float*)alloc((size_t)N * 2 * 4);
  float* ftfbB = (float*)alloc((size_t)N * 2 * 4);
  unsigned short* dHall = (unsigned short*)alloc((size_t)N * L * 64 * 2);
  float* tau = (float*)alloc((size_t)P * L * 4);
  (void)ws_size;
  (void)n_in;
  (void)out_size;

  const int* erow = edge;
  const int* ecol = edge + E;

  hipMemsetAsync(cnt, 0, (size_t)N * 4, stream);
  hipMemsetAsync(pcnt, 0, (size_t)N * 4, stream);
  count_kernel<<<(E + 255) / 256, 256, 0, stream>>>(ecol, E, cnt);
  pcount_kernel<<<(P + 255) / 256, 256, 0, stream>>>(pairs, P, pcnt);
  scan1_kernel<<<NB, 1024, 0, stream>>>(cnt, colptr, dinv, bsum, N);
  scan1_kernel<<<NB, 1024, 0, stream>>>(pcnt, pptr, nullptr, pbsum, N);
  scan2_kernel<<<1, 64, 0, stream>>>(bsum, NB);
  scan2_kernel<<<1, 64, 0, stream>>>(pbsum, NB);
  scan3_kernel<<<(N + 256) / 256, 256, 0, stream>>>(colptr, bsum, N);
  scan3_kernel<<<(N + 256) / 256, 256, 0, stream>>>(pptr, pbsum, N);
  fill_kernel<<<(E + 255) / 256, 256, 0, stream>>>(erow, ecol, E, colptr, cnt, csr);
  pfill_kernel<<<(P + 255) / 256, 256, 0, stream>>>(pairs, P, pptr, pcnt, porder);
  prep_weights<<<(128 * 64 + 128 * 128 + 2 * 64 * 128 + 255) / 256, 256, 0, stream>>>(
      Om, Wsr, Wfc1, Wenc, Wp1, Wn2T, Wn2Tlo, Wfc1T, WencT, Wp1T);

  int nwaves = (N + 15) / 16;
  enc_gemm<<<(nwaves + 3) / 4, 256, 0, stream>>>(x, WencT, H, H0, Hb_hi, Hb_lo, N);
  node_gemm<<<(nwaves + 3) / 4, 256, 0, stream>>>(Hb_hi, Hb_lo, Wn2T, Wn2Tlo, Wfc1T, H, Wfv,
                                                  dinv, A_a, Bs_a, T_a, D_a, ftfbA, N);

  float* A_cur = A_a;   float* A_nxt = A_b;
  float* Bs_cur = Bs_a; float* Bs_nxt = Bs_b;
  unsigned short* T_cur = T_a; unsigned short* T_nxt = T_b;
  unsigned short* D_cur = D_a; unsigned short* D_nxt = D_b;
  float* ff_cur = ftfbA;
  float* ff_nxt = ftfbB;
  const int PB = (P + 31) / 32;
  const int AGB = (N + 15) / 16;
  for (int t = 0; t < L; t++) {
    step_fused<<<PB + AGB, 256, 0, stream>>>(
        A_cur, Bs_cur, T_cur, D_cur, A_nxt, Bs_nxt, T_nxt, D_nxt, colptr, csr, dinv, H, dHall,
        Wn2T, Wn2Tlo, Wfc1T, Wfc2, ff_cur, ff_nxt, Wfv, pairs, porder,
        gumbel + (size_t)t * P * 2, tau, t, L, N, P, PB);
    { float* tmp = A_cur; A_cur = A_nxt; A_nxt = tmp; }
    { float* tmp = Bs_cur; Bs_cur = Bs_nxt; Bs_nxt = tmp; }
    { unsigned short* tmp = T_cur; T_cur = T_nxt; T_nxt = tmp; }
    { unsigned short* tmp = D_cur; D_cur = D_nxt; D_nxt = tmp; }
    { float* tmp = ff_cur; ff_cur = ff_nxt; ff_nxt = tmp; }
  }
  rbuild_final<<<(P + 15) / 16, 256, 0, stream>>>(H0, dHall, tau, pairs, porder, Wp1T, Wp2,
                                                  out, out + P, P, N, L);
}